// Round 13
// baseline (652.634 us; speedup 1.0000x reference)
//
#include <hip/hip_runtime.h>
#include <hip/hip_bf16.h>

#define NB   16384
#define TT   50
#define HH   30
#define IND  8
#define CTXD 80
#define IN2  82
#define F2   52
#define NOUT 50
#define HID  100
#define CVD  20
#define HSTR2 40  // H row stride in shorts (80B: 16B-aligned, bank-quad-cycling)

typedef __attribute__((ext_vector_type(8))) short s8v;
typedef __attribute__((ext_vector_type(4))) float f4v;
typedef __attribute__((ext_vector_type(4))) unsigned short us4v;

__device__ __forceinline__ float sg(float x){
  return 1.f/(1.f+__expf(-x));
}
__device__ __forceinline__ float th(float x){
  x = fminf(x, 15.f);
  float e = __expf(2.f*x);
  return (e-1.f)/(e+1.f);
}
__device__ __forceinline__ unsigned short f2b(float f){
  __hip_bfloat16 h = __float2bfloat16(f);
  return *reinterpret_cast<unsigned short*>(&h);
}
__device__ __forceinline__ float b2f(unsigned short u){
  __hip_bfloat16 h;
  *reinterpret_cast<unsigned short*>(&h) = u;
  return __bfloat162float(h);
}
__device__ __forceinline__ double shfl_xor_d(double v, int m){
  long long ll = __double_as_longlong(v);
  int lo = (int)(ll & 0xffffffffLL), hi = (int)(ll >> 32);
  lo = __shfl_xor(lo, m, 64); hi = __shfl_xor(hi, m, 64);
  return __longlong_as_double(((long long)hi << 32) | (unsigned int)(unsigned)lo);
}

// ---------------- decoder MFMA fragment tables ----------------
__global__ void k_tw2(const float* __restrict__ w2ih0, const float* __restrict__ w2hh0,
                      const float* __restrict__ w2ih1, const float* __restrict__ w2hh1,
                      const float* __restrict__ b2ih0, const float* __restrict__ b2hh0,
                      const float* __restrict__ b2ih1, const float* __restrict__ b2hh1,
                      unsigned short* __restrict__ wb2, float* __restrict__ tb)
{
  int idx = blockIdx.x*256 + threadIdx.x;
  if (idx < 48*512){
    int f = idx >> 9, rem = idx & 511;
    int l = rem >> 3, j = rem & 7;
    int lr = l & 15, lq = l >> 4;
    float v = 0.f;
    if (f < 8){
      int ct = f, k = 8*lq + j, col = ct*16 + lr;
      int g = col>>5, u = col&31;
      if (k < HH && u < HH) v = w2hh0[(size_t)(g*HH+u)*HH + k];
    } else if (f < 24){
      int ct = (f-8)>>1, ks = (f-8)&1, k = 8*lq + j, col = ct*16 + lr;
      int g = col>>5, u = col&31;
      if (k < HH && u < HH) v = ks ? w2hh1[(size_t)(g*HH+u)*HH + k] : w2ih1[(size_t)(g*HH+u)*HH + k];
    } else {
      int ct = (f-24)/3, ks = (f-24)%3, k = ks*32 + 8*lq + j, col = ct*16 + lr;
      int g = col>>5, u = col&31;
      if (k < CTXD && u < HH) v = w2ih0[(size_t)(g*HH+u)*IN2 + k];
    }
    wb2[idx] = f2b(v);
  } else if (idx < 48*512 + 512){
    int t = idx - 48*512;
    int col = t & 127, sel = t >> 7;
    int g = col>>5, u = col&31;
    float v = 0.f;
    if (u < HH){
      int r = g*HH + u;
      if (sel == 0) v = b2ih0[r] + b2hh0[r];
      else if (sel == 1) v = b2ih1[r] + b2hh1[r];
      else if (sel == 2) v = w2ih0[(size_t)r*IN2 + 80];
      else v = w2ih0[(size_t)r*IN2 + 81];
    }
    tb[sel*128 + col] = v;
  }
}

// ---------------- encoder MFMA fragment tables ----------------
__global__ void k_tw3(const float* __restrict__ wih0, const float* __restrict__ whh0,
                      const float* __restrict__ wih1, const float* __restrict__ whh1,
                      const float* __restrict__ bih0, const float* __restrict__ bhh0,
                      const float* __restrict__ bih1, const float* __restrict__ bhh1,
                      unsigned short* __restrict__ wb3, float* __restrict__ tbe)
{
  int idx = blockIdx.x*256 + threadIdx.x;
  if (idx < 32*512){
    int f = idx >> 9, rem = idx & 511;
    int l = rem >> 3, j = rem & 7;
    int lr = l & 15, lq = l >> 4;
    int k = 8*lq + j;
    float v = 0.f;
    if (f < 8){
      int col = f*16 + lr; int g = col>>5, u = col&31;
      if (k < IND && u < HH) v = wih0[(size_t)(g*HH+u)*IND + k];
    } else if (f < 16){
      int ct = f-8; int col = ct*16 + lr; int g = col>>5, u = col&31;
      if (k < HH && u < HH) v = whh0[(size_t)(g*HH+u)*HH + k];
    } else {
      int ct = (f-16)>>1, ks = (f-16)&1; int col = ct*16 + lr; int g = col>>5, u = col&31;
      if (k < HH && u < HH) v = ks ? whh1[(size_t)(g*HH+u)*HH + k] : wih1[(size_t)(g*HH+u)*HH + k];
    }
    wb3[idx] = f2b(v);
  } else if (idx < 32*512 + 256){
    int t2 = idx - 32*512;
    int col = t2 & 127, sel = t2 >> 7;
    int g = col>>5, u = col&31;
    float v = 0.f;
    if (u < HH){
      int r = g*HH + u;
      v = sel ? (bih1[r] + bhh1[r]) : (bih0[r] + bhh0[r]);
    }
    tbe[sel*128 + col] = v;
  }
}

// ---------------- conv MFMA fragment tables ----------------
__global__ void k_tw4(const float* __restrict__ c1w, const float* __restrict__ c2w,
                      const float* __restrict__ c3w, const float* __restrict__ fcw,
                      unsigned short* __restrict__ wc)
{
  int idx = blockIdx.x*256 + threadIdx.x;
  if (idx >= 96*512) return;
  int f = idx >> 9, rem = idx & 511;
  int l = rem >> 3, j = rem & 7;
  int lr = l & 15, lq = l >> 4;
  int k = 8*lq + j;
  float v = 0.f;
  if (f < 4){
    int ks = f>>1, ct = f&1; int kk2 = ks*32 + k;
    if (kk2 < 40){ int kk = kk2>>3, ic = kk2&7; v = c1w[((size_t)(ct*16+lr)*8 + ic)*5 + kk]; }
  } else if (f < 16){
    int fi = f-4; int ks = fi>>2, ct = fi&3;
    v = c2w[((size_t)(ct*16+lr)*32 + k)*3 + ks];
  } else if (f < 64){
    int fi = f-16; int ks = fi>>3, ct = fi&7; int kk2 = ks*32 + k;
    int kk = kk2>>6, ic = kk2&63;
    v = c3w[((size_t)(ct*16+lr)*64 + ic)*3 + kk];
  } else {
    int fi = f-64; int ks = fi>>1, ct = fi&1; int kk2 = ks*32 + k;
    int p = kk2>>7, ocb = kk2&127;
    int n = ct*16 + lr;
    if (n < 20) v = fcw[(size_t)n*512 + ocb*4 + p];
  }
  wc[idx] = f2b(v);
}

// ---------------- readout Wd fragment table ----------------
__global__ void k_tw5(const float* __restrict__ Wd, unsigned short* __restrict__ wd5){
  int idx = blockIdx.x*256 + threadIdx.x;
  if (idx >= NOUT*14*512) return;
  int s = idx / (14*512), rem = idx - s*(14*512);
  int fi = rem >> 9, r2i = rem & 511;
  int l = r2i >> 3, j = r2i & 7;
  int lr = l & 15, lq = l >> 4;
  int ks = fi / 7, ct = fi - ks*7;
  int k = ks*32 + 8*lq + j, col = ct*16 + lr;
  float v = (k < F2 && col < HID) ? Wd[((size_t)s*F2 + k)*HID + col] : 0.f;
  wd5[idx] = f2b(v);
}

// ---------------- pack/transpose helpers ----------------
__global__ void k_pack(const float* __restrict__ x, float* __restrict__ tpack, float* __restrict__ ypack){
  int r = blockIdx.x*256 + threadIdx.x;
  if (r < NB){
    tpack[r] = x[(size_t)r*(TT*IND) + (TT-1)*IND + 7];
    ypack[r] = x[(size_t)r*(TT*IND) + (TT-1)*IND + 0];
  }
}

__global__ __launch_bounds__(256) void k_ty(const float* __restrict__ y, float* __restrict__ yT){
  __shared__ float tile[NOUT*65];
  int rr0 = blockIdx.x*64;
  for (int i=threadIdx.x; i<64*NOUT; i+=256){
    int r = i/NOUT, s = i - r*NOUT;
    tile[s*65 + r] = y[(size_t)(rr0+r)*NOUT + s];
  }
  __syncthreads();
  for (int i=threadIdx.x; i<64*NOUT; i+=256){
    int s = i>>6, r = i&63;
    yT[(size_t)s*NB + rr0 + r] = tile[s*65 + r];
  }
}

__global__ __launch_bounds__(256) void k_tro(const float* __restrict__ outT, float* __restrict__ out){
  __shared__ float tile[NOUT*65];
  int rr0 = blockIdx.x*64;
  for (int i=threadIdx.x; i<64*NOUT; i+=256){
    int s = i>>6, r = i&63;
    tile[s*65 + r] = outT[(size_t)s*NB + rr0 + r];
  }
  __syncthreads();
  for (int i=threadIdx.x; i<64*NOUT; i+=256){
    int r = i/NOUT, s = i - r*NOUT;
    out[(size_t)(rr0+r)*NOUT + s] = tile[s*65 + r];
  }
}

// ---------------- zero accumulators (s1 + s2) ----------------
__global__ void k_zero(double* s1, double* s2){
  int i = blockIdx.x*256 + threadIdx.x;
  if (i < CTXD*2) s1[i] = 0.0;
  if (i < NOUT*F2*2) s2[i] = 0.0;
}

// ---------------- encoder: barrier-free per-wave MFMA LSTM ----------------
// 256 thr = 4 waves; wave w owns 16 samples (blk*64 + w*16 ..). Each lane: units lr, lr+16,
// samples 4*lq+i. All 8 ct fragments per wave -> no cross-wave deps, no step-loop barriers.
__global__ __launch_bounds__(256, 2) void k_encm(
    const float* __restrict__ x, const float* __restrict__ h0i, const float* __restrict__ c0i,
    const unsigned short* __restrict__ wb3, const float* __restrict__ tbe,
    float* __restrict__ h0f, float* __restrict__ h1f,
    float* __restrict__ c0f, float* __restrict__ c1f)
{
  __shared__ __align__(16) unsigned short XS[TT*64*8];
  __shared__ __align__(16) unsigned short H0[64*HSTR2];
  __shared__ __align__(16) unsigned short H1[64*HSTR2];
  const int tid = threadIdx.x;
  const int l = tid & 63, w = tid >> 6;
  const int lr = l & 15, lq = l >> 4;
  const int blk = blockIdx.x;
  const int wbase = w*16;

  for (int i = tid; i < 64*HSTR2; i += 256){ H0[i]=0; H1[i]=0; }
  for (int i = tid; i < 64*100; i += 256){
    int smp = i/100, q = i - smp*100;
    float4 v = ((const float4*)(x + (size_t)(blk*64+smp)*(TT*IND)))[q];
    int t = q>>1, d = (q&1)*4;
    unsigned short* p = &XS[t*512 + smp*8 + d];
    p[0]=f2b(v.x); p[1]=f2b(v.y); p[2]=f2b(v.z); p[3]=f2b(v.w);
  }
  __syncthreads();
  for (int i = tid; i < 64*HH; i += 256){
    int r = i/HH, u2 = i - r*HH;
    H0[r*HSTR2 + u2] = f2b(h0i[u2]);
    H1[r*HSTR2 + u2] = f2b(h0i[HH+u2]);
  }

  const int uA = lr, uB = lr + 16;
  const int uBc = uB < HH ? uB : HH-1;
  const int aoff = (wbase + lr)*HSTR2 + lq*8;
  float c0a[4], c0b[4], c1a[4], c1b[4];
  #pragma unroll
  for (int i=0;i<4;++i){
    c0a[i] = c0i[uA];  c0b[i] = c0i[uBc];
    c1a[i] = c0i[HH+uA]; c1b[i] = c0i[HH+uBc];
  }
  s8v BX[8], BH[8], B10[8], B11[8];
  float b0v[8], b1v[8];
  #pragma unroll
  for (int ct=0; ct<8; ++ct){
    const int col = ct*16 + lr;
    BX[ct]  = *(const s8v*)(wb3 + ((size_t)(ct)*64 + l)*8);
    BH[ct]  = *(const s8v*)(wb3 + ((size_t)(8 + ct)*64 + l)*8);
    B10[ct] = *(const s8v*)(wb3 + ((size_t)(16 + ct*2 + 0)*64 + l)*8);
    B11[ct] = *(const s8v*)(wb3 + ((size_t)(16 + ct*2 + 1)*64 + l)*8);
    b0v[ct] = tbe[col]; b1v[ct] = tbe[128+col];
  }
  __syncthreads();

  const int wr0 = (wbase + 4*lq)*HSTR2;
  for (int t=0; t<TT; ++t){
    s8v ax = {0,0,0,0,0,0,0,0};
    if (lq == 0) ax = *(const s8v*)&XS[t*512 + (wbase+lr)*8];
    const s8v ah = *(const s8v*)&H0[aoff];
    f4v ac[8];
    #pragma unroll
    for (int ct=0; ct<8; ++ct){
      f4v a = {b0v[ct], b0v[ct], b0v[ct], b0v[ct]};
      a = __builtin_amdgcn_mfma_f32_16x16x32_bf16(ax, BX[ct], a, 0, 0, 0);
      ac[ct] = __builtin_amdgcn_mfma_f32_16x16x32_bf16(ah, BH[ct], a, 0, 0, 0);
    }
    #pragma unroll
    for (int i=0;i<4;++i){
      float iv = sg(ac[0][i]), fv = sg(ac[2][i]), gv = th(ac[4][i]), ov = sg(ac[6][i]);
      c0a[i] = fv*c0a[i] + iv*gv;
      H0[wr0 + i*HSTR2 + uA] = f2b(ov*th(c0a[i]));
      float iv2 = sg(ac[1][i]), fv2 = sg(ac[3][i]), gv2 = th(ac[5][i]), ov2 = sg(ac[7][i]);
      c0b[i] = fv2*c0b[i] + iv2*gv2;
      H0[wr0 + i*HSTR2 + uB] = f2b(ov2*th(c0b[i]));
    }
    const s8v a1 = *(const s8v*)&H0[aoff];
    const s8v a2 = *(const s8v*)&H1[aoff];
    #pragma unroll
    for (int ct=0; ct<8; ++ct){
      f4v a = {b1v[ct], b1v[ct], b1v[ct], b1v[ct]};
      a = __builtin_amdgcn_mfma_f32_16x16x32_bf16(a1, B10[ct], a, 0, 0, 0);
      ac[ct] = __builtin_amdgcn_mfma_f32_16x16x32_bf16(a2, B11[ct], a, 0, 0, 0);
    }
    #pragma unroll
    for (int i=0;i<4;++i){
      float iv = sg(ac[0][i]), fv = sg(ac[2][i]), gv = th(ac[4][i]), ov = sg(ac[6][i]);
      c1a[i] = fv*c1a[i] + iv*gv;
      H1[wr0 + i*HSTR2 + uA] = f2b(ov*th(c1a[i]));
      float iv2 = sg(ac[1][i]), fv2 = sg(ac[3][i]), gv2 = th(ac[5][i]), ov2 = sg(ac[7][i]);
      c1b[i] = fv2*c1b[i] + iv2*gv2;
      H1[wr0 + i*HSTR2 + uB] = f2b(ov2*th(c1b[i]));
    }
  }
  __syncthreads();
  for (int i2 = tid; i2 < 64*HH; i2 += 256){
    int sl = i2 / HH, uu = i2 - sl*HH;
    h0f[((size_t)blk*64 + sl)*HH + uu] = b2f(H0[sl*HSTR2 + uu]);
    h1f[((size_t)blk*64 + sl)*HH + uu] = b2f(H1[sl*HSTR2 + uu]);
  }
  {
    const int sb = blk*64 + wbase + 4*lq;
    #pragma unroll
    for (int i=0;i<4;++i){
      c0f[(size_t)(sb+i)*HH + uA] = c0a[i];
      c1f[(size_t)(sb+i)*HH + uA] = c1a[i];
      if (uB < HH){
        c0f[(size_t)(sb+i)*HH + uB] = c0b[i];
        c1f[(size_t)(sb+i)*HH + uB] = c1b[i];
      }
    }
  }
}

// ---------------- conv path: MFMA ----------------
__global__ __launch_bounds__(256, 2) void k_convm(
    const float* __restrict__ x, const unsigned short* __restrict__ wc,
    const float* __restrict__ b1, const float* __restrict__ b2,
    const float* __restrict__ b3, const float* __restrict__ fb,
    float* __restrict__ xcg)
{
  __shared__ __align__(16) unsigned short XT[16*52*8];
  __shared__ __align__(16) unsigned short P1[16*26*32];
  __shared__ __align__(16) unsigned short P2[16*10*64];
  __shared__ __align__(16) unsigned short P3[16*4*128];
  const int tid = threadIdx.x, l = tid & 63, w = tid >> 6;
  const int lr = l & 15, lq = l >> 4;
  const int blk = blockIdx.x;
  for (int i=tid; i<16*16; i+=256){ int s=i>>4, q=i&15; XT[s*416 + 400 + q] = 0; }
  for (int i=tid; i<16*96; i+=256){ int s=i/96, q=i - (i/96)*96; P1[s*832 + 736 + q] = 0; }
  for (int i=tid; i<1600; i+=256){
    int s = i/100, q = i - s*100;
    float4 v = ((const float4*)(x + (size_t)(blk*16+s)*400))[q];
    int t = q>>1, d = (q&1)*4;
    unsigned short* p = &XT[s*416 + t*8 + d];
    p[0]=f2b(v.x); p[1]=f2b(v.y); p[2]=f2b(v.z); p[3]=f2b(v.w);
  }
  __syncthreads();
  {
    s8v B[2][2];
    #pragma unroll
    for (int ks=0;ks<2;++ks)
      #pragma unroll
      for (int ct=0;ct<2;++ct)
        B[ks][ct] = *(const s8v*)(wc + ((size_t)(ks*2+ct)*512) + l*8);
    float bv[2] = { b1[lr], b1[16+lr] };
    for (int t5=w; t5<48; t5+=4){
      int row = t5*16 + lr, s = row/48, pos = row - s*48;
      s8v a0 = *(const s8v*)&XT[s*416 + (pos+lq)*8];
      s8v a1 = {0,0,0,0,0,0,0,0};
      if (lq == 0) a1 = *(const s8v*)&XT[s*416 + (pos+4)*8];
      int rb = t5*16 + 4*lq, s2 = rb/48, pp = rb - s2*48;
      #pragma unroll
      for (int ct=0;ct<2;++ct){
        f4v acc = {bv[ct],bv[ct],bv[ct],bv[ct]};
        acc = __builtin_amdgcn_mfma_f32_16x16x32_bf16(a0, B[0][ct], acc, 0, 0, 0);
        acc = __builtin_amdgcn_mfma_f32_16x16x32_bf16(a1, B[1][ct], acc, 0, 0, 0);
        int oc = ct*16 + lr;
        #pragma unroll
        for (int pr=0;pr<2;++pr){
          int pos2 = (pp>>1) + pr;
          if (pos2 < 23){
            float v = fmaxf(fmaxf(acc[2*pr],0.f), fmaxf(acc[2*pr+1],0.f));
            int ch = (oc>>3) ^ (pos2&3);
            P1[s2*832 + pos2*32 + ch*8 + (oc&7)] = f2b(v);
          }
        }
      }
    }
  }
  __syncthreads();
  {
    s8v B[3][4];
    #pragma unroll
    for (int ks=0;ks<3;++ks)
      #pragma unroll
      for (int ct=0;ct<4;++ct)
        B[ks][ct] = *(const s8v*)(wc + ((size_t)(4+ks*4+ct)*512) + l*8);
    float bv[4] = { b2[lr], b2[16+lr], b2[32+lr], b2[48+lr] };
    for (int t6=w; t6<24; t6+=4){
      int row = t6*16 + lr, s = row/24, pos = row - s*24;
      s8v a[3];
      #pragma unroll
      for (int ks=0;ks<3;++ks){
        int pr = pos + ks, ch = lq ^ (pr&3);
        a[ks] = *(const s8v*)&P1[s*832 + pr*32 + ch*8];
      }
      int rb = t6*16 + 4*lq, s2 = rb/24, pp = rb - s2*24;
      #pragma unroll
      for (int ct=0;ct<4;++ct){
        f4v acc = {bv[ct],bv[ct],bv[ct],bv[ct]};
        #pragma unroll
        for (int ks=0;ks<3;++ks)
          acc = __builtin_amdgcn_mfma_f32_16x16x32_bf16(a[ks], B[ks][ct], acc, 0, 0, 0);
        int oc = ct*16 + lr;
        #pragma unroll
        for (int pr=0;pr<2;++pr){
          int pos2 = (pp>>1) + pr;
          if (pos2 < 10){
            float v = fmaxf(fmaxf(acc[2*pr],0.f), fmaxf(acc[2*pr+1],0.f));
            int ch = (oc>>3) ^ (pos2&7);
            P2[s2*640 + pos2*64 + ch*8 + (oc&7)] = f2b(v);
          }
        }
      }
    }
  }
  __syncthreads();
  {
    s8v A[2][6]; int sS[2], ppS[2];
    #pragma unroll
    for (int tt=0;tt<2;++tt){
      int t7 = w*2 + tt;
      int row = t7*16 + lr, s = row>>3, pos = row&7;
      #pragma unroll
      for (int ks=0;ks<6;++ks){
        int pr = pos + (ks>>1);
        int cb = 4*(ks&1) + lq;
        int ch = cb ^ (pr&7);
        A[tt][ks] = *(const s8v*)&P2[s*640 + pr*64 + ch*8];
      }
      int rb = t7*16 + 4*lq;
      sS[tt] = rb>>3; ppS[tt] = rb&7;
    }
    for (int ct=0;ct<8;++ct){
      s8v B[6];
      #pragma unroll
      for (int ks=0;ks<6;++ks)
        B[ks] = *(const s8v*)(wc + ((size_t)(16+ks*8+ct)*512) + l*8);
      int oc = ct*16 + lr;
      float bb = b3[oc];
      #pragma unroll
      for (int tt=0;tt<2;++tt){
        f4v acc = {bb,bb,bb,bb};
        #pragma unroll
        for (int ks=0;ks<6;++ks)
          acc = __builtin_amdgcn_mfma_f32_16x16x32_bf16(A[tt][ks], B[ks], acc, 0, 0, 0);
        #pragma unroll
        for (int pr=0;pr<2;++pr){
          int pos2 = (ppS[tt]>>1) + pr;
          float v = fmaxf(fmaxf(acc[2*pr],0.f), fmaxf(acc[2*pr+1],0.f));
          int flat = pos2*128 + oc;
          int ch = (flat>>3) ^ (sS[tt]&7);
          P3[sS[tt]*512 + ch*8 + (oc&7)] = f2b(v);
        }
      }
    }
  }
  __syncthreads();
  if (w == 0){
    f4v acc[2];
    float fb0 = fb[lr];
    float fb1 = (lr < 4) ? fb[16+lr] : 0.f;
    acc[0] = (f4v){fb0,fb0,fb0,fb0};
    acc[1] = (f4v){fb1,fb1,fb1,fb1};
    for (int ks=0;ks<16;++ks){
      int k0 = ks*32 + 8*lq;
      int ch = (k0>>3) ^ (lr&7);
      s8v a = *(const s8v*)&P3[lr*512 + ch*8];
      #pragma unroll
      for (int ct=0;ct<2;++ct){
        s8v Bf = *(const s8v*)(wc + ((size_t)(64+ks*2+ct)*512) + l*8);
        acc[ct] = __builtin_amdgcn_mfma_f32_16x16x32_bf16(a, Bf, acc[ct], 0, 0, 0);
      }
    }
    #pragma unroll
    for (int ct=0;ct<2;++ct){
      int oc = ct*16 + lr;
      if (oc < 20){
        #pragma unroll
        for (int i=0;i<4;++i){
          int smp = 4*lq + i;
          xcg[(size_t)(blk*16+smp)*CVD + oc] = fmaxf(acc[ct][i], 0.f);
        }
      }
    }
  }
}

// ---------------- BN1 stats ----------------
__global__ __launch_bounds__(128) void k_bn1s(const float* __restrict__ h0f, const float* __restrict__ h1f,
    const float* __restrict__ xcg, double* __restrict__ s1)
{
  int f = threadIdx.x;
  if (f >= CTXD) return;
  int r0 = blockIdx.x*128;
  double s=0.0, q=0.0;
  for (int i=0;i<128;++i){
    int r = r0+i;
    float v = (f<HH) ? h0f[(size_t)r*HH+f] : (f<2*HH) ? h1f[(size_t)r*HH + f-HH] : xcg[(size_t)r*CVD + f-2*HH];
    s += (double)v; q += (double)v*(double)v;
  }
  atomicAdd(&s1[f*2],   s);
  atomicAdd(&s1[f*2+1], q);
}

__global__ void k_fin1(const double* __restrict__ s1, float* __restrict__ st1){
  int f = threadIdx.x;
  if (f >= CTXD) return;
  double m = s1[f*2]/(double)NB;
  double var = s1[f*2+1]/(double)NB - m*m;
  if (var < 0.0) var = 0.0;
  st1[f*2]   = (float)m;
  st1[f*2+1] = (float)(1.0/sqrt(var + 1e-5));
}

__global__ __launch_bounds__(256) void k_context(const float* __restrict__ h0f, const float* __restrict__ h1f,
    const float* __restrict__ xcg, const float* __restrict__ st1,
    const float* __restrict__ g1, const float* __restrict__ bb1, float* __restrict__ ctx)
{
  int idx = blockIdx.x*256 + threadIdx.x;
  if (idx >= NB*CTXD) return;
  int rr = idx / CTXD, f = idx - rr*CTXD;
  float v = (f<HH) ? h0f[(size_t)rr*HH+f] : (f<2*HH) ? h1f[(size_t)rr*HH + f-HH] : xcg[(size_t)rr*CVD + f-2*HH];
  ctx[idx] = (v - st1[f*2]) * st1[f*2+1] * g1[f] + bb1[f];
}

// ---------------- decoder pass 1: barrier-free per-wave MFMA LSTM ----------------
__global__ __launch_bounds__(256, 2) void k_dec1m(
    const float* __restrict__ tpack, const float* __restrict__ ypack, const float* __restrict__ yT,
    const float* __restrict__ ctx,
    const unsigned short* __restrict__ wb2, const float* __restrict__ tb,
    const float* __restrict__ h0fi, const float* __restrict__ h1fi,
    const float* __restrict__ c0fi, const float* __restrict__ c1fi,
    __hip_bfloat16* __restrict__ h1n)
{
  __shared__ __align__(16) unsigned short CT[64*96];
  __shared__ __align__(16) unsigned short H0[64*HSTR2];
  __shared__ __align__(16) unsigned short H1[64*HSTR2];
  const int tid = threadIdx.x;
  const int l = tid & 63, w = tid >> 6;
  const int lr = l & 15, lq = l >> 4, l3 = l & 3;
  const int blk = blockIdx.x;
  const int wbase = w*16;

  for (int i = tid; i < 64*HSTR2; i += 256){ H0[i]=0; H1[i]=0; }
  for (int i = tid; i < 64*96; i += 256) CT[i] = 0;
  __syncthreads();
  for (int i = tid; i < 64*CTXD; i += 256){
    int r = i / CTXD, kk = i - r*CTXD;
    float v = ctx[((size_t)blk*64 + r)*CTXD + kk];
    CT[r*96 + (((kk>>3) ^ (r&3))<<3) + (kk&7)] = f2b(v);
  }
  for (int i = tid; i < 64*HH; i += 256){
    int r = i / HH, u2 = i - r*HH;
    H0[r*HSTR2 + u2] = f2b(h0fi[((size_t)blk*64 + r)*HH + u2]);
    H1[r*HSTR2 + u2] = f2b(h1fi[((size_t)blk*64 + r)*HH + u2]);
  }

  const int uA = lr, uB = lr + 16;
  const int uBc = uB < HH ? uB : HH-1;
  const int aoff = (wbase + lr)*HSTR2 + lq*8;
  const int sbase = blk*64 + wbase + 4*lq;
  float c0a[4], c0b[4], c1a[4], c1b[4], tt[4], yv[4];
  {
    float4 tv = *(const float4*)&tpack[sbase];
    float4 yv4 = *(const float4*)&ypack[sbase];
    tt[0]=tv.x; tt[1]=tv.y; tt[2]=tv.z; tt[3]=tv.w;
    yv[0]=yv4.x; yv[1]=yv4.y; yv[2]=yv4.z; yv[3]=yv4.w;
  }
  #pragma unroll
  for (int i=0;i<4;++i){
    c0a[i] = c0fi[(size_t)(sbase+i)*HH + uA];
    c0b[i] = c0fi[(size_t)(sbase+i)*HH + uBc];
    c1a[i] = c1fi[(size_t)(sbase+i)*HH + uA];
    c1b[i] = c1fi[(size_t)(sbase+i)*HH + uBc];
  }
  s8v B0[8], B10[8], B11[8];
  float bias1[8], wtt8[8], wty8[8], b0v[8];
  #pragma unroll
  for (int ct=0; ct<8; ++ct){
    const int col = ct*16 + lr;
    B0[ct]  = *(const s8v*)(wb2 + ((size_t)(ct)*64 + l)*8);
    B10[ct] = *(const s8v*)(wb2 + ((size_t)(8 + ct*2 + 0)*64 + l)*8);
    B11[ct] = *(const s8v*)(wb2 + ((size_t)(8 + ct*2 + 1)*64 + l)*8);
    b0v[ct] = tb[col]; bias1[ct] = tb[128+col];
    wtt8[ct] = tb[256+col]; wty8[ct] = tb[384+col];
  }
  __syncthreads();

  const int arow = wbase + lr;
  f4v pc[8];
  #pragma unroll
  for (int ct=0; ct<8; ++ct){
    f4v a = {b0v[ct], b0v[ct], b0v[ct], b0v[ct]};
    #pragma unroll
    for (int ks=0; ks<3; ++ks){
      s8v bc = *(const s8v*)(wb2 + ((size_t)(24 + ct*3 + ks)*64 + l)*8);
      s8v av = *(const s8v*)&CT[arow*96 + (((ks*4+lq) ^ l3)<<3)];
      a = __builtin_amdgcn_mfma_f32_16x16x32_bf16(av, bc, a, 0, 0, 0);
    }
    pc[ct] = a;
  }

  const int wr0 = (wbase + 4*lq)*HSTR2;
  unsigned short* h1s = reinterpret_cast<unsigned short*>(h1n);
  for (int s = 0; s < NOUT; ++s){
    #pragma unroll
    for (int i=0;i<4;++i) tt[i] = fmodf(tt[i] + 15.f, 1440.f);
    const s8v a0 = *(const s8v*)&H0[aoff];
    f4v ac[8];
    #pragma unroll
    for (int ct=0; ct<8; ++ct){
      f4v a = pc[ct];
      #pragma unroll
      for (int i=0;i<4;++i) a[i] += tt[i]*wtt8[ct] + yv[i]*wty8[ct];
      ac[ct] = __builtin_amdgcn_mfma_f32_16x16x32_bf16(a0, B0[ct], a, 0, 0, 0);
    }
    #pragma unroll
    for (int i=0;i<4;++i){
      float iv = sg(ac[0][i]), fv = sg(ac[2][i]), gv = th(ac[4][i]), ov = sg(ac[6][i]);
      c0a[i] = fv*c0a[i] + iv*gv;
      H0[wr0 + i*HSTR2 + uA] = f2b(ov*th(c0a[i]));
      float iv2 = sg(ac[1][i]), fv2 = sg(ac[3][i]), gv2 = th(ac[5][i]), ov2 = sg(ac[7][i]);
      c0b[i] = fv2*c0b[i] + iv2*gv2;
      H0[wr0 + i*HSTR2 + uB] = f2b(ov2*th(c0b[i]));
    }
    const s8v a1 = *(const s8v*)&H0[aoff];
    const s8v a2 = *(const s8v*)&H1[aoff];
    #pragma unroll
    for (int ct=0; ct<8; ++ct){
      f4v a = {bias1[ct], bias1[ct], bias1[ct], bias1[ct]};
      a = __builtin_amdgcn_mfma_f32_16x16x32_bf16(a1, B10[ct], a, 0, 0, 0);
      ac[ct] = __builtin_amdgcn_mfma_f32_16x16x32_bf16(a2, B11[ct], a, 0, 0, 0);
    }
    unsigned short hA[4], hB[4];
    #pragma unroll
    for (int i=0;i<4;++i){
      float iv = sg(ac[0][i]), fv = sg(ac[2][i]), gv = th(ac[4][i]), ov = sg(ac[6][i]);
      c1a[i] = fv*c1a[i] + iv*gv;
      hA[i] = f2b(ov*th(c1a[i]));
      H1[wr0 + i*HSTR2 + uA] = hA[i];
      float iv2 = sg(ac[1][i]), fv2 = sg(ac[3][i]), gv2 = th(ac[5][i]), ov2 = sg(ac[7][i]);
      c1b[i] = fv2*c1b[i] + iv2*gv2;
      hB[i] = f2b(ov2*th(c1b[i]));
      H1[wr0 + i*HSTR2 + uB] = hB[i];
    }
    {
      us4v pkA = {hA[0], hA[1], hA[2], hA[3]};
      *reinterpret_cast<us4v*>(&h1s[((size_t)s*HH + uA)*NB + sbase]) = pkA;
      if (uB < HH){
        us4v pkB = {hB[0], hB[1], hB[2], hB[3]};
        *reinterpret_cast<us4v*>(&h1s[((size_t)s*HH + uB)*NB + sbase]) = pkB;
      }
    }
    {
      float4 yv4 = *(const float4*)&yT[(size_t)s*NB + sbase];
      yv[0]=yv4.x; yv[1]=yv4.y; yv[2]=yv4.z; yv[3]=yv4.w;
    }
  }
}

// ---------------- BN2 stats: contiguous-array reductions ----------------
__global__ __launch_bounds__(256) void k_bn2h(
    const __hip_bfloat16* __restrict__ h1n, double* __restrict__ s2)
{
  __shared__ double sd[256];
  __shared__ double qd[256];
  const int s = blockIdx.x, u = blockIdx.y;
  const unsigned short* p = (const unsigned short*)(h1n + ((size_t)s*HH + u)*NB);
  double sv = 0.0, sq = 0.0;
  #pragma unroll
  for (int c = 0; c < 8; ++c){
    s8v v = *(const s8v*)(p + ((size_t)c*256 + threadIdx.x)*8);
    #pragma unroll
    for (int j=0;j<8;++j){
      float f = b2f((unsigned short)v[j]);
      sv += f; sq += (double)f*(double)f;
    }
  }
  sd[threadIdx.x] = sv; qd[threadIdx.x] = sq;
  __syncthreads();
  for (int st2=128; st2>0; st2>>=1){
    if ((int)threadIdx.x < st2){
      sd[threadIdx.x] += sd[threadIdx.x+st2];
      qd[threadIdx.x] += qd[threadIdx.x+st2];
    }
    __syncthreads();
  }
  if (threadIdx.x == 0){
    s2[((size_t)s*F2 + u)*2]   = sd[0];
    s2[((size_t)s*F2 + u)*2+1] = qd[0];
  }
}

__global__ __launch_bounds__(256) void k_bn2y(
    const float* __restrict__ ypack, const float* __restrict__ yT, double* __restrict__ s2)
{
  __shared__ double sd[256];
  __shared__ double qd[256];
  const int s = blockIdx.x;
  const float* src = (s == 0) ? ypack : (yT + (size_t)(s-1)*NB);
  double sv = 0.0, sq = 0.0;
  #pragma unroll
  for (int c = 0; c < 16; ++c){
    float4 v = *(const float4*)(src + ((size_t)c*256 + threadIdx.x)*4);
    sv += (double)v.x + (double)v.y + (double)v.z + (double)v.w;
    sq += (double)v.x*v.x + (double)v.y*v.y + (double)v.z*v.z + (double)v.w*v.w;
  }
  sd[threadIdx.x] = sv; qd[threadIdx.x] = sq;
  __syncthreads();
  for (int st2=128; st2>0; st2>>=1){
    if ((int)threadIdx.x < st2){
      sd[threadIdx.x] += sd[threadIdx.x+st2];
      qd[threadIdx.x] += qd[threadIdx.x+st2];
    }
    __syncthreads();
  }
  if (threadIdx.x == 0){
    s2[((size_t)s*F2 + 51)*2]   = sd[0];
    s2[((size_t)s*F2 + 51)*2+1] = qd[0];
  }
}

__global__ __launch_bounds__(256) void k_bn2t(
    const float* __restrict__ tpack, double* __restrict__ s2)
{
  const int r = blockIdx.x*256 + threadIdx.x;
  float t = tpack[r];
  const int lane = threadIdx.x & 63;
  for (int s = 0; s < NOUT; ++s){
    t = fmodf(t + 15.f, 1440.f);
    double sv = (double)t, sq = (double)t*(double)t;
    #pragma unroll
    for (int m=32;m>0;m>>=1){ sv += shfl_xor_d(sv,m); sq += shfl_xor_d(sq,m); }
    if (lane == 0){
      atomicAdd(&s2[((size_t)s*F2 + 50)*2],   sv);
      atomicAdd(&s2[((size_t)s*F2 + 50)*2+1], sq);
    }
  }
}

__global__ __launch_bounds__(256) void k_fin2b(
    const double* __restrict__ s1, const double* __restrict__ s2,
    float* __restrict__ m2, float* __restrict__ r2)
{
  int i = blockIdx.x*256 + threadIdx.x;
  if (i >= NOUT*F2) return;
  int f = i % F2;
  double sv, sq;
  if (f >= HH && f < HH+CVD){
    sv = s1[(2*HH + (f-HH))*2];
    sq = s1[(2*HH + (f-HH))*2+1];
  } else {
    sv = s2[i*2]; sq = s2[i*2+1];
  }
  double m = sv/(double)NB;
  double var = sq/(double)NB - m*m;
  if (var < 0.0) var = 0.0;
  m2[i] = (float)m;
  r2[i] = (float)(1.0/sqrt(var + 1e-5));
}

// ---------------- readout: MFMA GEMM with split-A bf16 ----------------
__global__ __launch_bounds__(256, 4) void k_rdm(
    const __hip_bfloat16* __restrict__ h1n, const float* __restrict__ xcg,
    const float* __restrict__ tpack, const float* __restrict__ ypack, const float* __restrict__ yT,
    const float* __restrict__ m2, const float* __restrict__ r2,
    const float* __restrict__ g2, const float* __restrict__ b2v,
    const unsigned short* __restrict__ wd5, const float* __restrict__ Bd,
    const float* __restrict__ Ud, const float* __restrict__ Cd,
    float* __restrict__ outT)
{
  __shared__ __align__(16) unsigned short FH[64*64];
  __shared__ __align__(16) unsigned short FL[64*64];
  __shared__ float scl[F2], sft[F2];
  const int tid = threadIdx.x, l = tid & 63, w = tid >> 6;
  const int lr = l & 15, lq = l >> 4;
  const int s = blockIdx.y, rr0 = blockIdx.x*64;
  if (tid < F2){
    float m = m2[s*F2+tid], rv = r2[s*F2+tid];
    float sc = rv * g2[tid];
    scl[tid] = sc;
    sft[tid] = b2v[tid] - m*sc;
  }
  __syncthreads();
  for (int i = tid; i < 64*64; i += 256){
    int f = i >> 6, r = i & 63;
    float v;
    if (f < HH) v = __bfloat162float(h1n[((size_t)s*HH + f)*NB + rr0 + r]);
    else if (f < HH+CVD) v = xcg[(size_t)(rr0+r)*CVD + (f-HH)];
    else if (f == 50){
      float t0 = tpack[rr0+r];
      for (int k=0;k<=s;++k) t0 = fmodf(t0 + 15.f, 1440.f);
      v = t0;
    }
    else if (f == 51) v = (s==0) ? ypack[rr0+r] : yT[(size_t)(s-1)*NB + rr0 + r];
    else v = 0.f;
    if (f < F2) v = v*scl[f] + sft[f];
    unsigned short hi = f2b(v);
    float lo = v - b2f(hi);
    int off = r*64 + ((((f>>3) ^ (r&7))&7)<<3) + (f&7);
    FH[off] = hi;
    FL[off] = f2b(lo);
  }
  __syncthreads();
  const int row = w*16 + lr;
  s8v ah[2], al[2];
  #pragma unroll
  for (int ks=0;ks<2;++ks){
    int ch = ((ks*4+lq) ^ (row&7)) & 7;
    ah[ks] = *(const s8v*)&FH[row*64 + ch*8];
    al[ks] = *(const s8v*)&FL[row*64 + ch*8];
  }
  f4v ps = {0.f,0.f,0.f,0.f};
  #pragma unroll 7
  for (int ct=0; ct<7; ++ct){
    int col = ct*16 + lr;
    float bd = (col < HID) ? Bd[(size_t)s*HID + col] : 0.f;
    f4v acc = {bd,bd,bd,bd};
    #pragma unroll
    for (int ks=0;ks<2;++ks){
      s8v B = *(const s8v*)(wd5 + ((size_t)(s*14 + ks*7 + ct)*512) + l*8);
      acc = __builtin_amdgcn_mfma_f32_16x16x32_bf16(ah[ks], B, acc, 0, 0, 0);
      acc = __builtin_amdgcn_mfma_f32_16x16x32_bf16(al[ks], B, acc, 0, 0, 0);
    }
    float ud = (col < HID) ? Ud[(size_t)s*HID + col] : 0.f;
    #pragma unroll
    for (int i=0;i<4;++i) ps[i] += fmaxf(acc[i], 0.f) * ud;
  }
  #pragma unroll
  for (int m=1; m<16; m<<=1){
    #pragma unroll
    for (int i=0;i<4;++i) ps[i] += __shfl_xor(ps[i], m, 64);
  }
  if (lr == 0){
    float cd = Cd[s];
    float4 o = { ps[0]+cd, ps[1]+cd, ps[2]+cd, ps[3]+cd };
    *(float4*)&outT[(size_t)s*NB + rr0 + w*16 + lq*4] = o;
  }
}

// ---------------- host ----------------
extern "C" void kernel_launch(void* const* d_in, const int* in_sizes, int n_in,
                              void* d_out, int out_size, void* d_ws, size_t ws_size,
                              hipStream_t stream)
{
  const float* x    = (const float*)d_in[0];
  const float* y    = (const float*)d_in[1];
  const float* h0i  = (const float*)d_in[2];
  const float* c0i  = (const float*)d_in[3];
  const float* wih0 = (const float*)d_in[4];
  const float* whh0 = (const float*)d_in[5];
  const float* bih0 = (const float*)d_in[6];
  const float* bhh0 = (const float*)d_in[7];
  const float* wih1 = (const float*)d_in[8];
  const float* whh1 = (const float*)d_in[9];
  const float* bih1 = (const float*)d_in[10];
  const float* bhh1 = (const float*)d_in[11];
  const float* w2ih0= (const float*)d_in[12];
  const float* w2hh0= (const float*)d_in[13];
  const float* b2ih0= (const float*)d_in[14];
  const float* b2hh0= (const float*)d_in[15];
  const float* w2ih1= (const float*)d_in[16];
  const float* w2hh1= (const float*)d_in[17];
  const float* b2ih1= (const float*)d_in[18];
  const float* b2hh1= (const float*)d_in[19];
  const float* c1w  = (const float*)d_in[20];
  const float* c1b  = (const float*)d_in[21];
  const float* c2w  = (const float*)d_in[22];
  const float* c2b  = (const float*)d_in[23];
  const float* c3w  = (const float*)d_in[24];
  const float* c3b  = (const float*)d_in[25];
  const float* fcw  = (const float*)d_in[26];
  const float* fcb  = (const float*)d_in[27];
  const float* bn1g = (const float*)d_in[28];
  const float* bn1b = (const float*)d_in[29];
  const float* bn2g = (const float*)d_in[30];
  const float* bn2b = (const float*)d_in[31];
  const float* Wd   = (const float*)d_in[32];
  const float* Bd   = (const float*)d_in[33];
  const float* Ud   = (const float*)d_in[34];
  const float* Cd   = (const float*)d_in[35];
  float* out = (float*)d_out;

  char* base = (char*)d_ws;
  size_t off = 0;
  auto take = [&](size_t bytes)->char*{
    char* p = base + off;
    off = (off + bytes + 255) & ~(size_t)255;
    return p;
  };
  float*  h0f = (float*) take((size_t)NB*HH*sizeof(float));
  float*  h1f = (float*) take((size_t)NB*HH*sizeof(float));
  float*  c0f = (float*) take((size_t)NB*HH*sizeof(float));
  float*  c1f = (float*) take((size_t)NB*HH*sizeof(float));
  float*  xcg = (float*) take((size_t)NB*CVD*sizeof(float));
  float*  ctx = (float*) take((size_t)NB*CTXD*sizeof(float));
  double* s1  = (double*)take((size_t)CTXD*2*sizeof(double));
  float*  st1 = (float*) take((size_t)CTXD*2*sizeof(float));
  double* s2  = (double*)take((size_t)NOUT*F2*2*sizeof(double));
  float*  m2  = (float*) take((size_t)NOUT*F2*sizeof(float));
  float*  r2  = (float*) take((size_t)NOUT*F2*sizeof(float));
  unsigned short* wb2 = (unsigned short*) take((size_t)48*512*sizeof(unsigned short));
  float*  tb  = (float*) take((size_t)4*128*sizeof(float));
  unsigned short* wb3 = (unsigned short*) take((size_t)32*512*sizeof(unsigned short));
  float*  tbe = (float*) take((size_t)2*128*sizeof(float));
  unsigned short* wc  = (unsigned short*) take((size_t)96*512*sizeof(unsigned short));
  unsigned short* wd5 = (unsigned short*) take((size_t)NOUT*14*512*sizeof(unsigned short));
  float*  tpk = (float*) take((size_t)NB*sizeof(float));
  float*  ypk = (float*) take((size_t)NB*sizeof(float));
  float*  yT  = (float*) take((size_t)NOUT*NB*sizeof(float));
  float*  oT  = (float*) take((size_t)NOUT*NB*sizeof(float));
  __hip_bfloat16* h1n = (__hip_bfloat16*) take((size_t)NOUT*HH*NB*sizeof(__hip_bfloat16));
  (void)ws_size;

  k_tw2<<<dim3((48*512+512+255)/256), dim3(256), 0, stream>>>(w2ih0, w2hh0, w2ih1, w2hh1,
      b2ih0, b2hh0, b2ih1, b2hh1, wb2, tb);
  k_tw3<<<dim3((32*512+256+255)/256), dim3(256), 0, stream>>>(wih0, whh0, wih1, whh1,
      bih0, bhh0, bih1, bhh1, wb3, tbe);
  k_tw4<<<dim3((96*512+255)/256), dim3(256), 0, stream>>>(c1w, c2w, c3w, fcw, wc);
  k_tw5<<<dim3((NOUT*14*512+255)/256), dim3(256), 0, stream>>>(Wd, wd5);
  k_pack<<<dim3(NB/256), dim3(256), 0, stream>>>(x, tpk, ypk);
  k_ty<<<dim3(NB/64), dim3(256), 0, stream>>>(y, yT);
  k_zero<<<dim3((NOUT*F2*2+255)/256), dim3(256), 0, stream>>>(s1, s2);
  k_encm<<<dim3(NB/64), dim3(256), 0, stream>>>(x, h0i, c0i, wb3, tbe, h0f, h1f, c0f, c1f);
  k_convm<<<dim3(NB/16), dim3(256), 0, stream>>>(x, wc, c1b, c2b, c3b, fcb, xcg);
  k_bn1s<<<dim3(NB/128), dim3(128), 0, stream>>>(h0f, h1f, xcg, s1);
  k_fin1<<<dim3(1), dim3(128), 0, stream>>>(s1, st1);
  k_context<<<dim3((NB*CTXD + 255)/256), dim3(256), 0, stream>>>(h0f, h1f, xcg, st1, bn1g, bn1b, ctx);
  k_dec1m<<<dim3(NB/64), dim3(256), 0, stream>>>(tpk, ypk, yT, ctx, wb2, tb,
      h0f, h1f, c0f, c1f, h1n);
  k_bn2h<<<dim3(NOUT, HH), dim3(256), 0, stream>>>(h1n, s2);
  k_bn2y<<<dim3(NOUT), dim3(256), 0, stream>>>(ypk, yT, s2);
  k_bn2t<<<dim3(NB/256), dim3(256), 0, stream>>>(tpk, s2);
  k_fin2b<<<dim3((NOUT*F2+255)/256), dim3(256), 0, stream>>>(s1, s2, m2, r2);
  k_rdm<<<dim3(NB/64, NOUT), dim3(256), 0, stream>>>(h1n, xcg, tpk, ypk, yT,
      m2, r2, bn2g, bn2b, wd5, Bd, Ud, Cd, oT);
  k_tro<<<dim3(NB/64), dim3(256), 0, stream>>>(oT, out);
}

// Round 14
// 559.239 us; speedup vs baseline: 1.1670x; 1.1670x over previous
//
#include <hip/hip_runtime.h>
#include <hip/hip_bf16.h>

#define NB   16384
#define TT   50
#define HH   30
#define IND  8
#define CTXD 80
#define IN2  82
#define F2   52
#define NOUT 50
#define HID  100
#define CVD  20
#define SMP  64   // samples per LSTM block (8 waves)
#define HSTR2 40  // H row stride in shorts (80B: 16B-aligned, bank-quad-cycling)

typedef __attribute__((ext_vector_type(8))) short s8v;
typedef __attribute__((ext_vector_type(4))) float f4v;
typedef __attribute__((ext_vector_type(4))) unsigned short us4v;

__device__ __forceinline__ float sg(float x){
  return 1.f/(1.f+__expf(-x));
}
__device__ __forceinline__ float th(float x){
  x = fminf(x, 15.f);
  float e = __expf(2.f*x);
  return (e-1.f)/(e+1.f);
}
__device__ __forceinline__ unsigned short f2b(float f){
  __hip_bfloat16 h = __float2bfloat16(f);
  return *reinterpret_cast<unsigned short*>(&h);
}
__device__ __forceinline__ float b2f(unsigned short u){
  __hip_bfloat16 h;
  *reinterpret_cast<unsigned short*>(&h) = u;
  return __bfloat162float(h);
}
__device__ __forceinline__ double shfl_xor_d(double v, int m){
  long long ll = __double_as_longlong(v);
  int lo = (int)(ll & 0xffffffffLL), hi = (int)(ll >> 32);
  lo = __shfl_xor(lo, m, 64); hi = __shfl_xor(hi, m, 64);
  return __longlong_as_double(((long long)hi << 32) | (unsigned int)(unsigned)lo);
}

// ---------------- decoder MFMA fragment tables ----------------
__global__ void k_tw2(const float* __restrict__ w2ih0, const float* __restrict__ w2hh0,
                      const float* __restrict__ w2ih1, const float* __restrict__ w2hh1,
                      const float* __restrict__ b2ih0, const float* __restrict__ b2hh0,
                      const float* __restrict__ b2ih1, const float* __restrict__ b2hh1,
                      unsigned short* __restrict__ wb2, float* __restrict__ tb)
{
  int idx = blockIdx.x*256 + threadIdx.x;
  if (idx < 48*512){
    int f = idx >> 9, rem = idx & 511;
    int l = rem >> 3, j = rem & 7;
    int lr = l & 15, lq = l >> 4;
    float v = 0.f;
    if (f < 8){
      int ct = f, k = 8*lq + j, col = ct*16 + lr;
      int g = col>>5, u = col&31;
      if (k < HH && u < HH) v = w2hh0[(size_t)(g*HH+u)*HH + k];
    } else if (f < 24){
      int ct = (f-8)>>1, ks = (f-8)&1, k = 8*lq + j, col = ct*16 + lr;
      int g = col>>5, u = col&31;
      if (k < HH && u < HH) v = ks ? w2hh1[(size_t)(g*HH+u)*HH + k] : w2ih1[(size_t)(g*HH+u)*HH + k];
    } else {
      int ct = (f-24)/3, ks = (f-24)%3, k = ks*32 + 8*lq + j, col = ct*16 + lr;
      int g = col>>5, u = col&31;
      if (k < CTXD && u < HH) v = w2ih0[(size_t)(g*HH+u)*IN2 + k];
    }
    wb2[idx] = f2b(v);
  } else if (idx < 48*512 + 512){
    int t = idx - 48*512;
    int col = t & 127, sel = t >> 7;
    int g = col>>5, u = col&31;
    float v = 0.f;
    if (u < HH){
      int r = g*HH + u;
      if (sel == 0) v = b2ih0[r] + b2hh0[r];
      else if (sel == 1) v = b2ih1[r] + b2hh1[r];
      else if (sel == 2) v = w2ih0[(size_t)r*IN2 + 80];
      else v = w2ih0[(size_t)r*IN2 + 81];
    }
    tb[sel*128 + col] = v;
  }
}

// ---------------- encoder MFMA fragment tables ----------------
__global__ void k_tw3(const float* __restrict__ wih0, const float* __restrict__ whh0,
                      const float* __restrict__ wih1, const float* __restrict__ whh1,
                      const float* __restrict__ bih0, const float* __restrict__ bhh0,
                      const float* __restrict__ bih1, const float* __restrict__ bhh1,
                      unsigned short* __restrict__ wb3, float* __restrict__ tbe)
{
  int idx = blockIdx.x*256 + threadIdx.x;
  if (idx < 32*512){
    int f = idx >> 9, rem = idx & 511;
    int l = rem >> 3, j = rem & 7;
    int lr = l & 15, lq = l >> 4;
    int k = 8*lq + j;
    float v = 0.f;
    if (f < 8){
      int col = f*16 + lr; int g = col>>5, u = col&31;
      if (k < IND && u < HH) v = wih0[(size_t)(g*HH+u)*IND + k];
    } else if (f < 16){
      int ct = f-8; int col = ct*16 + lr; int g = col>>5, u = col&31;
      if (k < HH && u < HH) v = whh0[(size_t)(g*HH+u)*HH + k];
    } else {
      int ct = (f-16)>>1, ks = (f-16)&1; int col = ct*16 + lr; int g = col>>5, u = col&31;
      if (k < HH && u < HH) v = ks ? whh1[(size_t)(g*HH+u)*HH + k] : wih1[(size_t)(g*HH+u)*HH + k];
    }
    wb3[idx] = f2b(v);
  } else if (idx < 32*512 + 256){
    int t2 = idx - 32*512;
    int col = t2 & 127, sel = t2 >> 7;
    int g = col>>5, u = col&31;
    float v = 0.f;
    if (u < HH){
      int r = g*HH + u;
      v = sel ? (bih1[r] + bhh1[r]) : (bih0[r] + bhh0[r]);
    }
    tbe[sel*128 + col] = v;
  }
}

// ---------------- conv MFMA fragment tables ----------------
__global__ void k_tw4(const float* __restrict__ c1w, const float* __restrict__ c2w,
                      const float* __restrict__ c3w, const float* __restrict__ fcw,
                      unsigned short* __restrict__ wc)
{
  int idx = blockIdx.x*256 + threadIdx.x;
  if (idx >= 96*512) return;
  int f = idx >> 9, rem = idx & 511;
  int l = rem >> 3, j = rem & 7;
  int lr = l & 15, lq = l >> 4;
  int k = 8*lq + j;
  float v = 0.f;
  if (f < 4){
    int ks = f>>1, ct = f&1; int kk2 = ks*32 + k;
    if (kk2 < 40){ int kk = kk2>>3, ic = kk2&7; v = c1w[((size_t)(ct*16+lr)*8 + ic)*5 + kk]; }
  } else if (f < 16){
    int fi = f-4; int ks = fi>>2, ct = fi&3;
    v = c2w[((size_t)(ct*16+lr)*32 + k)*3 + ks];
  } else if (f < 64){
    int fi = f-16; int ks = fi>>3, ct = fi&7; int kk2 = ks*32 + k;
    int kk = kk2>>6, ic = kk2&63;
    v = c3w[((size_t)(ct*16+lr)*64 + ic)*3 + kk];
  } else {
    int fi = f-64; int ks = fi>>1, ct = fi&1; int kk2 = ks*32 + k;
    int p = kk2>>7, ocb = kk2&127;
    int n = ct*16 + lr;
    if (n < 20) v = fcw[(size_t)n*512 + ocb*4 + p];
  }
  wc[idx] = f2b(v);
}

// ---------------- readout Wd fragment table ----------------
__global__ void k_tw5(const float* __restrict__ Wd, unsigned short* __restrict__ wd5){
  int idx = blockIdx.x*256 + threadIdx.x;
  if (idx >= NOUT*14*512) return;
  int s = idx / (14*512), rem = idx - s*(14*512);
  int fi = rem >> 9, r2i = rem & 511;
  int l = r2i >> 3, j = r2i & 7;
  int lr = l & 15, lq = l >> 4;
  int ks = fi / 7, ct = fi - ks*7;
  int k = ks*32 + 8*lq + j, col = ct*16 + lr;
  float v = (k < F2 && col < HID) ? Wd[((size_t)s*F2 + k)*HID + col] : 0.f;
  wd5[idx] = f2b(v);
}

// ---------------- pack/transpose helpers ----------------
__global__ void k_pack(const float* __restrict__ x, float* __restrict__ tpack, float* __restrict__ ypack){
  int r = blockIdx.x*256 + threadIdx.x;
  if (r < NB){
    tpack[r] = x[(size_t)r*(TT*IND) + (TT-1)*IND + 7];
    ypack[r] = x[(size_t)r*(TT*IND) + (TT-1)*IND + 0];
  }
}

__global__ __launch_bounds__(256) void k_ty(const float* __restrict__ y, float* __restrict__ yT){
  __shared__ float tile[NOUT*65];
  int rr0 = blockIdx.x*64;
  for (int i=threadIdx.x; i<64*NOUT; i+=256){
    int r = i/NOUT, s = i - r*NOUT;
    tile[s*65 + r] = y[(size_t)(rr0+r)*NOUT + s];
  }
  __syncthreads();
  for (int i=threadIdx.x; i<64*NOUT; i+=256){
    int s = i>>6, r = i&63;
    yT[(size_t)s*NB + rr0 + r] = tile[s*65 + r];
  }
}

__global__ __launch_bounds__(256) void k_tro(const float* __restrict__ outT, float* __restrict__ out){
  __shared__ float tile[NOUT*65];
  int rr0 = blockIdx.x*64;
  for (int i=threadIdx.x; i<64*NOUT; i+=256){
    int s = i>>6, r = i&63;
    tile[s*65 + r] = outT[(size_t)s*NB + rr0 + r];
  }
  __syncthreads();
  for (int i=threadIdx.x; i<64*NOUT; i+=256){
    int r = i/NOUT, s = i - r*NOUT;
    out[(size_t)(rr0+r)*NOUT + s] = tile[s*65 + r];
  }
}

// ---------------- zero accumulators (s1 + s2) ----------------
__global__ void k_zero(double* s1, double* s2){
  int i = blockIdx.x*256 + threadIdx.x;
  if (i < CTXD*2) s1[i] = 0.0;
  if (i < NOUT*F2*2) s2[i] = 0.0;
}

// ---------------- encoder: MFMA LSTM, 64 samples / 8 waves (R12 structure) ----------------
__global__ __launch_bounds__(512, 2) void k_encm(
    const float* __restrict__ x, const float* __restrict__ h0i, const float* __restrict__ c0i,
    const unsigned short* __restrict__ wb3, const float* __restrict__ tbe,
    float* __restrict__ h0f, float* __restrict__ h1f,
    float* __restrict__ c0f, float* __restrict__ c1f)
{
  __shared__ __align__(16) unsigned short XS[TT*SMP*8];
  __shared__ __align__(16) unsigned short H0[2][SMP*HSTR2];
  __shared__ __align__(16) unsigned short H1[2][SMP*HSTR2];
  const int tid = threadIdx.x;
  const int l = tid & 63, w = tid >> 6;           // 8 waves
  const int st = w & 3, ug = w >> 2;
  const int lr = l & 15, lq = l >> 4;
  const int blk = blockIdx.x;

  for (int i = tid; i < SMP*HSTR2; i += 512){
    H0[0][i]=0; H0[1][i]=0; H1[0][i]=0; H1[1][i]=0;
  }
  for (int i = tid; i < SMP*100; i += 512){
    int smp = i/100, q = i - smp*100;
    float4 v = ((const float4*)(x + (size_t)(blk*SMP+smp)*(TT*IND)))[q];
    int t = q>>1, d = (q&1)*4;
    unsigned short* p = &XS[t*(SMP*8) + smp*8 + d];
    p[0]=f2b(v.x); p[1]=f2b(v.y); p[2]=f2b(v.z); p[3]=f2b(v.w);
  }
  __syncthreads();
  for (int i = tid; i < SMP*HH; i += 512){
    int r = i/HH, u2 = i - r*HH;
    H0[0][r*HSTR2 + u2] = f2b(h0i[u2]);
    H1[0][r*HSTR2 + u2] = f2b(h0i[HH+u2]);
  }

  const int u  = ug*16 + lr;
  const int uc = u < HH ? u : HH-1;
  const int arow = st*16 + lr;
  const int aoff = arow*HSTR2 + lq*8;
  float c0[4], c1[4];
  #pragma unroll
  for (int i=0;i<4;++i){
    c0[i] = c0i[uc];
    c1[i] = c0i[HH+uc];
  }
  s8v BX[4], BH[4], B10[4], B11[4];
  float b0v[4], b1v[4];
  #pragma unroll
  for (int g=0; g<4; ++g){
    const int ct = g*2 + ug;
    const int col = ct*16 + lr;
    BX[g]  = *(const s8v*)(wb3 + ((size_t)(ct)*64 + l)*8);
    BH[g]  = *(const s8v*)(wb3 + ((size_t)(8 + ct)*64 + l)*8);
    B10[g] = *(const s8v*)(wb3 + ((size_t)(16 + ct*2 + 0)*64 + l)*8);
    B11[g] = *(const s8v*)(wb3 + ((size_t)(16 + ct*2 + 1)*64 + l)*8);
    b0v[g] = tbe[col]; b1v[g] = tbe[128+col];
  }
  __syncthreads();

  const int wrow = (st*16 + 4*lq)*HSTR2 + u;   // base of 4 consecutive sample rows
  int cur = 0;
  for (int t=0; t<TT; ++t){
    const int nxt = cur ^ 1;
    s8v ax = {0,0,0,0,0,0,0,0};
    if (lq == 0) ax = *(const s8v*)&XS[t*(SMP*8) + arow*8];
    const s8v ah = *(const s8v*)&H0[cur][aoff];
    f4v ac[4];
    #pragma unroll
    for (int g=0; g<4; ++g){
      f4v a = {b0v[g], b0v[g], b0v[g], b0v[g]};
      a = __builtin_amdgcn_mfma_f32_16x16x32_bf16(ax, BX[g], a, 0, 0, 0);
      ac[g] = __builtin_amdgcn_mfma_f32_16x16x32_bf16(ah, BH[g], a, 0, 0, 0);
    }
    unsigned short hw[4];
    #pragma unroll
    for (int i=0;i<4;++i){
      float iv = sg(ac[0][i]), fv = sg(ac[1][i]), gv = th(ac[2][i]), ov = sg(ac[3][i]);
      c0[i] = fv*c0[i] + iv*gv;
      hw[i] = f2b(ov*th(c0[i]));
    }
    if (u < HH){
      #pragma unroll
      for (int i=0;i<4;++i) H0[nxt][wrow + i*HSTR2] = hw[i];
    }
    __syncthreads();
    const s8v a1 = *(const s8v*)&H0[nxt][aoff];
    const s8v a2 = *(const s8v*)&H1[cur][aoff];
    #pragma unroll
    for (int g=0; g<4; ++g){
      f4v a = {b1v[g], b1v[g], b1v[g], b1v[g]};
      a = __builtin_amdgcn_mfma_f32_16x16x32_bf16(a1, B10[g], a, 0, 0, 0);
      ac[g] = __builtin_amdgcn_mfma_f32_16x16x32_bf16(a2, B11[g], a, 0, 0, 0);
    }
    #pragma unroll
    for (int i=0;i<4;++i){
      float iv = sg(ac[0][i]), fv = sg(ac[1][i]), gv = th(ac[2][i]), ov = sg(ac[3][i]);
      c1[i] = fv*c1[i] + iv*gv;
      hw[i] = f2b(ov*th(c1[i]));
    }
    if (u < HH){
      #pragma unroll
      for (int i=0;i<4;++i) H1[nxt][wrow + i*HSTR2] = hw[i];
    }
    __syncthreads();
    cur = nxt;
  }
  for (int i2 = tid; i2 < SMP*HH; i2 += 512){
    int sl = i2 / HH, uu = i2 - sl*HH;
    h0f[((size_t)blk*SMP + sl)*HH + uu] = b2f(H0[cur][sl*HSTR2 + uu]);
    h1f[((size_t)blk*SMP + sl)*HH + uu] = b2f(H1[cur][sl*HSTR2 + uu]);
  }
  if (u < HH){
    #pragma unroll
    for (int i=0;i<4;++i){
      int gS = blk*SMP + st*16 + 4*lq + i;
      c0f[(size_t)gS*HH + u] = c0[i];
      c1f[(size_t)gS*HH + u] = c1[i];
    }
  }
}

// ---------------- conv path: MFMA ----------------
__global__ __launch_bounds__(256, 2) void k_convm(
    const float* __restrict__ x, const unsigned short* __restrict__ wc,
    const float* __restrict__ b1, const float* __restrict__ b2,
    const float* __restrict__ b3, const float* __restrict__ fb,
    float* __restrict__ xcg)
{
  __shared__ __align__(16) unsigned short XT[16*52*8];
  __shared__ __align__(16) unsigned short P1[16*26*32];
  __shared__ __align__(16) unsigned short P2[16*10*64];
  __shared__ __align__(16) unsigned short P3[16*4*128];
  const int tid = threadIdx.x, l = tid & 63, w = tid >> 6;
  const int lr = l & 15, lq = l >> 4;
  const int blk = blockIdx.x;
  for (int i=tid; i<16*16; i+=256){ int s=i>>4, q=i&15; XT[s*416 + 400 + q] = 0; }
  for (int i=tid; i<16*96; i+=256){ int s=i/96, q=i - (i/96)*96; P1[s*832 + 736 + q] = 0; }
  for (int i=tid; i<1600; i+=256){
    int s = i/100, q = i - s*100;
    float4 v = ((const float4*)(x + (size_t)(blk*16+s)*400))[q];
    int t = q>>1, d = (q&1)*4;
    unsigned short* p = &XT[s*416 + t*8 + d];
    p[0]=f2b(v.x); p[1]=f2b(v.y); p[2]=f2b(v.z); p[3]=f2b(v.w);
  }
  __syncthreads();
  {
    s8v B[2][2];
    #pragma unroll
    for (int ks=0;ks<2;++ks)
      #pragma unroll
      for (int ct=0;ct<2;++ct)
        B[ks][ct] = *(const s8v*)(wc + ((size_t)(ks*2+ct)*512) + l*8);
    float bv[2] = { b1[lr], b1[16+lr] };
    for (int t5=w; t5<48; t5+=4){
      int row = t5*16 + lr, s = row/48, pos = row - s*48;
      s8v a0 = *(const s8v*)&XT[s*416 + (pos+lq)*8];
      s8v a1 = {0,0,0,0,0,0,0,0};
      if (lq == 0) a1 = *(const s8v*)&XT[s*416 + (pos+4)*8];
      int rb = t5*16 + 4*lq, s2 = rb/48, pp = rb - s2*48;
      #pragma unroll
      for (int ct=0;ct<2;++ct){
        f4v acc = {bv[ct],bv[ct],bv[ct],bv[ct]};
        acc = __builtin_amdgcn_mfma_f32_16x16x32_bf16(a0, B[0][ct], acc, 0, 0, 0);
        acc = __builtin_amdgcn_mfma_f32_16x16x32_bf16(a1, B[1][ct], acc, 0, 0, 0);
        int oc = ct*16 + lr;
        #pragma unroll
        for (int pr=0;pr<2;++pr){
          int pos2 = (pp>>1) + pr;
          if (pos2 < 23){
            float v = fmaxf(fmaxf(acc[2*pr],0.f), fmaxf(acc[2*pr+1],0.f));
            int ch = (oc>>3) ^ (pos2&3);
            P1[s2*832 + pos2*32 + ch*8 + (oc&7)] = f2b(v);
          }
        }
      }
    }
  }
  __syncthreads();
  {
    s8v B[3][4];
    #pragma unroll
    for (int ks=0;ks<3;++ks)
      #pragma unroll
      for (int ct=0;ct<4;++ct)
        B[ks][ct] = *(const s8v*)(wc + ((size_t)(4+ks*4+ct)*512) + l*8);
    float bv[4] = { b2[lr], b2[16+lr], b2[32+lr], b2[48+lr] };
    for (int t6=w; t6<24; t6+=4){
      int row = t6*16 + lr, s = row/24, pos = row - s*24;
      s8v a[3];
      #pragma unroll
      for (int ks=0;ks<3;++ks){
        int pr = pos + ks, ch = lq ^ (pr&3);
        a[ks] = *(const s8v*)&P1[s*832 + pr*32 + ch*8];
      }
      int rb = t6*16 + 4*lq, s2 = rb/24, pp = rb - s2*24;
      #pragma unroll
      for (int ct=0;ct<4;++ct){
        f4v acc = {bv[ct],bv[ct],bv[ct],bv[ct]};
        #pragma unroll
        for (int ks=0;ks<3;++ks)
          acc = __builtin_amdgcn_mfma_f32_16x16x32_bf16(a[ks], B[ks][ct], acc, 0, 0, 0);
        int oc = ct*16 + lr;
        #pragma unroll
        for (int pr=0;pr<2;++pr){
          int pos2 = (pp>>1) + pr;
          if (pos2 < 10){
            float v = fmaxf(fmaxf(acc[2*pr],0.f), fmaxf(acc[2*pr+1],0.f));
            int ch = (oc>>3) ^ (pos2&7);
            P2[s2*640 + pos2*64 + ch*8 + (oc&7)] = f2b(v);
          }
        }
      }
    }
  }
  __syncthreads();
  {
    s8v A[2][6]; int sS[2], ppS[2];
    #pragma unroll
    for (int tt=0;tt<2;++tt){
      int t7 = w*2 + tt;
      int row = t7*16 + lr, s = row>>3, pos = row&7;
      #pragma unroll
      for (int ks=0;ks<6;++ks){
        int pr = pos + (ks>>1);
        int cb = 4*(ks&1) + lq;
        int ch = cb ^ (pr&7);
        A[tt][ks] = *(const s8v*)&P2[s*640 + pr*64 + ch*8];
      }
      int rb = t7*16 + 4*lq;
      sS[tt] = rb>>3; ppS[tt] = rb&7;
    }
    for (int ct=0;ct<8;++ct){
      s8v B[6];
      #pragma unroll
      for (int ks=0;ks<6;++ks)
        B[ks] = *(const s8v*)(wc + ((size_t)(16+ks*8+ct)*512) + l*8);
      int oc = ct*16 + lr;
      float bb = b3[oc];
      #pragma unroll
      for (int tt=0;tt<2;++tt){
        f4v acc = {bb,bb,bb,bb};
        #pragma unroll
        for (int ks=0;ks<6;++ks)
          acc = __builtin_amdgcn_mfma_f32_16x16x32_bf16(A[tt][ks], B[ks], acc, 0, 0, 0);
        #pragma unroll
        for (int pr=0;pr<2;++pr){
          int pos2 = (ppS[tt]>>1) + pr;
          float v = fmaxf(fmaxf(acc[2*pr],0.f), fmaxf(acc[2*pr+1],0.f));
          int flat = pos2*128 + oc;
          int ch = (flat>>3) ^ (sS[tt]&7);
          P3[sS[tt]*512 + ch*8 + (oc&7)] = f2b(v);
        }
      }
    }
  }
  __syncthreads();
  if (w == 0){
    f4v acc[2];
    float fb0 = fb[lr];
    float fb1 = (lr < 4) ? fb[16+lr] : 0.f;
    acc[0] = (f4v){fb0,fb0,fb0,fb0};
    acc[1] = (f4v){fb1,fb1,fb1,fb1};
    for (int ks=0;ks<16;++ks){
      int k0 = ks*32 + 8*lq;
      int ch = (k0>>3) ^ (lr&7);
      s8v a = *(const s8v*)&P3[lr*512 + ch*8];
      #pragma unroll
      for (int ct=0;ct<2;++ct){
        s8v Bf = *(const s8v*)(wc + ((size_t)(64+ks*2+ct)*512) + l*8);
        acc[ct] = __builtin_amdgcn_mfma_f32_16x16x32_bf16(a, Bf, acc[ct], 0, 0, 0);
      }
    }
    #pragma unroll
    for (int ct=0;ct<2;++ct){
      int oc = ct*16 + lr;
      if (oc < 20){
        #pragma unroll
        for (int i=0;i<4;++i){
          int smp = 4*lq + i;
          xcg[(size_t)(blk*16+smp)*CVD + oc] = fmaxf(acc[ct][i], 0.f);
        }
      }
    }
  }
}

// ---------------- BN1 stats ----------------
__global__ __launch_bounds__(128) void k_bn1s(const float* __restrict__ h0f, const float* __restrict__ h1f,
    const float* __restrict__ xcg, double* __restrict__ s1)
{
  int f = threadIdx.x;
  if (f >= CTXD) return;
  int r0 = blockIdx.x*128;
  double s=0.0, q=0.0;
  for (int i=0;i<128;++i){
    int r = r0+i;
    float v = (f<HH) ? h0f[(size_t)r*HH+f] : (f<2*HH) ? h1f[(size_t)r*HH + f-HH] : xcg[(size_t)r*CVD + f-2*HH];
    s += (double)v; q += (double)v*(double)v;
  }
  atomicAdd(&s1[f*2],   s);
  atomicAdd(&s1[f*2+1], q);
}

__global__ void k_fin1(const double* __restrict__ s1, float* __restrict__ st1){
  int f = threadIdx.x;
  if (f >= CTXD) return;
  double m = s1[f*2]/(double)NB;
  double var = s1[f*2+1]/(double)NB - m*m;
  if (var < 0.0) var = 0.0;
  st1[f*2]   = (float)m;
  st1[f*2+1] = (float)(1.0/sqrt(var + 1e-5));
}

__global__ __launch_bounds__(256) void k_context(const float* __restrict__ h0f, const float* __restrict__ h1f,
    const float* __restrict__ xcg, const float* __restrict__ st1,
    const float* __restrict__ g1, const float* __restrict__ bb1, float* __restrict__ ctx)
{
  int idx = blockIdx.x*256 + threadIdx.x;
  if (idx >= NB*CTXD) return;
  int rr = idx / CTXD, f = idx - rr*CTXD;
  float v = (f<HH) ? h0f[(size_t)rr*HH+f] : (f<2*HH) ? h1f[(size_t)rr*HH + f-HH] : xcg[(size_t)rr*CVD + f-2*HH];
  ctx[idx] = (v - st1[f*2]) * st1[f*2+1] * g1[f] + bb1[f];
}

// ---------------- decoder pass 1: MFMA LSTM, merged phase (layer1(s)+layer0(s+1)) ----------------
__global__ __launch_bounds__(512, 2) void k_dec1m(
    const float* __restrict__ tpack, const float* __restrict__ ypack, const float* __restrict__ yT,
    const float* __restrict__ ctx,
    const unsigned short* __restrict__ wb2, const float* __restrict__ tb,
    const float* __restrict__ h0fi, const float* __restrict__ h1fi,
    const float* __restrict__ c0fi, const float* __restrict__ c1fi,
    __hip_bfloat16* __restrict__ h1n)
{
  __shared__ __align__(16) unsigned short CT[SMP*96];
  __shared__ __align__(16) unsigned short Hh0[2][SMP*HSTR2];
  __shared__ __align__(16) unsigned short Hh1[2][SMP*HSTR2];
  const int tid = threadIdx.x;
  const int l  = tid & 63, w = tid >> 6;          // 8 waves
  const int st = w & 3, ug = w >> 2;
  const int lr = l & 15, lq = l >> 4, l3 = l & 3;
  const int blk = blockIdx.x;

  for (int i = tid; i < SMP*HSTR2; i += 512){
    Hh0[0][i] = 0; Hh0[1][i] = 0; Hh1[0][i] = 0; Hh1[1][i] = 0;
  }
  for (int i = tid; i < SMP*96; i += 512) CT[i] = 0;
  __syncthreads();
  for (int i = tid; i < SMP*CTXD; i += 512){
    int r = i / CTXD, kk = i - r*CTXD;
    float v = ctx[((size_t)blk*SMP + r)*CTXD + kk];
    CT[r*96 + (((kk>>3) ^ (r&3))<<3) + (kk&7)] = f2b(v);
  }
  for (int i = tid; i < SMP*HH; i += 512){
    int r = i / HH, u2 = i - r*HH;
    Hh0[0][r*HSTR2 + u2] = f2b(h0fi[((size_t)blk*SMP + r)*HH + u2]);
    Hh1[0][r*HSTR2 + u2] = f2b(h1fi[((size_t)blk*SMP + r)*HH + u2]);
  }

  const int u  = ug*16 + lr;
  const int uc = u < HH ? u : HH-1;
  const int arow = st*16 + lr;
  const int aoff = arow*HSTR2 + lq*8;
  const int sbase = blk*SMP + st*16 + 4*lq;       // first of this lane's 4 samples

  float c0[4], c1[4], tt[4], yv[4];
  {
    float4 tv = *(const float4*)&tpack[sbase];
    float4 yv4 = *(const float4*)&ypack[sbase];
    tt[0]=tv.x; tt[1]=tv.y; tt[2]=tv.z; tt[3]=tv.w;
    yv[0]=yv4.x; yv[1]=yv4.y; yv[2]=yv4.z; yv[3]=yv4.w;
  }
  #pragma unroll
  for (int i=0;i<4;++i){
    c0[i] = c0fi[(size_t)(sbase+i)*HH + uc];
    c1[i] = c1fi[(size_t)(sbase+i)*HH + uc];
  }

  s8v B0[4], B10[4], B11[4], BC0[4], BC1[4], BC2[4];
  float bias0[4], bias1[4], wtt[4], wty[4];
  #pragma unroll
  for (int g=0; g<4; ++g){
    const int ct = g*2 + ug;
    const int col = ct*16 + lr;
    B0[g]  = *(const s8v*)(wb2 + ((size_t)(ct)*64 + l)*8);
    B10[g] = *(const s8v*)(wb2 + ((size_t)(8 + ct*2 + 0)*64 + l)*8);
    B11[g] = *(const s8v*)(wb2 + ((size_t)(8 + ct*2 + 1)*64 + l)*8);
    BC0[g] = *(const s8v*)(wb2 + ((size_t)(24 + ct*3 + 0)*64 + l)*8);
    BC1[g] = *(const s8v*)(wb2 + ((size_t)(24 + ct*3 + 1)*64 + l)*8);
    BC2[g] = *(const s8v*)(wb2 + ((size_t)(24 + ct*3 + 2)*64 + l)*8);
    bias0[g] = tb[col]; bias1[g] = tb[128+col];
    wtt[g] = tb[256+col]; wty[g] = tb[384+col];
  }
  __syncthreads();

  f4v pc[4];
  #pragma unroll
  for (int g=0; g<4; ++g){
    f4v a = {bias0[g], bias0[g], bias0[g], bias0[g]};
    {
      const s8v av = *(const s8v*)&CT[arow*96 + (((0*4+lq) ^ l3)<<3)];
      a = __builtin_amdgcn_mfma_f32_16x16x32_bf16(av, BC0[g], a, 0, 0, 0);
    }
    {
      const s8v av = *(const s8v*)&CT[arow*96 + (((1*4+lq) ^ l3)<<3)];
      a = __builtin_amdgcn_mfma_f32_16x16x32_bf16(av, BC1[g], a, 0, 0, 0);
    }
    {
      const s8v av = *(const s8v*)&CT[arow*96 + (((2*4+lq) ^ l3)<<3)];
      a = __builtin_amdgcn_mfma_f32_16x16x32_bf16(av, BC2[g], a, 0, 0, 0);
    }
    pc[g] = a;
  }

  const int wrow = (st*16 + 4*lq)*HSTR2 + u;
  unsigned short* h1s = reinterpret_cast<unsigned short*>(h1n);

  // ---- prologue: layer0(step 0). H0 state of step s lives in buffer (s+1)&1. ----
  {
    #pragma unroll
    for (int i=0;i<4;++i) tt[i] = fmodf(tt[i] + 15.f, 1440.f);
    const s8v a0 = *(const s8v*)&Hh0[0][aoff];
    f4v ac[4];
    #pragma unroll
    for (int g=0; g<4; ++g){
      f4v a = pc[g];
      #pragma unroll
      for (int i=0;i<4;++i) a[i] += tt[i]*wtt[g] + yv[i]*wty[g];
      ac[g] = __builtin_amdgcn_mfma_f32_16x16x32_bf16(a0, B0[g], a, 0, 0, 0);
    }
    #pragma unroll
    for (int i=0;i<4;++i){
      float iv = sg(ac[0][i]), fv = sg(ac[1][i]), gv = th(ac[2][i]), ov = sg(ac[3][i]);
      c0[i] = fv*c0[i] + iv*gv;
      if (u < HH) Hh0[1][wrow + i*HSTR2] = f2b(ov*th(c0[i]));
    }
    __syncthreads();
  }

  // ---- merged loop: per iteration { layer1(s) ; layer0(s+1) } then one barrier ----
  for (int s = 0; s < NOUT; ++s){
    const int b = (s+1)&1;
    const s8v a1 = *(const s8v*)&Hh0[b][aoff];      // h0 state after step s (shared by both layers)
    const s8v a2 = *(const s8v*)&Hh1[s&1][aoff];    // h1 state after step s-1
    f4v ac1[4];
    #pragma unroll
    for (int g=0; g<4; ++g){
      f4v a = {bias1[g], bias1[g], bias1[g], bias1[g]};
      a = __builtin_amdgcn_mfma_f32_16x16x32_bf16(a1, B10[g], a, 0, 0, 0);
      ac1[g] = __builtin_amdgcn_mfma_f32_16x16x32_bf16(a2, B11[g], a, 0, 0, 0);
    }
    const bool hasNext = (s < NOUT-1);
    f4v ac0[4];
    if (hasNext){
      #pragma unroll
      for (int i=0;i<4;++i) tt[i] = fmodf(tt[i] + 15.f, 1440.f);
      float4 yv4 = *(const float4*)&yT[(size_t)s*NB + sbase];   // teacher y for step s+1
      yv[0]=yv4.x; yv[1]=yv4.y; yv[2]=yv4.z; yv[3]=yv4.w;
      #pragma unroll
      for (int g=0; g<4; ++g){
        f4v a = pc[g];
        #pragma unroll
        for (int i=0;i<4;++i) a[i] += tt[i]*wtt[g] + yv[i]*wty[g];
        ac0[g] = __builtin_amdgcn_mfma_f32_16x16x32_bf16(a1, B0[g], a, 0, 0, 0);
      }
    }
    // layer1(s) activations + H1 write + h1n store
    unsigned short hw[4];
    #pragma unroll
    for (int i=0;i<4;++i){
      float iv = sg(ac1[0][i]), fv = sg(ac1[1][i]), gv = th(ac1[2][i]), ov = sg(ac1[3][i]);
      c1[i] = fv*c1[i] + iv*gv;
      hw[i] = f2b(ov*th(c1[i]));
    }
    if (u < HH){
      #pragma unroll
      for (int i=0;i<4;++i) Hh1[b][wrow + i*HSTR2] = hw[i];
      us4v pk = {hw[0], hw[1], hw[2], hw[3]};
      *reinterpret_cast<us4v*>(&h1s[((size_t)s*HH + u)*NB + sbase]) = pk;
    }
    // layer0(s+1) activations + H0 write into the retired buffer
    if (hasNext){
      #pragma unroll
      for (int i=0;i<4;++i){
        float iv = sg(ac0[0][i]), fv = sg(ac0[1][i]), gv = th(ac0[2][i]), ov = sg(ac0[3][i]);
        c0[i] = fv*c0[i] + iv*gv;
        if (u < HH) Hh0[s&1][wrow + i*HSTR2] = f2b(ov*th(c0[i]));
      }
    }
    __syncthreads();
  }
}

// ---------------- BN2 stats: contiguous-array reductions ----------------
__global__ __launch_bounds__(256) void k_bn2h(
    const __hip_bfloat16* __restrict__ h1n, double* __restrict__ s2)
{
  __shared__ double sd[256];
  __shared__ double qd[256];
  const int s = blockIdx.x, u = blockIdx.y;
  const unsigned short* p = (const unsigned short*)(h1n + ((size_t)s*HH + u)*NB);
  double sv = 0.0, sq = 0.0;
  #pragma unroll
  for (int c = 0; c < 8; ++c){
    s8v v = *(const s8v*)(p + ((size_t)c*256 + threadIdx.x)*8);
    #pragma unroll
    for (int j=0;j<8;++j){
      float f = b2f((unsigned short)v[j]);
      sv += f; sq += (double)f*(double)f;
    }
  }
  sd[threadIdx.x] = sv; qd[threadIdx.x] = sq;
  __syncthreads();
  for (int st2=128; st2>0; st2>>=1){
    if ((int)threadIdx.x < st2){
      sd[threadIdx.x] += sd[threadIdx.x+st2];
      qd[threadIdx.x] += qd[threadIdx.x+st2];
    }
    __syncthreads();
  }
  if (threadIdx.x == 0){
    s2[((size_t)s*F2 + u)*2]   = sd[0];
    s2[((size_t)s*F2 + u)*2+1] = qd[0];
  }
}

__global__ __launch_bounds__(256) void k_bn2y(
    const float* __restrict__ ypack, const float* __restrict__ yT, double* __restrict__ s2)
{
  __shared__ double sd[256];
  __shared__ double qd[256];
  const int s = blockIdx.x;
  const float* src = (s == 0) ? ypack : (yT + (size_t)(s-1)*NB);
  double sv = 0.0, sq = 0.0;
  #pragma unroll
  for (int c = 0; c < 16; ++c){
    float4 v = *(const float4*)(src + ((size_t)c*256 + threadIdx.x)*4);
    sv += (double)v.x + (double)v.y + (double)v.z + (double)v.w;
    sq += (double)v.x*v.x + (double)v.y*v.y + (double)v.z*v.z + (double)v.w*v.w;
  }
  sd[threadIdx.x] = sv; qd[threadIdx.x] = sq;
  __syncthreads();
  for (int st2=128; st2>0; st2>>=1){
    if ((int)threadIdx.x < st2){
      sd[threadIdx.x] += sd[threadIdx.x+st2];
      qd[threadIdx.x] += qd[threadIdx.x+st2];
    }
    __syncthreads();
  }
  if (threadIdx.x == 0){
    s2[((size_t)s*F2 + 51)*2]   = sd[0];
    s2[((size_t)s*F2 + 51)*2+1] = qd[0];
  }
}

__global__ __launch_bounds__(256) void k_bn2t(
    const float* __restrict__ tpack, double* __restrict__ s2)
{
  const int r = blockIdx.x*256 + threadIdx.x;
  float t = tpack[r];
  const int lane = threadIdx.x & 63;
  for (int s = 0; s < NOUT; ++s){
    t = fmodf(t + 15.f, 1440.f);
    double sv = (double)t, sq = (double)t*(double)t;
    #pragma unroll
    for (int m=32;m>0;m>>=1){ sv += shfl_xor_d(sv,m); sq += shfl_xor_d(sq,m); }
    if (lane == 0){
      atomicAdd(&s2[((size_t)s*F2 + 50)*2],   sv);
      atomicAdd(&s2[((size_t)s*F2 + 50)*2+1], sq);
    }
  }
}

__global__ __launch_bounds__(256) void k_fin2b(
    const double* __restrict__ s1, const double* __restrict__ s2,
    float* __restrict__ m2, float* __restrict__ r2)
{
  int i = blockIdx.x*256 + threadIdx.x;
  if (i >= NOUT*F2) return;
  int f = i % F2;
  double sv, sq;
  if (f >= HH && f < HH+CVD){
    sv = s1[(2*HH + (f-HH))*2];
    sq = s1[(2*HH + (f-HH))*2+1];
  } else {
    sv = s2[i*2]; sq = s2[i*2+1];
  }
  double m = sv/(double)NB;
  double var = sq/(double)NB - m*m;
  if (var < 0.0) var = 0.0;
  m2[i] = (float)m;
  r2[i] = (float)(1.0/sqrt(var + 1e-5));
}

// ---------------- readout: MFMA GEMM with split-A bf16 ----------------
__global__ __launch_bounds__(256, 4) void k_rdm(
    const __hip_bfloat16* __restrict__ h1n, const float* __restrict__ xcg,
    const float* __restrict__ tpack, const float* __restrict__ ypack, const float* __restrict__ yT,
    const float* __restrict__ m2, const float* __restrict__ r2,
    const float* __restrict__ g2, const float* __restrict__ b2v,
    const unsigned short* __restrict__ wd5, const float* __restrict__ Bd,
    const float* __restrict__ Ud, const float* __restrict__ Cd,
    float* __restrict__ outT)
{
  __shared__ __align__(16) unsigned short FH[64*64];
  __shared__ __align__(16) unsigned short FL[64*64];
  __shared__ float scl[F2], sft[F2];
  const int tid = threadIdx.x, l = tid & 63, w = tid >> 6;
  const int lr = l & 15, lq = l >> 4;
  const int s = blockIdx.y, rr0 = blockIdx.x*64;
  if (tid < F2){
    float m = m2[s*F2+tid], rv = r2[s*F2+tid];
    float sc = rv * g2[tid];
    scl[tid] = sc;
    sft[tid] = b2v[tid] - m*sc;
  }
  __syncthreads();
  for (int i = tid; i < 64*64; i += 256){
    int f = i >> 6, r = i & 63;
    float v;
    if (f < HH) v = __bfloat162float(h1n[((size_t)s*HH + f)*NB + rr0 + r]);
    else if (f < HH+CVD) v = xcg[(size_t)(rr0+r)*CVD + (f-HH)];
    else if (f == 50){
      float t0 = tpack[rr0+r];
      for (int k=0;k<=s;++k) t0 = fmodf(t0 + 15.f, 1440.f);
      v = t0;
    }
    else if (f == 51) v = (s==0) ? ypack[rr0+r] : yT[(size_t)(s-1)*NB + rr0 + r];
    else v = 0.f;
    if (f < F2) v = v*scl[f] + sft[f];
    unsigned short hi = f2b(v);
    float lo = v - b2f(hi);
    int off = r*64 + ((((f>>3) ^ (r&7))&7)<<3) + (f&7);
    FH[off] = hi;
    FL[off] = f2b(lo);
  }
  __syncthreads();
  const int row = w*16 + lr;
  s8v ah[2], al[2];
  #pragma unroll
  for (int ks=0;ks<2;++ks){
    int ch = ((ks*4+lq) ^ (row&7)) & 7;
    ah[ks] = *(const s8v*)&FH[row*64 + ch*8];
    al[ks] = *(const s8v*)&FL[row*64 + ch*8];
  }
  f4v ps = {0.f,0.f,0.f,0.f};
  #pragma unroll 7
  for (int ct=0; ct<7; ++ct){
    int col = ct*16 + lr;
    float bd = (col < HID) ? Bd[(size_t)s*HID + col] : 0.f;
    f4v acc = {bd,bd,bd,bd};
    #pragma unroll
    for (int ks=0;ks<2;++ks){
      s8v B = *(const s8v*)(wd5 + ((size_t)(s*14 + ks*7 + ct)*512) + l*8);
      acc = __builtin_amdgcn_mfma_f32_16x16x32_bf16(ah[ks], B, acc, 0, 0, 0);
      acc = __builtin_amdgcn_mfma_f32_16x16x32_bf16(al[ks], B, acc, 0, 0, 0);
    }
    float ud = (col < HID) ? Ud[(size_t)s*HID + col] : 0.f;
    #pragma unroll
    for (int i=0;i<4;++i) ps[i] += fmaxf(acc[i], 0.f) * ud;
  }
  #pragma unroll
  for (int m=1; m<16; m<<=1){
    #pragma unroll
    for (int i=0;i<4;++i) ps[i] += __shfl_xor(ps[i], m, 64);
  }
  if (lr == 0){
    float cd = Cd[s];
    float4 o = { ps[0]+cd, ps[1]+cd, ps[2]+cd, ps[3]+cd };
    *(float4*)&outT[(size_t)s*NB + rr0 + w*16 + lq*4] = o;
  }
}

// ---------------- host ----------------
extern "C" void kernel_launch(void* const* d_in, const int* in_sizes, int n_in,
                              void* d_out, int out_size, void* d_ws, size_t ws_size,
                              hipStream_t stream)
{
  const float* x    = (const float*)d_in[0];
  const float* y    = (const float*)d_in[1];
  const float* h0i  = (const float*)d_in[2];
  const float* c0i  = (const float*)d_in[3];
  const float* wih0 = (const float*)d_in[4];
  const float* whh0 = (const float*)d_in[5];
  const float* bih0 = (const float*)d_in[6];
  const float* bhh0 = (const float*)d_in[7];
  const float* wih1 = (const float*)d_in[8];
  const float* whh1 = (const float*)d_in[9];
  const float* bih1 = (const float*)d_in[10];
  const float* bhh1 = (const float*)d_in[11];
  const float* w2ih0= (const float*)d_in[12];
  const float* w2hh0= (const float*)d_in[13];
  const float* b2ih0= (const float*)d_in[14];
  const float* b2hh0= (const float*)d_in[15];
  const float* w2ih1= (const float*)d_in[16];
  const float* w2hh1= (const float*)d_in[17];
  const float* b2ih1= (const float*)d_in[18];
  const float* b2hh1= (const float*)d_in[19];
  const float* c1w  = (const float*)d_in[20];
  const float* c1b  = (const float*)d_in[21];
  const float* c2w  = (const float*)d_in[22];
  const float* c2b  = (const float*)d_in[23];
  const float* c3w  = (const float*)d_in[24];
  const float* c3b  = (const float*)d_in[25];
  const float* fcw  = (const float*)d_in[26];
  const float* fcb  = (const float*)d_in[27];
  const float* bn1g = (const float*)d_in[28];
  const float* bn1b = (const float*)d_in[29];
  const float* bn2g = (const float*)d_in[30];
  const float* bn2b = (const float*)d_in[31];
  const float* Wd   = (const float*)d_in[32];
  const float* Bd   = (const float*)d_in[33];
  const float* Ud   = (const float*)d_in[34];
  const float* Cd   = (const float*)d_in[35];
  float* out = (float*)d_out;

  char* base = (char*)d_ws;
  size_t off = 0;
  auto take = [&](size_t bytes)->char*{
    char* p = base + off;
    off = (off + bytes + 255) & ~(size_t)255;
    return p;
  };
  float*  h0f = (float*) take((size_t)NB*HH*sizeof(float));
  float*  h1f = (float*) take((size_t)NB*HH*sizeof(float));
  float*  c0f = (float*) take((size_t)NB*HH*sizeof(float));
  float*  c1f = (float*) take((size_t)NB*HH*sizeof(float));
  float*  xcg = (float*) take((size_t)NB*CVD*sizeof(float));
  float*  ctx = (float*) take((size_t)NB*CTXD*sizeof(float));
  double* s1  = (double*)take((size_t)CTXD*2*sizeof(double));
  float*  st1 = (float*) take((size_t)CTXD*2*sizeof(float));
  double* s2  = (double*)take((size_t)NOUT*F2*2*sizeof(double));
  float*  m2  = (float*) take((size_t)NOUT*F2*sizeof(float));
  float*  r2  = (float*) take((size_t)NOUT*F2*sizeof(float));
  unsigned short* wb2 = (unsigned short*) take((size_t)48*512*sizeof(unsigned short));
  float*  tb  = (float*) take((size_t)4*128*sizeof(float));
  unsigned short* wb3 = (unsigned short*) take((size_t)32*512*sizeof(unsigned short));
  float*  tbe = (float*) take((size_t)2*128*sizeof(float));
  unsigned short* wc  = (unsigned short*) take((size_t)96*512*sizeof(unsigned short));
  unsigned short* wd5 = (unsigned short*) take((size_t)NOUT*14*512*sizeof(unsigned short));
  float*  tpk = (float*) take((size_t)NB*sizeof(float));
  float*  ypk = (float*) take((size_t)NB*sizeof(float));
  float*  yT  = (float*) take((size_t)NOUT*NB*sizeof(float));
  float*  oT  = (float*) take((size_t)NOUT*NB*sizeof(float));
  __hip_bfloat16* h1n = (__hip_bfloat16*) take((size_t)NOUT*HH*NB*sizeof(__hip_bfloat16));
  (void)ws_size;

  k_tw2<<<dim3((48*512+512+255)/256), dim3(256), 0, stream>>>(w2ih0, w2hh0, w2ih1, w2hh1,
      b2ih0, b2hh0, b2ih1, b2hh1, wb2, tb);
  k_tw3<<<dim3((32*512+256+255)/256), dim3(256), 0, stream>>>(wih0, whh0, wih1, whh1,
      bih0, bhh0, bih1, bhh1, wb3, tbe);
  k_tw4<<<dim3((96*512+255)/256), dim3(256), 0, stream>>>(c1w, c2w, c3w, fcw, wc);
  k_tw5<<<dim3((NOUT*14*512+255)/256), dim3(256), 0, stream>>>(Wd, wd5);
  k_pack<<<dim3(NB/256), dim3(256), 0, stream>>>(x, tpk, ypk);
  k_ty<<<dim3(NB/64), dim3(256), 0, stream>>>(y, yT);
  k_zero<<<dim3((NOUT*F2*2+255)/256), dim3(256), 0, stream>>>(s1, s2);
  k_encm<<<dim3(NB/SMP), dim3(512), 0, stream>>>(x, h0i, c0i, wb3, tbe, h0f, h1f, c0f, c1f);
  k_convm<<<dim3(NB/16), dim3(256), 0, stream>>>(x, wc, c1b, c2b, c3b, fcb, xcg);
  k_bn1s<<<dim3(NB/128), dim3(128), 0, stream>>>(h0f, h1f, xcg, s1);
  k_fin1<<<dim3(1), dim3(128), 0, stream>>>(s1, st1);
  k_context<<<dim3((NB*CTXD + 255)/256), dim3(256), 0, stream>>>(h0f, h1f, xcg, st1, bn1g, bn1b, ctx);
  k_dec1m<<<dim3(NB/SMP), dim3(512), 0, stream>>>(tpk, ypk, yT, ctx, wb2, tb,
      h0f, h1f, c0f, c1f, h1n);
  k_bn2h<<<dim3(NOUT, HH), dim3(256), 0, stream>>>(h1n, s2);
  k_bn2y<<<dim3(NOUT), dim3(256), 0, stream>>>(ypk, yT, s2);
  k_bn2t<<<dim3(NB/256), dim3(256), 0, stream>>>(tpk, s2);
  k_fin2b<<<dim3((NOUT*F2+255)/256), dim3(256), 0, stream>>>(s1, s2, m2, r2);
  k_rdm<<<dim3(NB/64, NOUT), dim3(256), 0, stream>>>(h1n, xcg, tpk, ypk, yT,
      m2, r2, bn2g, bn2b, wd5, Bd, Ud, Cd, oT);
  k_tro<<<dim3(NB/64), dim3(256), 0, stream>>>(oT, out);
}

// Round 15
// 558.656 us; speedup vs baseline: 1.1682x; 1.0010x over previous
//
#include <hip/hip_runtime.h>
#include <hip/hip_bf16.h>

#define NB   16384
#define TT   50
#define HH   30
#define IND  8
#define CTXD 80
#define IN2  82
#define F2   52
#define NOUT 50
#define HID  100
#define CVD  20
#define SMP  64   // samples per LSTM block (8 waves)
#define HSTR2 40  // H row stride in shorts (80B: 16B-aligned, bank-quad-cycling)

typedef __attribute__((ext_vector_type(8))) short s8v;
typedef __attribute__((ext_vector_type(4))) float f4v;
typedef __attribute__((ext_vector_type(4))) unsigned short us4v;

__device__ __forceinline__ float sg(float x){
  return 1.f/(1.f+__expf(-x));
}
__device__ __forceinline__ float th(float x){
  x = fminf(x, 15.f);
  float e = __expf(2.f*x);
  return (e-1.f)/(e+1.f);
}
__device__ __forceinline__ unsigned short f2b(float f){
  __hip_bfloat16 h = __float2bfloat16(f);
  return *reinterpret_cast<unsigned short*>(&h);
}
__device__ __forceinline__ float b2f(unsigned short u){
  __hip_bfloat16 h;
  *reinterpret_cast<unsigned short*>(&h) = u;
  return __bfloat162float(h);
}
__device__ __forceinline__ double shfl_xor_d(double v, int m){
  long long ll = __double_as_longlong(v);
  int lo = (int)(ll & 0xffffffffLL), hi = (int)(ll >> 32);
  lo = __shfl_xor(lo, m, 64); hi = __shfl_xor(hi, m, 64);
  return __longlong_as_double(((long long)hi << 32) | (unsigned int)(unsigned)lo);
}

// ---------------- decoder MFMA fragment tables ----------------
__global__ void k_tw2(const float* __restrict__ w2ih0, const float* __restrict__ w2hh0,
                      const float* __restrict__ w2ih1, const float* __restrict__ w2hh1,
                      const float* __restrict__ b2ih0, const float* __restrict__ b2hh0,
                      const float* __restrict__ b2ih1, const float* __restrict__ b2hh1,
                      unsigned short* __restrict__ wb2, float* __restrict__ tb)
{
  int idx = blockIdx.x*256 + threadIdx.x;
  if (idx < 48*512){
    int f = idx >> 9, rem = idx & 511;
    int l = rem >> 3, j = rem & 7;
    int lr = l & 15, lq = l >> 4;
    float v = 0.f;
    if (f < 8){
      int ct = f, k = 8*lq + j, col = ct*16 + lr;
      int g = col>>5, u = col&31;
      if (k < HH && u < HH) v = w2hh0[(size_t)(g*HH+u)*HH + k];
    } else if (f < 24){
      int ct = (f-8)>>1, ks = (f-8)&1, k = 8*lq + j, col = ct*16 + lr;
      int g = col>>5, u = col&31;
      if (k < HH && u < HH) v = ks ? w2hh1[(size_t)(g*HH+u)*HH + k] : w2ih1[(size_t)(g*HH+u)*HH + k];
    } else {
      int ct = (f-24)/3, ks = (f-24)%3, k = ks*32 + 8*lq + j, col = ct*16 + lr;
      int g = col>>5, u = col&31;
      if (k < CTXD && u < HH) v = w2ih0[(size_t)(g*HH+u)*IN2 + k];
    }
    wb2[idx] = f2b(v);
  } else if (idx < 48*512 + 512){
    int t = idx - 48*512;
    int col = t & 127, sel = t >> 7;
    int g = col>>5, u = col&31;
    float v = 0.f;
    if (u < HH){
      int r = g*HH + u;
      if (sel == 0) v = b2ih0[r] + b2hh0[r];
      else if (sel == 1) v = b2ih1[r] + b2hh1[r];
      else if (sel == 2) v = w2ih0[(size_t)r*IN2 + 80];
      else v = w2ih0[(size_t)r*IN2 + 81];
    }
    tb[sel*128 + col] = v;
  }
}

// ---------------- encoder MFMA fragment tables ----------------
__global__ void k_tw3(const float* __restrict__ wih0, const float* __restrict__ whh0,
                      const float* __restrict__ wih1, const float* __restrict__ whh1,
                      const float* __restrict__ bih0, const float* __restrict__ bhh0,
                      const float* __restrict__ bih1, const float* __restrict__ bhh1,
                      unsigned short* __restrict__ wb3, float* __restrict__ tbe)
{
  int idx = blockIdx.x*256 + threadIdx.x;
  if (idx < 32*512){
    int f = idx >> 9, rem = idx & 511;
    int l = rem >> 3, j = rem & 7;
    int lr = l & 15, lq = l >> 4;
    int k = 8*lq + j;
    float v = 0.f;
    if (f < 8){
      int col = f*16 + lr; int g = col>>5, u = col&31;
      if (k < IND && u < HH) v = wih0[(size_t)(g*HH+u)*IND + k];
    } else if (f < 16){
      int ct = f-8; int col = ct*16 + lr; int g = col>>5, u = col&31;
      if (k < HH && u < HH) v = whh0[(size_t)(g*HH+u)*HH + k];
    } else {
      int ct = (f-16)>>1, ks = (f-16)&1; int col = ct*16 + lr; int g = col>>5, u = col&31;
      if (k < HH && u < HH) v = ks ? whh1[(size_t)(g*HH+u)*HH + k] : wih1[(size_t)(g*HH+u)*HH + k];
    }
    wb3[idx] = f2b(v);
  } else if (idx < 32*512 + 256){
    int t2 = idx - 32*512;
    int col = t2 & 127, sel = t2 >> 7;
    int g = col>>5, u = col&31;
    float v = 0.f;
    if (u < HH){
      int r = g*HH + u;
      v = sel ? (bih1[r] + bhh1[r]) : (bih0[r] + bhh0[r]);
    }
    tbe[sel*128 + col] = v;
  }
}

// ---------------- conv MFMA fragment tables ----------------
__global__ void k_tw4(const float* __restrict__ c1w, const float* __restrict__ c2w,
                      const float* __restrict__ c3w, const float* __restrict__ fcw,
                      unsigned short* __restrict__ wc)
{
  int idx = blockIdx.x*256 + threadIdx.x;
  if (idx >= 96*512) return;
  int f = idx >> 9, rem = idx & 511;
  int l = rem >> 3, j = rem & 7;
  int lr = l & 15, lq = l >> 4;
  int k = 8*lq + j;
  float v = 0.f;
  if (f < 4){
    int ks = f>>1, ct = f&1; int kk2 = ks*32 + k;
    if (kk2 < 40){ int kk = kk2>>3, ic = kk2&7; v = c1w[((size_t)(ct*16+lr)*8 + ic)*5 + kk]; }
  } else if (f < 16){
    int fi = f-4; int ks = fi>>2, ct = fi&3;
    v = c2w[((size_t)(ct*16+lr)*32 + k)*3 + ks];
  } else if (f < 64){
    int fi = f-16; int ks = fi>>3, ct = fi&7; int kk2 = ks*32 + k;
    int kk = kk2>>6, ic = kk2&63;
    v = c3w[((size_t)(ct*16+lr)*64 + ic)*3 + kk];
  } else {
    int fi = f-64; int ks = fi>>1, ct = fi&1; int kk2 = ks*32 + k;
    int p = kk2>>7, ocb = kk2&127;
    int n = ct*16 + lr;
    if (n < 20) v = fcw[(size_t)n*512 + ocb*4 + p];
  }
  wc[idx] = f2b(v);
}

// ---------------- readout Wd fragment table ----------------
__global__ void k_tw5(const float* __restrict__ Wd, unsigned short* __restrict__ wd5){
  int idx = blockIdx.x*256 + threadIdx.x;
  if (idx >= NOUT*14*512) return;
  int s = idx / (14*512), rem = idx - s*(14*512);
  int fi = rem >> 9, r2i = rem & 511;
  int l = r2i >> 3, j = r2i & 7;
  int lr = l & 15, lq = l >> 4;
  int ks = fi / 7, ct = fi - ks*7;
  int k = ks*32 + 8*lq + j, col = ct*16 + lr;
  float v = (k < F2 && col < HID) ? Wd[((size_t)s*F2 + k)*HID + col] : 0.f;
  wd5[idx] = f2b(v);
}

// ---------------- pack/transpose helpers ----------------
__global__ void k_pack(const float* __restrict__ x, float* __restrict__ tpack, float* __restrict__ ypack){
  int r = blockIdx.x*256 + threadIdx.x;
  if (r < NB){
    tpack[r] = x[(size_t)r*(TT*IND) + (TT-1)*IND + 7];
    ypack[r] = x[(size_t)r*(TT*IND) + (TT-1)*IND + 0];
  }
}

__global__ __launch_bounds__(256) void k_ty(const float* __restrict__ y, float* __restrict__ yT){
  __shared__ float tile[NOUT*65];
  int rr0 = blockIdx.x*64;
  for (int i=threadIdx.x; i<64*NOUT; i+=256){
    int r = i/NOUT, s = i - r*NOUT;
    tile[s*65 + r] = y[(size_t)(rr0+r)*NOUT + s];
  }
  __syncthreads();
  for (int i=threadIdx.x; i<64*NOUT; i+=256){
    int s = i>>6, r = i&63;
    yT[(size_t)s*NB + rr0 + r] = tile[s*65 + r];
  }
}

__global__ __launch_bounds__(256) void k_tro(const float* __restrict__ outT, float* __restrict__ out){
  __shared__ float tile[NOUT*65];
  int rr0 = blockIdx.x*64;
  for (int i=threadIdx.x; i<64*NOUT; i+=256){
    int s = i>>6, r = i&63;
    tile[s*65 + r] = outT[(size_t)s*NB + rr0 + r];
  }
  __syncthreads();
  for (int i=threadIdx.x; i<64*NOUT; i+=256){
    int r = i/NOUT, s = i - r*NOUT;
    out[(size_t)(rr0+r)*NOUT + s] = tile[s*65 + r];
  }
}

// ---------------- zero accumulators (s1 + s2) ----------------
__global__ void k_zero(double* s1, double* s2){
  int i = blockIdx.x*256 + threadIdx.x;
  if (i < CTXD*2) s1[i] = 0.0;
  if (i < NOUT*F2*2) s2[i] = 0.0;
}

// ---------------- encoder: MFMA LSTM, 64 samples / 8 waves, merged phase ----------------
// per iteration t: { layer1(t) ; layer0(t+1) } then one barrier.
// H0 state after step s lives in buffer (s+1)&1; H1 state after step s in buffer (s+1)&1.
__global__ __launch_bounds__(512, 2) void k_encm(
    const float* __restrict__ x, const float* __restrict__ h0i, const float* __restrict__ c0i,
    const unsigned short* __restrict__ wb3, const float* __restrict__ tbe,
    float* __restrict__ h0f, float* __restrict__ h1f,
    float* __restrict__ c0f, float* __restrict__ c1f)
{
  __shared__ __align__(16) unsigned short XS[TT*SMP*8];
  __shared__ __align__(16) unsigned short H0[2][SMP*HSTR2];
  __shared__ __align__(16) unsigned short H1[2][SMP*HSTR2];
  const int tid = threadIdx.x;
  const int l = tid & 63, w = tid >> 6;           // 8 waves
  const int st = w & 3, ug = w >> 2;
  const int lr = l & 15, lq = l >> 4;
  const int blk = blockIdx.x;

  for (int i = tid; i < SMP*HSTR2; i += 512){
    H0[0][i]=0; H0[1][i]=0; H1[0][i]=0; H1[1][i]=0;
  }
  for (int i = tid; i < SMP*100; i += 512){
    int smp = i/100, q = i - smp*100;
    float4 v = ((const float4*)(x + (size_t)(blk*SMP+smp)*(TT*IND)))[q];
    int t = q>>1, d = (q&1)*4;
    unsigned short* p = &XS[t*(SMP*8) + smp*8 + d];
    p[0]=f2b(v.x); p[1]=f2b(v.y); p[2]=f2b(v.z); p[3]=f2b(v.w);
  }
  __syncthreads();
  for (int i = tid; i < SMP*HH; i += 512){
    int r = i/HH, u2 = i - r*HH;
    H0[0][r*HSTR2 + u2] = f2b(h0i[u2]);
    H1[0][r*HSTR2 + u2] = f2b(h0i[HH+u2]);
  }

  const int u  = ug*16 + lr;
  const int uc = u < HH ? u : HH-1;
  const int arow = st*16 + lr;
  const int aoff = arow*HSTR2 + lq*8;
  float c0[4], c1[4];
  #pragma unroll
  for (int i=0;i<4;++i){
    c0[i] = c0i[uc];
    c1[i] = c0i[HH+uc];
  }
  s8v BX[4], BH[4], B10[4], B11[4];
  float b0v[4], b1v[4];
  #pragma unroll
  for (int g=0; g<4; ++g){
    const int ct = g*2 + ug;
    const int col = ct*16 + lr;
    BX[g]  = *(const s8v*)(wb3 + ((size_t)(ct)*64 + l)*8);
    BH[g]  = *(const s8v*)(wb3 + ((size_t)(8 + ct)*64 + l)*8);
    B10[g] = *(const s8v*)(wb3 + ((size_t)(16 + ct*2 + 0)*64 + l)*8);
    B11[g] = *(const s8v*)(wb3 + ((size_t)(16 + ct*2 + 1)*64 + l)*8);
    b0v[g] = tbe[col]; b1v[g] = tbe[128+col];
  }
  __syncthreads();

  const int wrow = (st*16 + 4*lq)*HSTR2 + u;   // base of 4 consecutive sample rows

  // ---- prologue: layer0(t=0) ----
  {
    s8v ax = {0,0,0,0,0,0,0,0};
    if (lq == 0) ax = *(const s8v*)&XS[0*(SMP*8) + arow*8];
    const s8v ah = *(const s8v*)&H0[0][aoff];
    f4v ac[4];
    #pragma unroll
    for (int g=0; g<4; ++g){
      f4v a = {b0v[g], b0v[g], b0v[g], b0v[g]};
      a = __builtin_amdgcn_mfma_f32_16x16x32_bf16(ax, BX[g], a, 0, 0, 0);
      ac[g] = __builtin_amdgcn_mfma_f32_16x16x32_bf16(ah, BH[g], a, 0, 0, 0);
    }
    #pragma unroll
    for (int i=0;i<4;++i){
      float iv = sg(ac[0][i]), fv = sg(ac[1][i]), gv = th(ac[2][i]), ov = sg(ac[3][i]);
      c0[i] = fv*c0[i] + iv*gv;
      if (u < HH) H0[1][wrow + i*HSTR2] = f2b(ov*th(c0[i]));
    }
    __syncthreads();
  }

  // ---- merged loop ----
  for (int t=0; t<TT; ++t){
    const int b = (t+1)&1;
    const s8v a1 = *(const s8v*)&H0[b][aoff];     // h0 after step t
    const s8v a2 = *(const s8v*)&H1[t&1][aoff];   // h1 after step t-1
    f4v ac1[4];
    #pragma unroll
    for (int g=0; g<4; ++g){
      f4v a = {b1v[g], b1v[g], b1v[g], b1v[g]};
      a = __builtin_amdgcn_mfma_f32_16x16x32_bf16(a1, B10[g], a, 0, 0, 0);
      ac1[g] = __builtin_amdgcn_mfma_f32_16x16x32_bf16(a2, B11[g], a, 0, 0, 0);
    }
    const bool hasNext = (t < TT-1);
    f4v ac0[4];
    if (hasNext){
      s8v ax = {0,0,0,0,0,0,0,0};
      if (lq == 0) ax = *(const s8v*)&XS[(t+1)*(SMP*8) + arow*8];
      #pragma unroll
      for (int g=0; g<4; ++g){
        f4v a = {b0v[g], b0v[g], b0v[g], b0v[g]};
        a = __builtin_amdgcn_mfma_f32_16x16x32_bf16(ax, BX[g], a, 0, 0, 0);
        ac0[g] = __builtin_amdgcn_mfma_f32_16x16x32_bf16(a1, BH[g], a, 0, 0, 0);
      }
    }
    #pragma unroll
    for (int i=0;i<4;++i){
      float iv = sg(ac1[0][i]), fv = sg(ac1[1][i]), gv = th(ac1[2][i]), ov = sg(ac1[3][i]);
      c1[i] = fv*c1[i] + iv*gv;
      if (u < HH) H1[b][wrow + i*HSTR2] = f2b(ov*th(c1[i]));
    }
    if (hasNext){
      #pragma unroll
      for (int i=0;i<4;++i){
        float iv = sg(ac0[0][i]), fv = sg(ac0[1][i]), gv = th(ac0[2][i]), ov = sg(ac0[3][i]);
        c0[i] = fv*c0[i] + iv*gv;
        if (u < HH) H0[t&1][wrow + i*HSTR2] = f2b(ov*th(c0[i]));
      }
    }
    __syncthreads();
  }
  // TT even: final H0 state in buffer (TT)&1 == 0, final H1 state in buffer 0
  for (int i2 = tid; i2 < SMP*HH; i2 += 512){
    int sl = i2 / HH, uu = i2 - sl*HH;
    h0f[((size_t)blk*SMP + sl)*HH + uu] = b2f(H0[0][sl*HSTR2 + uu]);
    h1f[((size_t)blk*SMP + sl)*HH + uu] = b2f(H1[0][sl*HSTR2 + uu]);
  }
  if (u < HH){
    #pragma unroll
    for (int i=0;i<4;++i){
      int gS = blk*SMP + st*16 + 4*lq + i;
      c0f[(size_t)gS*HH + u] = c0[i];
      c1f[(size_t)gS*HH + u] = c1[i];
    }
  }
}

// ---------------- conv path: MFMA ----------------
__global__ __launch_bounds__(256, 2) void k_convm(
    const float* __restrict__ x, const unsigned short* __restrict__ wc,
    const float* __restrict__ b1, const float* __restrict__ b2,
    const float* __restrict__ b3, const float* __restrict__ fb,
    float* __restrict__ xcg)
{
  __shared__ __align__(16) unsigned short XT[16*52*8];
  __shared__ __align__(16) unsigned short P1[16*26*32];
  __shared__ __align__(16) unsigned short P2[16*10*64];
  __shared__ __align__(16) unsigned short P3[16*4*128];
  const int tid = threadIdx.x, l = tid & 63, w = tid >> 6;
  const int lr = l & 15, lq = l >> 4;
  const int blk = blockIdx.x;
  for (int i=tid; i<16*16; i+=256){ int s=i>>4, q=i&15; XT[s*416 + 400 + q] = 0; }
  for (int i=tid; i<16*96; i+=256){ int s=i/96, q=i - (i/96)*96; P1[s*832 + 736 + q] = 0; }
  for (int i=tid; i<1600; i+=256){
    int s = i/100, q = i - s*100;
    float4 v = ((const float4*)(x + (size_t)(blk*16+s)*400))[q];
    int t = q>>1, d = (q&1)*4;
    unsigned short* p = &XT[s*416 + t*8 + d];
    p[0]=f2b(v.x); p[1]=f2b(v.y); p[2]=f2b(v.z); p[3]=f2b(v.w);
  }
  __syncthreads();
  {
    s8v B[2][2];
    #pragma unroll
    for (int ks=0;ks<2;++ks)
      #pragma unroll
      for (int ct=0;ct<2;++ct)
        B[ks][ct] = *(const s8v*)(wc + ((size_t)(ks*2+ct)*512) + l*8);
    float bv[2] = { b1[lr], b1[16+lr] };
    for (int t5=w; t5<48; t5+=4){
      int row = t5*16 + lr, s = row/48, pos = row - s*48;
      s8v a0 = *(const s8v*)&XT[s*416 + (pos+lq)*8];
      s8v a1 = {0,0,0,0,0,0,0,0};
      if (lq == 0) a1 = *(const s8v*)&XT[s*416 + (pos+4)*8];
      int rb = t5*16 + 4*lq, s2 = rb/48, pp = rb - s2*48;
      #pragma unroll
      for (int ct=0;ct<2;++ct){
        f4v acc = {bv[ct],bv[ct],bv[ct],bv[ct]};
        acc = __builtin_amdgcn_mfma_f32_16x16x32_bf16(a0, B[0][ct], acc, 0, 0, 0);
        acc = __builtin_amdgcn_mfma_f32_16x16x32_bf16(a1, B[1][ct], acc, 0, 0, 0);
        int oc = ct*16 + lr;
        #pragma unroll
        for (int pr=0;pr<2;++pr){
          int pos2 = (pp>>1) + pr;
          if (pos2 < 23){
            float v = fmaxf(fmaxf(acc[2*pr],0.f), fmaxf(acc[2*pr+1],0.f));
            int ch = (oc>>3) ^ (pos2&3);
            P1[s2*832 + pos2*32 + ch*8 + (oc&7)] = f2b(v);
          }
        }
      }
    }
  }
  __syncthreads();
  {
    s8v B[3][4];
    #pragma unroll
    for (int ks=0;ks<3;++ks)
      #pragma unroll
      for (int ct=0;ct<4;++ct)
        B[ks][ct] = *(const s8v*)(wc + ((size_t)(4+ks*4+ct)*512) + l*8);
    float bv[4] = { b2[lr], b2[16+lr], b2[32+lr], b2[48+lr] };
    for (int t6=w; t6<24; t6+=4){
      int row = t6*16 + lr, s = row/24, pos = row - s*24;
      s8v a[3];
      #pragma unroll
      for (int ks=0;ks<3;++ks){
        int pr = pos + ks, ch = lq ^ (pr&3);
        a[ks] = *(const s8v*)&P1[s*832 + pr*32 + ch*8];
      }
      int rb = t6*16 + 4*lq, s2 = rb/24, pp = rb - s2*24;
      #pragma unroll
      for (int ct=0;ct<4;++ct){
        f4v acc = {bv[ct],bv[ct],bv[ct],bv[ct]};
        #pragma unroll
        for (int ks=0;ks<3;++ks)
          acc = __builtin_amdgcn_mfma_f32_16x16x32_bf16(a[ks], B[ks][ct], acc, 0, 0, 0);
        int oc = ct*16 + lr;
        #pragma unroll
        for (int pr=0;pr<2;++pr){
          int pos2 = (pp>>1) + pr;
          if (pos2 < 10){
            float v = fmaxf(fmaxf(acc[2*pr],0.f), fmaxf(acc[2*pr+1],0.f));
            int ch = (oc>>3) ^ (pos2&7);
            P2[s2*640 + pos2*64 + ch*8 + (oc&7)] = f2b(v);
          }
        }
      }
    }
  }
  __syncthreads();
  {
    s8v A[2][6]; int sS[2], ppS[2];
    #pragma unroll
    for (int tt=0;tt<2;++tt){
      int t7 = w*2 + tt;
      int row = t7*16 + lr, s = row>>3, pos = row&7;
      #pragma unroll
      for (int ks=0;ks<6;++ks){
        int pr = pos + (ks>>1);
        int cb = 4*(ks&1) + lq;
        int ch = cb ^ (pr&7);
        A[tt][ks] = *(const s8v*)&P2[s*640 + pr*64 + ch*8];
      }
      int rb = t7*16 + 4*lq;
      sS[tt] = rb>>3; ppS[tt] = rb&7;
    }
    for (int ct=0;ct<8;++ct){
      s8v B[6];
      #pragma unroll
      for (int ks=0;ks<6;++ks)
        B[ks] = *(const s8v*)(wc + ((size_t)(16+ks*8+ct)*512) + l*8);
      int oc = ct*16 + lr;
      float bb = b3[oc];
      #pragma unroll
      for (int tt=0;tt<2;++tt){
        f4v acc = {bb,bb,bb,bb};
        #pragma unroll
        for (int ks=0;ks<6;++ks)
          acc = __builtin_amdgcn_mfma_f32_16x16x32_bf16(A[tt][ks], B[ks], acc, 0, 0, 0);
        #pragma unroll
        for (int pr=0;pr<2;++pr){
          int pos2 = (ppS[tt]>>1) + pr;
          float v = fmaxf(fmaxf(acc[2*pr],0.f), fmaxf(acc[2*pr+1],0.f));
          int flat = pos2*128 + oc;
          int ch = (flat>>3) ^ (sS[tt]&7);
          P3[sS[tt]*512 + ch*8 + (oc&7)] = f2b(v);
        }
      }
    }
  }
  __syncthreads();
  if (w == 0){
    f4v acc[2];
    float fb0 = fb[lr];
    float fb1 = (lr < 4) ? fb[16+lr] : 0.f;
    acc[0] = (f4v){fb0,fb0,fb0,fb0};
    acc[1] = (f4v){fb1,fb1,fb1,fb1};
    for (int ks=0;ks<16;++ks){
      int k0 = ks*32 + 8*lq;
      int ch = (k0>>3) ^ (lr&7);
      s8v a = *(const s8v*)&P3[lr*512 + ch*8];
      #pragma unroll
      for (int ct=0;ct<2;++ct){
        s8v Bf = *(const s8v*)(wc + ((size_t)(64+ks*2+ct)*512) + l*8);
        acc[ct] = __builtin_amdgcn_mfma_f32_16x16x32_bf16(a, Bf, acc[ct], 0, 0, 0);
      }
    }
    #pragma unroll
    for (int ct=0;ct<2;++ct){
      int oc = ct*16 + lr;
      if (oc < 20){
        #pragma unroll
        for (int i=0;i<4;++i){
          int smp = 4*lq + i;
          xcg[(size_t)(blk*16+smp)*CVD + oc] = fmaxf(acc[ct][i], 0.f);
        }
      }
    }
  }
}

// ---------------- BN1 stats ----------------
__global__ __launch_bounds__(128) void k_bn1s(const float* __restrict__ h0f, const float* __restrict__ h1f,
    const float* __restrict__ xcg, double* __restrict__ s1)
{
  int f = threadIdx.x;
  if (f >= CTXD) return;
  int r0 = blockIdx.x*128;
  double s=0.0, q=0.0;
  for (int i=0;i<128;++i){
    int r = r0+i;
    float v = (f<HH) ? h0f[(size_t)r*HH+f] : (f<2*HH) ? h1f[(size_t)r*HH + f-HH] : xcg[(size_t)r*CVD + f-2*HH];
    s += (double)v; q += (double)v*(double)v;
  }
  atomicAdd(&s1[f*2],   s);
  atomicAdd(&s1[f*2+1], q);
}

__global__ void k_fin1(const double* __restrict__ s1, float* __restrict__ st1){
  int f = threadIdx.x;
  if (f >= CTXD) return;
  double m = s1[f*2]/(double)NB;
  double var = s1[f*2+1]/(double)NB - m*m;
  if (var < 0.0) var = 0.0;
  st1[f*2]   = (float)m;
  st1[f*2+1] = (float)(1.0/sqrt(var + 1e-5));
}

__global__ __launch_bounds__(256) void k_context(const float* __restrict__ h0f, const float* __restrict__ h1f,
    const float* __restrict__ xcg, const float* __restrict__ st1,
    const float* __restrict__ g1, const float* __restrict__ bb1, float* __restrict__ ctx)
{
  int idx = blockIdx.x*256 + threadIdx.x;
  if (idx >= NB*CTXD) return;
  int rr = idx / CTXD, f = idx - rr*CTXD;
  float v = (f<HH) ? h0f[(size_t)rr*HH+f] : (f<2*HH) ? h1f[(size_t)rr*HH + f-HH] : xcg[(size_t)rr*CVD + f-2*HH];
  ctx[idx] = (v - st1[f*2]) * st1[f*2+1] * g1[f] + bb1[f];
}

// ---------------- decoder pass 1: MFMA LSTM, merged phase + batched h1n stores ----------------
__global__ __launch_bounds__(512, 2) void k_dec1m(
    const float* __restrict__ tpack, const float* __restrict__ ypack, const float* __restrict__ yT,
    const float* __restrict__ ctx,
    const unsigned short* __restrict__ wb2, const float* __restrict__ tb,
    const float* __restrict__ h0fi, const float* __restrict__ h1fi,
    const float* __restrict__ c0fi, const float* __restrict__ c1fi,
    __hip_bfloat16* __restrict__ h1n)
{
  __shared__ __align__(16) unsigned short CT[SMP*96];
  __shared__ __align__(16) unsigned short Hh0[2][SMP*HSTR2];
  __shared__ __align__(16) unsigned short Hh1[2][SMP*HSTR2];
  const int tid = threadIdx.x;
  const int l  = tid & 63, w = tid >> 6;          // 8 waves
  const int st = w & 3, ug = w >> 2;
  const int lr = l & 15, lq = l >> 4, l3 = l & 3;
  const int blk = blockIdx.x;

  for (int i = tid; i < SMP*HSTR2; i += 512){
    Hh0[0][i] = 0; Hh0[1][i] = 0; Hh1[0][i] = 0; Hh1[1][i] = 0;
  }
  for (int i = tid; i < SMP*96; i += 512) CT[i] = 0;
  __syncthreads();
  for (int i = tid; i < SMP*CTXD; i += 512){
    int r = i / CTXD, kk = i - r*CTXD;
    float v = ctx[((size_t)blk*SMP + r)*CTXD + kk];
    CT[r*96 + (((kk>>3) ^ (r&3))<<3) + (kk&7)] = f2b(v);
  }
  for (int i = tid; i < SMP*HH; i += 512){
    int r = i / HH, u2 = i - r*HH;
    Hh0[0][r*HSTR2 + u2] = f2b(h0fi[((size_t)blk*SMP + r)*HH + u2]);
    Hh1[0][r*HSTR2 + u2] = f2b(h1fi[((size_t)blk*SMP + r)*HH + u2]);
  }

  const int u  = ug*16 + lr;
  const int uc = u < HH ? u : HH-1;
  const int arow = st*16 + lr;
  const int aoff = arow*HSTR2 + lq*8;
  const int sbase = blk*SMP + st*16 + 4*lq;       // first of this lane's 4 samples

  float c0[4], c1[4], tt[4], yv[4];
  {
    float4 tv = *(const float4*)&tpack[sbase];
    float4 yv4 = *(const float4*)&ypack[sbase];
    tt[0]=tv.x; tt[1]=tv.y; tt[2]=tv.z; tt[3]=tv.w;
    yv[0]=yv4.x; yv[1]=yv4.y; yv[2]=yv4.z; yv[3]=yv4.w;
  }
  #pragma unroll
  for (int i=0;i<4;++i){
    c0[i] = c0fi[(size_t)(sbase+i)*HH + uc];
    c1[i] = c1fi[(size_t)(sbase+i)*HH + uc];
  }

  s8v B0[4], B10[4], B11[4], BC0[4], BC1[4], BC2[4];
  float bias0[4], bias1[4], wtt[4], wty[4];
  #pragma unroll
  for (int g=0; g<4; ++g){
    const int ct = g*2 + ug;
    const int col = ct*16 + lr;
    B0[g]  = *(const s8v*)(wb2 + ((size_t)(ct)*64 + l)*8);
    B10[g] = *(const s8v*)(wb2 + ((size_t)(8 + ct*2 + 0)*64 + l)*8);
    B11[g] = *(const s8v*)(wb2 + ((size_t)(8 + ct*2 + 1)*64 + l)*8);
    BC0[g] = *(const s8v*)(wb2 + ((size_t)(24 + ct*3 + 0)*64 + l)*8);
    BC1[g] = *(const s8v*)(wb2 + ((size_t)(24 + ct*3 + 1)*64 + l)*8);
    BC2[g] = *(const s8v*)(wb2 + ((size_t)(24 + ct*3 + 2)*64 + l)*8);
    bias0[g] = tb[col]; bias1[g] = tb[128+col];
    wtt[g] = tb[256+col]; wty[g] = tb[384+col];
  }
  __syncthreads();

  f4v pc[4];
  #pragma unroll
  for (int g=0; g<4; ++g){
    f4v a = {bias0[g], bias0[g], bias0[g], bias0[g]};
    {
      const s8v av = *(const s8v*)&CT[arow*96 + (((0*4+lq) ^ l3)<<3)];
      a = __builtin_amdgcn_mfma_f32_16x16x32_bf16(av, BC0[g], a, 0, 0, 0);
    }
    {
      const s8v av = *(const s8v*)&CT[arow*96 + (((1*4+lq) ^ l3)<<3)];
      a = __builtin_amdgcn_mfma_f32_16x16x32_bf16(av, BC1[g], a, 0, 0, 0);
    }
    {
      const s8v av = *(const s8v*)&CT[arow*96 + (((2*4+lq) ^ l3)<<3)];
      a = __builtin_amdgcn_mfma_f32_16x16x32_bf16(av, BC2[g], a, 0, 0, 0);
    }
    pc[g] = a;
  }

  const int wrow = (st*16 + 4*lq)*HSTR2 + u;
  unsigned short* h1s = reinterpret_cast<unsigned short*>(h1n);

  // ---- prologue: layer0(step 0). H0 state of step s lives in buffer (s+1)&1. ----
  {
    #pragma unroll
    for (int i=0;i<4;++i) tt[i] = fmodf(tt[i] + 15.f, 1440.f);
    const s8v a0 = *(const s8v*)&Hh0[0][aoff];
    f4v ac[4];
    #pragma unroll
    for (int g=0; g<4; ++g){
      f4v a = pc[g];
      #pragma unroll
      for (int i=0;i<4;++i) a[i] += tt[i]*wtt[g] + yv[i]*wty[g];
      ac[g] = __builtin_amdgcn_mfma_f32_16x16x32_bf16(a0, B0[g], a, 0, 0, 0);
    }
    #pragma unroll
    for (int i=0;i<4;++i){
      float iv = sg(ac[0][i]), fv = sg(ac[1][i]), gv = th(ac[2][i]), ov = sg(ac[3][i]);
      c0[i] = fv*c0[i] + iv*gv;
      if (u < HH) Hh0[1][wrow + i*HSTR2] = f2b(ov*th(c0[i]));
    }
    __syncthreads();
  }

  // ---- merged loop: per iteration { layer1(s) ; layer0(s+1) } then one barrier ----
  us4v pend;
  for (int s = 0; s < NOUT; ++s){
    const int b = (s+1)&1;
    const s8v a1 = *(const s8v*)&Hh0[b][aoff];      // h0 state after step s (shared by both layers)
    const s8v a2 = *(const s8v*)&Hh1[s&1][aoff];    // h1 state after step s-1
    f4v ac1[4];
    #pragma unroll
    for (int g=0; g<4; ++g){
      f4v a = {bias1[g], bias1[g], bias1[g], bias1[g]};
      a = __builtin_amdgcn_mfma_f32_16x16x32_bf16(a1, B10[g], a, 0, 0, 0);
      ac1[g] = __builtin_amdgcn_mfma_f32_16x16x32_bf16(a2, B11[g], a, 0, 0, 0);
    }
    const bool hasNext = (s < NOUT-1);
    f4v ac0[4];
    if (hasNext){
      #pragma unroll
      for (int i=0;i<4;++i) tt[i] = fmodf(tt[i] + 15.f, 1440.f);
      float4 yv4 = *(const float4*)&yT[(size_t)s*NB + sbase];   // teacher y for step s+1
      yv[0]=yv4.x; yv[1]=yv4.y; yv[2]=yv4.z; yv[3]=yv4.w;
      #pragma unroll
      for (int g=0; g<4; ++g){
        f4v a = pc[g];
        #pragma unroll
        for (int i=0;i<4;++i) a[i] += tt[i]*wtt[g] + yv[i]*wty[g];
        ac0[g] = __builtin_amdgcn_mfma_f32_16x16x32_bf16(a1, B0[g], a, 0, 0, 0);
      }
    }
    // layer1(s) activations + H1 write + batched h1n store (issue globals every 2nd step)
    unsigned short hw[4];
    #pragma unroll
    for (int i=0;i<4;++i){
      float iv = sg(ac1[0][i]), fv = sg(ac1[1][i]), gv = th(ac1[2][i]), ov = sg(ac1[3][i]);
      c1[i] = fv*c1[i] + iv*gv;
      hw[i] = f2b(ov*th(c1[i]));
    }
    if (u < HH){
      #pragma unroll
      for (int i=0;i<4;++i) Hh1[b][wrow + i*HSTR2] = hw[i];
    }
    us4v pk = {hw[0], hw[1], hw[2], hw[3]};
    if (s & 1){
      if (u < HH){
        *reinterpret_cast<us4v*>(&h1s[((size_t)(s-1)*HH + u)*NB + sbase]) = pend;
        *reinterpret_cast<us4v*>(&h1s[((size_t)s*HH + u)*NB + sbase]) = pk;
      }
    } else {
      pend = pk;
    }
    // layer0(s+1) activations + H0 write into the retired buffer
    if (hasNext){
      #pragma unroll
      for (int i=0;i<4;++i){
        float iv = sg(ac0[0][i]), fv = sg(ac0[1][i]), gv = th(ac0[2][i]), ov = sg(ac0[3][i]);
        c0[i] = fv*c0[i] + iv*gv;
        if (u < HH) Hh0[s&1][wrow + i*HSTR2] = f2b(ov*th(c0[i]));
      }
    }
    __syncthreads();
  }
}

// ---------------- BN2 stats: contiguous-array reductions ----------------
__global__ __launch_bounds__(256) void k_bn2h(
    const __hip_bfloat16* __restrict__ h1n, double* __restrict__ s2)
{
  __shared__ double sd[256];
  __shared__ double qd[256];
  const int s = blockIdx.x, u = blockIdx.y;
  const unsigned short* p = (const unsigned short*)(h1n + ((size_t)s*HH + u)*NB);
  double sv = 0.0, sq = 0.0;
  #pragma unroll
  for (int c = 0; c < 8; ++c){
    s8v v = *(const s8v*)(p + ((size_t)c*256 + threadIdx.x)*8);
    #pragma unroll
    for (int j=0;j<8;++j){
      float f = b2f((unsigned short)v[j]);
      sv += f; sq += (double)f*(double)f;
    }
  }
  sd[threadIdx.x] = sv; qd[threadIdx.x] = sq;
  __syncthreads();
  for (int st2=128; st2>0; st2>>=1){
    if ((int)threadIdx.x < st2){
      sd[threadIdx.x] += sd[threadIdx.x+st2];
      qd[threadIdx.x] += qd[threadIdx.x+st2];
    }
    __syncthreads();
  }
  if (threadIdx.x == 0){
    s2[((size_t)s*F2 + u)*2]   = sd[0];
    s2[((size_t)s*F2 + u)*2+1] = qd[0];
  }
}

__global__ __launch_bounds__(256) void k_bn2y(
    const float* __restrict__ ypack, const float* __restrict__ yT, double* __restrict__ s2)
{
  __shared__ double sd[256];
  __shared__ double qd[256];
  const int s = blockIdx.x;
  const float* src = (s == 0) ? ypack : (yT + (size_t)(s-1)*NB);
  double sv = 0.0, sq = 0.0;
  #pragma unroll
  for (int c = 0; c < 16; ++c){
    float4 v = *(const float4*)(src + ((size_t)c*256 + threadIdx.x)*4);
    sv += (double)v.x + (double)v.y + (double)v.z + (double)v.w;
    sq += (double)v.x*v.x + (double)v.y*v.y + (double)v.z*v.z + (double)v.w*v.w;
  }
  sd[threadIdx.x] = sv; qd[threadIdx.x] = sq;
  __syncthreads();
  for (int st2=128; st2>0; st2>>=1){
    if ((int)threadIdx.x < st2){
      sd[threadIdx.x] += sd[threadIdx.x+st2];
      qd[threadIdx.x] += qd[threadIdx.x+st2];
    }
    __syncthreads();
  }
  if (threadIdx.x == 0){
    s2[((size_t)s*F2 + 51)*2]   = sd[0];
    s2[((size_t)s*F2 + 51)*2+1] = qd[0];
  }
}

__global__ __launch_bounds__(256) void k_bn2t(
    const float* __restrict__ tpack, double* __restrict__ s2)
{
  const int r = blockIdx.x*256 + threadIdx.x;
  float t = tpack[r];
  const int lane = threadIdx.x & 63;
  for (int s = 0; s < NOUT; ++s){
    t = fmodf(t + 15.f, 1440.f);
    double sv = (double)t, sq = (double)t*(double)t;
    #pragma unroll
    for (int m=32;m>0;m>>=1){ sv += shfl_xor_d(sv,m); sq += shfl_xor_d(sq,m); }
    if (lane == 0){
      atomicAdd(&s2[((size_t)s*F2 + 50)*2],   sv);
      atomicAdd(&s2[((size_t)s*F2 + 50)*2+1], sq);
    }
  }
}

__global__ __launch_bounds__(256) void k_fin2b(
    const double* __restrict__ s1, const double* __restrict__ s2,
    float* __restrict__ m2, float* __restrict__ r2)
{
  int i = blockIdx.x*256 + threadIdx.x;
  if (i >= NOUT*F2) return;
  int f = i % F2;
  double sv, sq;
  if (f >= HH && f < HH+CVD){
    sv = s1[(2*HH + (f-HH))*2];
    sq = s1[(2*HH + (f-HH))*2+1];
  } else {
    sv = s2[i*2]; sq = s2[i*2+1];
  }
  double m = sv/(double)NB;
  double var = sq/(double)NB - m*m;
  if (var < 0.0) var = 0.0;
  m2[i] = (float)m;
  r2[i] = (float)(1.0/sqrt(var + 1e-5));
}

// ---------------- readout: MFMA GEMM with split-A bf16 ----------------
__global__ __launch_bounds__(256, 4) void k_rdm(
    const __hip_bfloat16* __restrict__ h1n, const float* __restrict__ xcg,
    const float* __restrict__ tpack, const float* __restrict__ ypack, const float* __restrict__ yT,
    const float* __restrict__ m2, const float* __restrict__ r2,
    const float* __restrict__ g2, const float* __restrict__ b2v,
    const unsigned short* __restrict__ wd5, const float* __restrict__ Bd,
    const float* __restrict__ Ud, const float* __restrict__ Cd,
    float* __restrict__ outT)
{
  __shared__ __align__(16) unsigned short FH[64*64];
  __shared__ __align__(16) unsigned short FL[64*64];
  __shared__ float scl[F2], sft[F2];
  const int tid = threadIdx.x, l = tid & 63, w = tid >> 6;
  const int lr = l & 15, lq = l >> 4;
  const int s = blockIdx.y, rr0 = blockIdx.x*64;
  if (tid < F2){
    float m = m2[s*F2+tid], rv = r2[s*F2+tid];
    float sc = rv * g2[tid];
    scl[tid] = sc;
    sft[tid] = b2v[tid] - m*sc;
  }
  __syncthreads();
  for (int i = tid; i < 64*64; i += 256){
    int f = i >> 6, r = i & 63;
    float v;
    if (f < HH) v = __bfloat162float(h1n[((size_t)s*HH + f)*NB + rr0 + r]);
    else if (f < HH+CVD) v = xcg[(size_t)(rr0+r)*CVD + (f-HH)];
    else if (f == 50){
      float t0 = tpack[rr0+r];
      for (int k=0;k<=s;++k) t0 = fmodf(t0 + 15.f, 1440.f);
      v = t0;
    }
    else if (f == 51) v = (s==0) ? ypack[rr0+r] : yT[(size_t)(s-1)*NB + rr0 + r];
    else v = 0.f;
    if (f < F2) v = v*scl[f] + sft[f];
    unsigned short hi = f2b(v);
    float lo = v - b2f(hi);
    int off = r*64 + ((((f>>3) ^ (r&7))&7)<<3) + (f&7);
    FH[off] = hi;
    FL[off] = f2b(lo);
  }
  __syncthreads();
  const int row = w*16 + lr;
  s8v ah[2], al[2];
  #pragma unroll
  for (int ks=0;ks<2;++ks){
    int ch = ((ks*4+lq) ^ (row&7)) & 7;
    ah[ks] = *(const s8v*)&FH[row*64 + ch*8];
    al[ks] = *(const s8v*)&FL[row*64 + ch*8];
  }
  f4v ps = {0.f,0.f,0.f,0.f};
  #pragma unroll 7
  for (int ct=0; ct<7; ++ct){
    int col = ct*16 + lr;
    float bd = (col < HID) ? Bd[(size_t)s*HID + col] : 0.f;
    f4v acc = {bd,bd,bd,bd};
    #pragma unroll
    for (int ks=0;ks<2;++ks){
      s8v B = *(const s8v*)(wd5 + ((size_t)(s*14 + ks*7 + ct)*512) + l*8);
      acc = __builtin_amdgcn_mfma_f32_16x16x32_bf16(ah[ks], B, acc, 0, 0, 0);
      acc = __builtin_amdgcn_mfma_f32_16x16x32_bf16(al[ks], B, acc, 0, 0, 0);
    }
    float ud = (col < HID) ? Ud[(size_t)s*HID + col] : 0.f;
    #pragma unroll
    for (int i=0;i<4;++i) ps[i] += fmaxf(acc[i], 0.f) * ud;
  }
  #pragma unroll
  for (int m=1; m<16; m<<=1){
    #pragma unroll
    for (int i=0;i<4;++i) ps[i] += __shfl_xor(ps[i], m, 64);
  }
  if (lr == 0){
    float cd = Cd[s];
    float4 o = { ps[0]+cd, ps[1]+cd, ps[2]+cd, ps[3]+cd };
    *(float4*)&outT[(size_t)s*NB + rr0 + w*16 + lq*4] = o;
  }
}

// ---------------- host ----------------
extern "C" void kernel_launch(void* const* d_in, const int* in_sizes, int n_in,
                              void* d_out, int out_size, void* d_ws, size_t ws_size,
                              hipStream_t stream)
{
  const float* x    = (const float*)d_in[0];
  const float* y    = (const float*)d_in[1];
  const float* h0i  = (const float*)d_in[2];
  const float* c0i  = (const float*)d_in[3];
  const float* wih0 = (const float*)d_in[4];
  const float* whh0 = (const float*)d_in[5];
  const float* bih0 = (const float*)d_in[6];
  const float* bhh0 = (const float*)d_in[7];
  const float* wih1 = (const float*)d_in[8];
  const float* whh1 = (const float*)d_in[9];
  const float* bih1 = (const float*)d_in[10];
  const float* bhh1 = (const float*)d_in[11];
  const float* w2ih0= (const float*)d_in[12];
  const float* w2hh0= (const float*)d_in[13];
  const float* b2ih0= (const float*)d_in[14];
  const float* b2hh0= (const float*)d_in[15];
  const float* w2ih1= (const float*)d_in[16];
  const float* w2hh1= (const float*)d_in[17];
  const float* b2ih1= (const float*)d_in[18];
  const float* b2hh1= (const float*)d_in[19];
  const float* c1w  = (const float*)d_in[20];
  const float* c1b  = (const float*)d_in[21];
  const float* c2w  = (const float*)d_in[22];
  const float* c2b  = (const float*)d_in[23];
  const float* c3w  = (const float*)d_in[24];
  const float* c3b  = (const float*)d_in[25];
  const float* fcw  = (const float*)d_in[26];
  const float* fcb  = (const float*)d_in[27];
  const float* bn1g = (const float*)d_in[28];
  const float* bn1b = (const float*)d_in[29];
  const float* bn2g = (const float*)d_in[30];
  const float* bn2b = (const float*)d_in[31];
  const float* Wd   = (const float*)d_in[32];
  const float* Bd   = (const float*)d_in[33];
  const float* Ud   = (const float*)d_in[34];
  const float* Cd   = (const float*)d_in[35];
  float* out = (float*)d_out;

  char* base = (char*)d_ws;
  size_t off = 0;
  auto take = [&](size_t bytes)->char*{
    char* p = base + off;
    off = (off + bytes + 255) & ~(size_t)255;
    return p;
  };
  float*  h0f = (float*) take((size_t)NB*HH*sizeof(float));
  float*  h1f = (float*) take((size_t)NB*HH*sizeof(float));
  float*  c0f = (float*) take((size_t)NB*HH*sizeof(float));
  float*  c1f = (float*) take((size_t)NB*HH*sizeof(float));
  float*  xcg = (float*) take((size_t)NB*CVD*sizeof(float));
  float*  ctx = (float*) take((size_t)NB*CTXD*sizeof(float));
  double* s1  = (double*)take((size_t)CTXD*2*sizeof(double));
  float*  st1 = (float*) take((size_t)CTXD*2*sizeof(float));
  double* s2  = (double*)take((size_t)NOUT*F2*2*sizeof(double));
  float*  m2  = (float*) take((size_t)NOUT*F2*sizeof(float));
  float*  r2  = (float*) take((size_t)NOUT*F2*sizeof(float));
  unsigned short* wb2 = (unsigned short*) take((size_t)48*512*sizeof(unsigned short));
  float*  tb  = (float*) take((size_t)4*128*sizeof(float));
  unsigned short* wb3 = (unsigned short*) take((size_t)32*512*sizeof(unsigned short));
  float*  tbe = (float*) take((size_t)2*128*sizeof(float));
  unsigned short* wc  = (unsigned short*) take((size_t)96*512*sizeof(unsigned short));
  unsigned short* wd5 = (unsigned short*) take((size_t)NOUT*14*512*sizeof(unsigned short));
  float*  tpk = (float*) take((size_t)NB*sizeof(float));
  float*  ypk = (float*) take((size_t)NB*sizeof(float));
  float*  yT  = (float*) take((size_t)NOUT*NB*sizeof(float));
  float*  oT  = (float*) take((size_t)NOUT*NB*sizeof(float));
  __hip_bfloat16* h1n = (__hip_bfloat16*) take((size_t)NOUT*HH*NB*sizeof(__hip_bfloat16));
  (void)ws_size;

  k_tw2<<<dim3((48*512+512+255)/256), dim3(256), 0, stream>>>(w2ih0, w2hh0, w2ih1, w2hh1,
      b2ih0, b2hh0, b2ih1, b2hh1, wb2, tb);
  k_tw3<<<dim3((32*512+256+255)/256), dim3(256), 0, stream>>>(wih0, whh0, wih1, whh1,
      bih0, bhh0, bih1, bhh1, wb3, tbe);
  k_tw4<<<dim3((96*512+255)/256), dim3(256), 0, stream>>>(c1w, c2w, c3w, fcw, wc);
  k_tw5<<<dim3((NOUT*14*512+255)/256), dim3(256), 0, stream>>>(Wd, wd5);
  k_pack<<<dim3(NB/256), dim3(256), 0, stream>>>(x, tpk, ypk);
  k_ty<<<dim3(NB/64), dim3(256), 0, stream>>>(y, yT);
  k_zero<<<dim3((NOUT*F2*2+255)/256), dim3(256), 0, stream>>>(s1, s2);
  k_encm<<<dim3(NB/SMP), dim3(512), 0, stream>>>(x, h0i, c0i, wb3, tbe, h0f, h1f, c0f, c1f);
  k_convm<<<dim3(NB/16), dim3(256), 0, stream>>>(x, wc, c1b, c2b, c3b, fcb, xcg);
  k_bn1s<<<dim3(NB/128), dim3(128), 0, stream>>>(h0f, h1f, xcg, s1);
  k_fin1<<<dim3(1), dim3(128), 0, stream>>>(s1, st1);
  k_context<<<dim3((NB*CTXD + 255)/256), dim3(256), 0, stream>>>(h0f, h1f, xcg, st1, bn1g, bn1b, ctx);
  k_dec1m<<<dim3(NB/SMP), dim3(512), 0, stream>>>(tpk, ypk, yT, ctx, wb2, tb,
      h0f, h1f, c0f, c1f, h1n);
  k_bn2h<<<dim3(NOUT, HH), dim3(256), 0, stream>>>(h1n, s2);
  k_bn2y<<<dim3(NOUT), dim3(256), 0, stream>>>(ypk, yT, s2);
  k_bn2t<<<dim3(NB/256), dim3(256), 0, stream>>>(tpk, s2);
  k_fin2b<<<dim3((NOUT*F2+255)/256), dim3(256), 0, stream>>>(s1, s2, m2, r2);
  k_rdm<<<dim3(NB/64, NOUT), dim3(256), 0, stream>>>(h1n, xcg, tpk, ypk, yT,
      m2, r2, bn2g, bn2b, wd5, Bd, Ud, Cd, oT);
  k_tro<<<dim3(NB/64), dim3(256), 0, stream>>>(oT, out);
}

// Round 16
// 529.339 us; speedup vs baseline: 1.2329x; 1.0554x over previous
//
#include <hip/hip_runtime.h>
#include <hip/hip_bf16.h>

#define NB   16384
#define TT   50
#define HH   30
#define IND  8
#define CTXD 80
#define IN2  82
#define F2   52
#define NOUT 50
#define HID  100
#define CVD  20
#define SMP  64   // samples per LSTM block (8 waves)
#define HSTR2 40  // H row stride in shorts (80B: 16B-aligned, bank-quad-cycling)

typedef __attribute__((ext_vector_type(8))) short s8v;
typedef __attribute__((ext_vector_type(4))) float f4v;
typedef __attribute__((ext_vector_type(4))) unsigned short us4v;

__device__ __forceinline__ float sg(float x){
  return 1.f/(1.f+__expf(-x));
}
__device__ __forceinline__ float th(float x){
  x = fminf(x, 15.f);
  float e = __expf(2.f*x);
  return (e-1.f)/(e+1.f);
}
// fast t-update: valid when t in (-1440,1440); bit-identical to fmodf(t+15,1440)
__device__ __forceinline__ float tstep(float t){
  t += 15.f;
  return (t >= 1440.f) ? t - 1440.f : t;
}
__device__ __forceinline__ unsigned short f2b(float f){
  __hip_bfloat16 h = __float2bfloat16(f);
  return *reinterpret_cast<unsigned short*>(&h);
}
__device__ __forceinline__ float b2f(unsigned short u){
  __hip_bfloat16 h;
  *reinterpret_cast<unsigned short*>(&h) = u;
  return __bfloat162float(h);
}
__device__ __forceinline__ double shfl_xor_d(double v, int m){
  long long ll = __double_as_longlong(v);
  int lo = (int)(ll & 0xffffffffLL), hi = (int)(ll >> 32);
  lo = __shfl_xor(lo, m, 64); hi = __shfl_xor(hi, m, 64);
  return __longlong_as_double(((long long)hi << 32) | (unsigned int)(unsigned)lo);
}

// ---------------- decoder MFMA fragment tables ----------------
__global__ void k_tw2(const float* __restrict__ w2ih0, const float* __restrict__ w2hh0,
                      const float* __restrict__ w2ih1, const float* __restrict__ w2hh1,
                      const float* __restrict__ b2ih0, const float* __restrict__ b2hh0,
                      const float* __restrict__ b2ih1, const float* __restrict__ b2hh1,
                      unsigned short* __restrict__ wb2, float* __restrict__ tb)
{
  int idx = blockIdx.x*256 + threadIdx.x;
  if (idx < 48*512){
    int f = idx >> 9, rem = idx & 511;
    int l = rem >> 3, j = rem & 7;
    int lr = l & 15, lq = l >> 4;
    float v = 0.f;
    if (f < 8){
      int ct = f, k = 8*lq + j, col = ct*16 + lr;
      int g = col>>5, u = col&31;
      if (k < HH && u < HH) v = w2hh0[(size_t)(g*HH+u)*HH + k];
    } else if (f < 24){
      int ct = (f-8)>>1, ks = (f-8)&1, k = 8*lq + j, col = ct*16 + lr;
      int g = col>>5, u = col&31;
      if (k < HH && u < HH) v = ks ? w2hh1[(size_t)(g*HH+u)*HH + k] : w2ih1[(size_t)(g*HH+u)*HH + k];
    } else {
      int ct = (f-24)/3, ks = (f-24)%3, k = ks*32 + 8*lq + j, col = ct*16 + lr;
      int g = col>>5, u = col&31;
      if (k < CTXD && u < HH) v = w2ih0[(size_t)(g*HH+u)*IN2 + k];
    }
    wb2[idx] = f2b(v);
  } else if (idx < 48*512 + 512){
    int t = idx - 48*512;
    int col = t & 127, sel = t >> 7;
    int g = col>>5, u = col&31;
    float v = 0.f;
    if (u < HH){
      int r = g*HH + u;
      if (sel == 0) v = b2ih0[r] + b2hh0[r];
      else if (sel == 1) v = b2ih1[r] + b2hh1[r];
      else if (sel == 2) v = w2ih0[(size_t)r*IN2 + 80];
      else v = w2ih0[(size_t)r*IN2 + 81];
    }
    tb[sel*128 + col] = v;
  }
}

// ---------------- encoder MFMA fragment tables ----------------
__global__ void k_tw3(const float* __restrict__ wih0, const float* __restrict__ whh0,
                      const float* __restrict__ wih1, const float* __restrict__ whh1,
                      const float* __restrict__ bih0, const float* __restrict__ bhh0,
                      const float* __restrict__ bih1, const float* __restrict__ bhh1,
                      unsigned short* __restrict__ wb3, float* __restrict__ tbe)
{
  int idx = blockIdx.x*256 + threadIdx.x;
  if (idx < 32*512){
    int f = idx >> 9, rem = idx & 511;
    int l = rem >> 3, j = rem & 7;
    int lr = l & 15, lq = l >> 4;
    int k = 8*lq + j;
    float v = 0.f;
    if (f < 8){
      int col = f*16 + lr; int g = col>>5, u = col&31;
      if (k < IND && u < HH) v = wih0[(size_t)(g*HH+u)*IND + k];
    } else if (f < 16){
      int ct = f-8; int col = ct*16 + lr; int g = col>>5, u = col&31;
      if (k < HH && u < HH) v = whh0[(size_t)(g*HH+u)*HH + k];
    } else {
      int ct = (f-16)>>1, ks = (f-16)&1; int col = ct*16 + lr; int g = col>>5, u = col&31;
      if (k < HH && u < HH) v = ks ? whh1[(size_t)(g*HH+u)*HH + k] : wih1[(size_t)(g*HH+u)*HH + k];
    }
    wb3[idx] = f2b(v);
  } else if (idx < 32*512 + 256){
    int t2 = idx - 32*512;
    int col = t2 & 127, sel = t2 >> 7;
    int g = col>>5, u = col&31;
    float v = 0.f;
    if (u < HH){
      int r = g*HH + u;
      v = sel ? (bih1[r] + bhh1[r]) : (bih0[r] + bhh0[r]);
    }
    tbe[sel*128 + col] = v;
  }
}

// ---------------- conv MFMA fragment tables ----------------
__global__ void k_tw4(const float* __restrict__ c1w, const float* __restrict__ c2w,
                      const float* __restrict__ c3w, const float* __restrict__ fcw,
                      unsigned short* __restrict__ wc)
{
  int idx = blockIdx.x*256 + threadIdx.x;
  if (idx >= 96*512) return;
  int f = idx >> 9, rem = idx & 511;
  int l = rem >> 3, j = rem & 7;
  int lr = l & 15, lq = l >> 4;
  int k = 8*lq + j;
  float v = 0.f;
  if (f < 4){
    int ks = f>>1, ct = f&1; int kk2 = ks*32 + k;
    if (kk2 < 40){ int kk = kk2>>3, ic = kk2&7; v = c1w[((size_t)(ct*16+lr)*8 + ic)*5 + kk]; }
  } else if (f < 16){
    int fi = f-4; int ks = fi>>2, ct = fi&3;
    v = c2w[((size_t)(ct*16+lr)*32 + k)*3 + ks];
  } else if (f < 64){
    int fi = f-16; int ks = fi>>3, ct = fi&7; int kk2 = ks*32 + k;
    int kk = kk2>>6, ic = kk2&63;
    v = c3w[((size_t)(ct*16+lr)*64 + ic)*3 + kk];
  } else {
    int fi = f-64; int ks = fi>>1, ct = fi&1; int kk2 = ks*32 + k;
    int p = kk2>>7, ocb = kk2&127;
    int n = ct*16 + lr;
    if (n < 20) v = fcw[(size_t)n*512 + ocb*4 + p];
  }
  wc[idx] = f2b(v);
}

// ---------------- readout Wd fragment table ----------------
__global__ void k_tw5(const float* __restrict__ Wd, unsigned short* __restrict__ wd5){
  int idx = blockIdx.x*256 + threadIdx.x;
  if (idx >= NOUT*14*512) return;
  int s = idx / (14*512), rem = idx - s*(14*512);
  int fi = rem >> 9, r2i = rem & 511;
  int l = r2i >> 3, j = r2i & 7;
  int lr = l & 15, lq = l >> 4;
  int ks = fi / 7, ct = fi - ks*7;
  int k = ks*32 + 8*lq + j, col = ct*16 + lr;
  float v = (k < F2 && col < HID) ? Wd[((size_t)s*F2 + k)*HID + col] : 0.f;
  wd5[idx] = f2b(v);
}

// ---------------- pack/transpose helpers ----------------
__global__ void k_pack(const float* __restrict__ x, float* __restrict__ tpack, float* __restrict__ ypack){
  int r = blockIdx.x*256 + threadIdx.x;
  if (r < NB){
    tpack[r] = x[(size_t)r*(TT*IND) + (TT-1)*IND + 7];
    ypack[r] = x[(size_t)r*(TT*IND) + (TT-1)*IND + 0];
  }
}

__global__ __launch_bounds__(256) void k_ty(const float* __restrict__ y, float* __restrict__ yT){
  __shared__ float tile[NOUT*65];
  int rr0 = blockIdx.x*64;
  for (int i=threadIdx.x; i<64*NOUT; i+=256){
    int r = i/NOUT, s = i - r*NOUT;
    tile[s*65 + r] = y[(size_t)(rr0+r)*NOUT + s];
  }
  __syncthreads();
  for (int i=threadIdx.x; i<64*NOUT; i+=256){
    int s = i>>6, r = i&63;
    yT[(size_t)s*NB + rr0 + r] = tile[s*65 + r];
  }
}

__global__ __launch_bounds__(256) void k_tro(const float* __restrict__ outT, float* __restrict__ out){
  __shared__ float tile[NOUT*65];
  int rr0 = blockIdx.x*64;
  for (int i=threadIdx.x; i<64*NOUT; i+=256){
    int s = i>>6, r = i&63;
    tile[s*65 + r] = outT[(size_t)s*NB + rr0 + r];
  }
  __syncthreads();
  for (int i=threadIdx.x; i<64*NOUT; i+=256){
    int r = i/NOUT, s = i - r*NOUT;
    out[(size_t)(rr0+r)*NOUT + s] = tile[s*65 + r];
  }
}

// ---------------- zero accumulators (s1 + s2) ----------------
__global__ void k_zero(double* s1, double* s2){
  int i = blockIdx.x*256 + threadIdx.x;
  if (i < CTXD*2) s1[i] = 0.0;
  if (i < NOUT*F2*2) s2[i] = 0.0;
}

// ---------------- encoder: MFMA LSTM, 64 samples / 8 waves, merged phase ----------------
__global__ __launch_bounds__(512, 2) void k_encm(
    const float* __restrict__ x, const float* __restrict__ h0i, const float* __restrict__ c0i,
    const unsigned short* __restrict__ wb3, const float* __restrict__ tbe,
    float* __restrict__ h0f, float* __restrict__ h1f,
    float* __restrict__ c0f, float* __restrict__ c1f)
{
  __shared__ __align__(16) unsigned short XS[TT*SMP*8];
  __shared__ __align__(16) unsigned short H0[2][SMP*HSTR2];
  __shared__ __align__(16) unsigned short H1[2][SMP*HSTR2];
  const int tid = threadIdx.x;
  const int l = tid & 63, w = tid >> 6;           // 8 waves
  const int st = w & 3, ug = w >> 2;
  const int lr = l & 15, lq = l >> 4;
  const int blk = blockIdx.x;

  for (int i = tid; i < SMP*HSTR2; i += 512){
    H0[0][i]=0; H0[1][i]=0; H1[0][i]=0; H1[1][i]=0;
  }
  for (int i = tid; i < SMP*100; i += 512){
    int smp = i/100, q = i - smp*100;
    float4 v = ((const float4*)(x + (size_t)(blk*SMP+smp)*(TT*IND)))[q];
    int t = q>>1, d = (q&1)*4;
    unsigned short* p = &XS[t*(SMP*8) + smp*8 + d];
    p[0]=f2b(v.x); p[1]=f2b(v.y); p[2]=f2b(v.z); p[3]=f2b(v.w);
  }
  __syncthreads();
  for (int i = tid; i < SMP*HH; i += 512){
    int r = i/HH, u2 = i - r*HH;
    H0[0][r*HSTR2 + u2] = f2b(h0i[u2]);
    H1[0][r*HSTR2 + u2] = f2b(h0i[HH+u2]);
  }

  const int u  = ug*16 + lr;
  const int uc = u < HH ? u : HH-1;
  const int arow = st*16 + lr;
  const int aoff = arow*HSTR2 + lq*8;
  float c0[4], c1[4];
  #pragma unroll
  for (int i=0;i<4;++i){
    c0[i] = c0i[uc];
    c1[i] = c0i[HH+uc];
  }
  s8v BX[4], BH[4], B10[4], B11[4];
  float b0v[4], b1v[4];
  #pragma unroll
  for (int g=0; g<4; ++g){
    const int ct = g*2 + ug;
    const int col = ct*16 + lr;
    BX[g]  = *(const s8v*)(wb3 + ((size_t)(ct)*64 + l)*8);
    BH[g]  = *(const s8v*)(wb3 + ((size_t)(8 + ct)*64 + l)*8);
    B10[g] = *(const s8v*)(wb3 + ((size_t)(16 + ct*2 + 0)*64 + l)*8);
    B11[g] = *(const s8v*)(wb3 + ((size_t)(16 + ct*2 + 1)*64 + l)*8);
    b0v[g] = tbe[col]; b1v[g] = tbe[128+col];
  }
  __syncthreads();

  const int wrow = (st*16 + 4*lq)*HSTR2 + u;   // base of 4 consecutive sample rows

  // ---- prologue: layer0(t=0) ----
  {
    s8v ax = {0,0,0,0,0,0,0,0};
    if (lq == 0) ax = *(const s8v*)&XS[0*(SMP*8) + arow*8];
    const s8v ah = *(const s8v*)&H0[0][aoff];
    f4v ac[4];
    #pragma unroll
    for (int g=0; g<4; ++g){
      f4v a = {b0v[g], b0v[g], b0v[g], b0v[g]};
      a = __builtin_amdgcn_mfma_f32_16x16x32_bf16(ax, BX[g], a, 0, 0, 0);
      ac[g] = __builtin_amdgcn_mfma_f32_16x16x32_bf16(ah, BH[g], a, 0, 0, 0);
    }
    #pragma unroll
    for (int i=0;i<4;++i){
      float iv = sg(ac[0][i]), fv = sg(ac[1][i]), gv = th(ac[2][i]), ov = sg(ac[3][i]);
      c0[i] = fv*c0[i] + iv*gv;
      if (u < HH) H0[1][wrow + i*HSTR2] = f2b(ov*th(c0[i]));
    }
    __syncthreads();
  }

  // ---- merged loop ----
  for (int t=0; t<TT; ++t){
    const int b = (t+1)&1;
    const s8v a1 = *(const s8v*)&H0[b][aoff];     // h0 after step t
    const s8v a2 = *(const s8v*)&H1[t&1][aoff];   // h1 after step t-1
    f4v ac1[4];
    #pragma unroll
    for (int g=0; g<4; ++g){
      f4v a = {b1v[g], b1v[g], b1v[g], b1v[g]};
      a = __builtin_amdgcn_mfma_f32_16x16x32_bf16(a1, B10[g], a, 0, 0, 0);
      ac1[g] = __builtin_amdgcn_mfma_f32_16x16x32_bf16(a2, B11[g], a, 0, 0, 0);
    }
    const bool hasNext = (t < TT-1);
    f4v ac0[4];
    if (hasNext){
      s8v ax = {0,0,0,0,0,0,0,0};
      if (lq == 0) ax = *(const s8v*)&XS[(t+1)*(SMP*8) + arow*8];
      #pragma unroll
      for (int g=0; g<4; ++g){
        f4v a = {b0v[g], b0v[g], b0v[g], b0v[g]};
        a = __builtin_amdgcn_mfma_f32_16x16x32_bf16(ax, BX[g], a, 0, 0, 0);
        ac0[g] = __builtin_amdgcn_mfma_f32_16x16x32_bf16(a1, BH[g], a, 0, 0, 0);
      }
    }
    #pragma unroll
    for (int i=0;i<4;++i){
      float iv = sg(ac1[0][i]), fv = sg(ac1[1][i]), gv = th(ac1[2][i]), ov = sg(ac1[3][i]);
      c1[i] = fv*c1[i] + iv*gv;
      if (u < HH) H1[b][wrow + i*HSTR2] = f2b(ov*th(c1[i]));
    }
    if (hasNext){
      #pragma unroll
      for (int i=0;i<4;++i){
        float iv = sg(ac0[0][i]), fv = sg(ac0[1][i]), gv = th(ac0[2][i]), ov = sg(ac0[3][i]);
        c0[i] = fv*c0[i] + iv*gv;
        if (u < HH) H0[t&1][wrow + i*HSTR2] = f2b(ov*th(c0[i]));
      }
    }
    __syncthreads();
  }
  for (int i2 = tid; i2 < SMP*HH; i2 += 512){
    int sl = i2 / HH, uu = i2 - sl*HH;
    h0f[((size_t)blk*SMP + sl)*HH + uu] = b2f(H0[0][sl*HSTR2 + uu]);
    h1f[((size_t)blk*SMP + sl)*HH + uu] = b2f(H1[0][sl*HSTR2 + uu]);
  }
  if (u < HH){
    #pragma unroll
    for (int i=0;i<4;++i){
      int gS = blk*SMP + st*16 + 4*lq + i;
      c0f[(size_t)gS*HH + u] = c0[i];
      c1f[(size_t)gS*HH + u] = c1[i];
    }
  }
}

// ---------------- conv path: MFMA ----------------
__global__ __launch_bounds__(256, 2) void k_convm(
    const float* __restrict__ x, const unsigned short* __restrict__ wc,
    const float* __restrict__ b1, const float* __restrict__ b2,
    const float* __restrict__ b3, const float* __restrict__ fb,
    float* __restrict__ xcg)
{
  __shared__ __align__(16) unsigned short XT[16*52*8];
  __shared__ __align__(16) unsigned short P1[16*26*32];
  __shared__ __align__(16) unsigned short P2[16*10*64];
  __shared__ __align__(16) unsigned short P3[16*4*128];
  const int tid = threadIdx.x, l = tid & 63, w = tid >> 6;
  const int lr = l & 15, lq = l >> 4;
  const int blk = blockIdx.x;
  for (int i=tid; i<16*16; i+=256){ int s=i>>4, q=i&15; XT[s*416 + 400 + q] = 0; }
  for (int i=tid; i<16*96; i+=256){ int s=i/96, q=i - (i/96)*96; P1[s*832 + 736 + q] = 0; }
  for (int i=tid; i<1600; i+=256){
    int s = i/100, q = i - s*100;
    float4 v = ((const float4*)(x + (size_t)(blk*16+s)*400))[q];
    int t = q>>1, d = (q&1)*4;
    unsigned short* p = &XT[s*416 + t*8 + d];
    p[0]=f2b(v.x); p[1]=f2b(v.y); p[2]=f2b(v.z); p[3]=f2b(v.w);
  }
  __syncthreads();
  {
    s8v B[2][2];
    #pragma unroll
    for (int ks=0;ks<2;++ks)
      #pragma unroll
      for (int ct=0;ct<2;++ct)
        B[ks][ct] = *(const s8v*)(wc + ((size_t)(ks*2+ct)*512) + l*8);
    float bv[2] = { b1[lr], b1[16+lr] };
    for (int t5=w; t5<48; t5+=4){
      int row = t5*16 + lr, s = row/48, pos = row - s*48;
      s8v a0 = *(const s8v*)&XT[s*416 + (pos+lq)*8];
      s8v a1 = {0,0,0,0,0,0,0,0};
      if (lq == 0) a1 = *(const s8v*)&XT[s*416 + (pos+4)*8];
      int rb = t5*16 + 4*lq, s2 = rb/48, pp = rb - s2*48;
      #pragma unroll
      for (int ct=0;ct<2;++ct){
        f4v acc = {bv[ct],bv[ct],bv[ct],bv[ct]};
        acc = __builtin_amdgcn_mfma_f32_16x16x32_bf16(a0, B[0][ct], acc, 0, 0, 0);
        acc = __builtin_amdgcn_mfma_f32_16x16x32_bf16(a1, B[1][ct], acc, 0, 0, 0);
        int oc = ct*16 + lr;
        #pragma unroll
        for (int pr=0;pr<2;++pr){
          int pos2 = (pp>>1) + pr;
          if (pos2 < 23){
            float v = fmaxf(fmaxf(acc[2*pr],0.f), fmaxf(acc[2*pr+1],0.f));
            int ch = (oc>>3) ^ (pos2&3);
            P1[s2*832 + pos2*32 + ch*8 + (oc&7)] = f2b(v);
          }
        }
      }
    }
  }
  __syncthreads();
  {
    s8v B[3][4];
    #pragma unroll
    for (int ks=0;ks<3;++ks)
      #pragma unroll
      for (int ct=0;ct<4;++ct)
        B[ks][ct] = *(const s8v*)(wc + ((size_t)(4+ks*4+ct)*512) + l*8);
    float bv[4] = { b2[lr], b2[16+lr], b2[32+lr], b2[48+lr] };
    for (int t6=w; t6<24; t6+=4){
      int row = t6*16 + lr, s = row/24, pos = row - s*24;
      s8v a[3];
      #pragma unroll
      for (int ks=0;ks<3;++ks){
        int pr = pos + ks, ch = lq ^ (pr&3);
        a[ks] = *(const s8v*)&P1[s*832 + pr*32 + ch*8];
      }
      int rb = t6*16 + 4*lq, s2 = rb/24, pp = rb - s2*24;
      #pragma unroll
      for (int ct=0;ct<4;++ct){
        f4v acc = {bv[ct],bv[ct],bv[ct],bv[ct]};
        #pragma unroll
        for (int ks=0;ks<3;++ks)
          acc = __builtin_amdgcn_mfma_f32_16x16x32_bf16(a[ks], B[ks][ct], acc, 0, 0, 0);
        int oc = ct*16 + lr;
        #pragma unroll
        for (int pr=0;pr<2;++pr){
          int pos2 = (pp>>1) + pr;
          if (pos2 < 10){
            float v = fmaxf(fmaxf(acc[2*pr],0.f), fmaxf(acc[2*pr+1],0.f));
            int ch = (oc>>3) ^ (pos2&7);
            P2[s2*640 + pos2*64 + ch*8 + (oc&7)] = f2b(v);
          }
        }
      }
    }
  }
  __syncthreads();
  {
    s8v A[2][6]; int sS[2], ppS[2];
    #pragma unroll
    for (int tt=0;tt<2;++tt){
      int t7 = w*2 + tt;
      int row = t7*16 + lr, s = row>>3, pos = row&7;
      #pragma unroll
      for (int ks=0;ks<6;++ks){
        int pr = pos + (ks>>1);
        int cb = 4*(ks&1) + lq;
        int ch = cb ^ (pr&7);
        A[tt][ks] = *(const s8v*)&P2[s*640 + pr*64 + ch*8];
      }
      int rb = t7*16 + 4*lq;
      sS[tt] = rb>>3; ppS[tt] = rb&7;
    }
    for (int ct=0;ct<8;++ct){
      s8v B[6];
      #pragma unroll
      for (int ks=0;ks<6;++ks)
        B[ks] = *(const s8v*)(wc + ((size_t)(16+ks*8+ct)*512) + l*8);
      int oc = ct*16 + lr;
      float bb = b3[oc];
      #pragma unroll
      for (int tt=0;tt<2;++tt){
        f4v acc = {bb,bb,bb,bb};
        #pragma unroll
        for (int ks=0;ks<6;++ks)
          acc = __builtin_amdgcn_mfma_f32_16x16x32_bf16(A[tt][ks], B[ks], acc, 0, 0, 0);
        #pragma unroll
        for (int pr=0;pr<2;++pr){
          int pos2 = (ppS[tt]>>1) + pr;
          float v = fmaxf(fmaxf(acc[2*pr],0.f), fmaxf(acc[2*pr+1],0.f));
          int flat = pos2*128 + oc;
          int ch = (flat>>3) ^ (sS[tt]&7);
          P3[sS[tt]*512 + ch*8 + (oc&7)] = f2b(v);
        }
      }
    }
  }
  __syncthreads();
  if (w == 0){
    f4v acc[2];
    float fb0 = fb[lr];
    float fb1 = (lr < 4) ? fb[16+lr] : 0.f;
    acc[0] = (f4v){fb0,fb0,fb0,fb0};
    acc[1] = (f4v){fb1,fb1,fb1,fb1};
    for (int ks=0;ks<16;++ks){
      int k0 = ks*32 + 8*lq;
      int ch = (k0>>3) ^ (lr&7);
      s8v a = *(const s8v*)&P3[lr*512 + ch*8];
      #pragma unroll
      for (int ct=0;ct<2;++ct){
        s8v Bf = *(const s8v*)(wc + ((size_t)(64+ks*2+ct)*512) + l*8);
        acc[ct] = __builtin_amdgcn_mfma_f32_16x16x32_bf16(a, Bf, acc[ct], 0, 0, 0);
      }
    }
    #pragma unroll
    for (int ct=0;ct<2;++ct){
      int oc = ct*16 + lr;
      if (oc < 20){
        #pragma unroll
        for (int i=0;i<4;++i){
          int smp = 4*lq + i;
          xcg[(size_t)(blk*16+smp)*CVD + oc] = fmaxf(acc[ct][i], 0.f);
        }
      }
    }
  }
}

// ---------------- BN1 stats ----------------
__global__ __launch_bounds__(128) void k_bn1s(const float* __restrict__ h0f, const float* __restrict__ h1f,
    const float* __restrict__ xcg, double* __restrict__ s1)
{
  int f = threadIdx.x;
  if (f >= CTXD) return;
  int r0 = blockIdx.x*128;
  double s=0.0, q=0.0;
  for (int i=0;i<128;++i){
    int r = r0+i;
    float v = (f<HH) ? h0f[(size_t)r*HH+f] : (f<2*HH) ? h1f[(size_t)r*HH + f-HH] : xcg[(size_t)r*CVD + f-2*HH];
    s += (double)v; q += (double)v*(double)v;
  }
  atomicAdd(&s1[f*2],   s);
  atomicAdd(&s1[f*2+1], q);
}

__global__ void k_fin1(const double* __restrict__ s1, float* __restrict__ st1){
  int f = threadIdx.x;
  if (f >= CTXD) return;
  double m = s1[f*2]/(double)NB;
  double var = s1[f*2+1]/(double)NB - m*m;
  if (var < 0.0) var = 0.0;
  st1[f*2]   = (float)m;
  st1[f*2+1] = (float)(1.0/sqrt(var + 1e-5));
}

__global__ __launch_bounds__(256) void k_context(const float* __restrict__ h0f, const float* __restrict__ h1f,
    const float* __restrict__ xcg, const float* __restrict__ st1,
    const float* __restrict__ g1, const float* __restrict__ bb1, float* __restrict__ ctx)
{
  int idx = blockIdx.x*256 + threadIdx.x;
  if (idx >= NB*CTXD) return;
  int rr = idx / CTXD, f = idx - rr*CTXD;
  float v = (f<HH) ? h0f[(size_t)rr*HH+f] : (f<2*HH) ? h1f[(size_t)rr*HH + f-HH] : xcg[(size_t)rr*CVD + f-2*HH];
  ctx[idx] = (v - st1[f*2]) * st1[f*2+1] * g1[f] + bb1[f];
}

// ---------------- decoder pass 1: MFMA LSTM, merged phase ----------------
__global__ __launch_bounds__(512, 2) void k_dec1m(
    const float* __restrict__ tpack, const float* __restrict__ ypack, const float* __restrict__ yT,
    const float* __restrict__ ctx,
    const unsigned short* __restrict__ wb2, const float* __restrict__ tb,
    const float* __restrict__ h0fi, const float* __restrict__ h1fi,
    const float* __restrict__ c0fi, const float* __restrict__ c1fi,
    __hip_bfloat16* __restrict__ h1n)
{
  __shared__ __align__(16) unsigned short CT[SMP*96];
  __shared__ __align__(16) unsigned short Hh0[2][SMP*HSTR2];
  __shared__ __align__(16) unsigned short Hh1[2][SMP*HSTR2];
  const int tid = threadIdx.x;
  const int l  = tid & 63, w = tid >> 6;          // 8 waves
  const int st = w & 3, ug = w >> 2;
  const int lr = l & 15, lq = l >> 4, l3 = l & 3;
  const int blk = blockIdx.x;

  for (int i = tid; i < SMP*HSTR2; i += 512){
    Hh0[0][i] = 0; Hh0[1][i] = 0; Hh1[0][i] = 0; Hh1[1][i] = 0;
  }
  for (int i = tid; i < SMP*96; i += 512) CT[i] = 0;
  __syncthreads();
  for (int i = tid; i < SMP*CTXD; i += 512){
    int r = i / CTXD, kk = i - r*CTXD;
    float v = ctx[((size_t)blk*SMP + r)*CTXD + kk];
    CT[r*96 + (((kk>>3) ^ (r&3))<<3) + (kk&7)] = f2b(v);
  }
  for (int i = tid; i < SMP*HH; i += 512){
    int r = i / HH, u2 = i - r*HH;
    Hh0[0][r*HSTR2 + u2] = f2b(h0fi[((size_t)blk*SMP + r)*HH + u2]);
    Hh1[0][r*HSTR2 + u2] = f2b(h1fi[((size_t)blk*SMP + r)*HH + u2]);
  }

  const int u  = ug*16 + lr;
  const int uc = u < HH ? u : HH-1;
  const int arow = st*16 + lr;
  const int aoff = arow*HSTR2 + lq*8;
  const int sbase = blk*SMP + st*16 + 4*lq;       // first of this lane's 4 samples

  float c0[4], c1[4], tt[4], yv[4];
  {
    float4 tv = *(const float4*)&tpack[sbase];
    float4 yv4 = *(const float4*)&ypack[sbase];
    tt[0]=tv.x; tt[1]=tv.y; tt[2]=tv.z; tt[3]=tv.w;
    yv[0]=yv4.x; yv[1]=yv4.y; yv[2]=yv4.z; yv[3]=yv4.w;
  }
  #pragma unroll
  for (int i=0;i<4;++i){
    c0[i] = c0fi[(size_t)(sbase+i)*HH + uc];
    c1[i] = c1fi[(size_t)(sbase+i)*HH + uc];
  }

  s8v B0[4], B10[4], B11[4], BC0[4], BC1[4], BC2[4];
  float bias0[4], bias1[4], wtt[4], wty[4];
  #pragma unroll
  for (int g=0; g<4; ++g){
    const int ct = g*2 + ug;
    const int col = ct*16 + lr;
    B0[g]  = *(const s8v*)(wb2 + ((size_t)(ct)*64 + l)*8);
    B10[g] = *(const s8v*)(wb2 + ((size_t)(8 + ct*2 + 0)*64 + l)*8);
    B11[g] = *(const s8v*)(wb2 + ((size_t)(8 + ct*2 + 1)*64 + l)*8);
    BC0[g] = *(const s8v*)(wb2 + ((size_t)(24 + ct*3 + 0)*64 + l)*8);
    BC1[g] = *(const s8v*)(wb2 + ((size_t)(24 + ct*3 + 1)*64 + l)*8);
    BC2[g] = *(const s8v*)(wb2 + ((size_t)(24 + ct*3 + 2)*64 + l)*8);
    bias0[g] = tb[col]; bias1[g] = tb[128+col];
    wtt[g] = tb[256+col]; wty[g] = tb[384+col];
  }
  __syncthreads();

  f4v pc[4];
  #pragma unroll
  for (int g=0; g<4; ++g){
    f4v a = {bias0[g], bias0[g], bias0[g], bias0[g]};
    {
      const s8v av = *(const s8v*)&CT[arow*96 + (((0*4+lq) ^ l3)<<3)];
      a = __builtin_amdgcn_mfma_f32_16x16x32_bf16(av, BC0[g], a, 0, 0, 0);
    }
    {
      const s8v av = *(const s8v*)&CT[arow*96 + (((1*4+lq) ^ l3)<<3)];
      a = __builtin_amdgcn_mfma_f32_16x16x32_bf16(av, BC1[g], a, 0, 0, 0);
    }
    {
      const s8v av = *(const s8v*)&CT[arow*96 + (((2*4+lq) ^ l3)<<3)];
      a = __builtin_amdgcn_mfma_f32_16x16x32_bf16(av, BC2[g], a, 0, 0, 0);
    }
    pc[g] = a;
  }

  const int wrow = (st*16 + 4*lq)*HSTR2 + u;
  unsigned short* h1s = reinterpret_cast<unsigned short*>(h1n);

  // ---- prologue: layer0(step 0) — first t-update is a true fmod ----
  {
    #pragma unroll
    for (int i=0;i<4;++i) tt[i] = fmodf(tt[i] + 15.f, 1440.f);
    const s8v a0 = *(const s8v*)&Hh0[0][aoff];
    f4v ac[4];
    #pragma unroll
    for (int g=0; g<4; ++g){
      f4v a = pc[g];
      #pragma unroll
      for (int i=0;i<4;++i) a[i] += tt[i]*wtt[g] + yv[i]*wty[g];
      ac[g] = __builtin_amdgcn_mfma_f32_16x16x32_bf16(a0, B0[g], a, 0, 0, 0);
    }
    #pragma unroll
    for (int i=0;i<4;++i){
      float iv = sg(ac[0][i]), fv = sg(ac[1][i]), gv = th(ac[2][i]), ov = sg(ac[3][i]);
      c0[i] = fv*c0[i] + iv*gv;
      if (u < HH) Hh0[1][wrow + i*HSTR2] = f2b(ov*th(c0[i]));
    }
    __syncthreads();
  }

  // ---- merged loop ----
  for (int s = 0; s < NOUT; ++s){
    const int b = (s+1)&1;
    const s8v a1 = *(const s8v*)&Hh0[b][aoff];
    const s8v a2 = *(const s8v*)&Hh1[s&1][aoff];
    f4v ac1[4];
    #pragma unroll
    for (int g=0; g<4; ++g){
      f4v a = {bias1[g], bias1[g], bias1[g], bias1[g]};
      a = __builtin_amdgcn_mfma_f32_16x16x32_bf16(a1, B10[g], a, 0, 0, 0);
      ac1[g] = __builtin_amdgcn_mfma_f32_16x16x32_bf16(a2, B11[g], a, 0, 0, 0);
    }
    const bool hasNext = (s < NOUT-1);
    f4v ac0[4];
    if (hasNext){
      #pragma unroll
      for (int i=0;i<4;++i) tt[i] = tstep(tt[i]);
      float4 yv4 = *(const float4*)&yT[(size_t)s*NB + sbase];
      yv[0]=yv4.x; yv[1]=yv4.y; yv[2]=yv4.z; yv[3]=yv4.w;
      #pragma unroll
      for (int g=0; g<4; ++g){
        f4v a = pc[g];
        #pragma unroll
        for (int i=0;i<4;++i) a[i] += tt[i]*wtt[g] + yv[i]*wty[g];
        ac0[g] = __builtin_amdgcn_mfma_f32_16x16x32_bf16(a1, B0[g], a, 0, 0, 0);
      }
    }
    unsigned short hw[4];
    #pragma unroll
    for (int i=0;i<4;++i){
      float iv = sg(ac1[0][i]), fv = sg(ac1[1][i]), gv = th(ac1[2][i]), ov = sg(ac1[3][i]);
      c1[i] = fv*c1[i] + iv*gv;
      hw[i] = f2b(ov*th(c1[i]));
    }
    if (u < HH){
      #pragma unroll
      for (int i=0;i<4;++i) Hh1[b][wrow + i*HSTR2] = hw[i];
      us4v pk = {hw[0], hw[1], hw[2], hw[3]};
      *reinterpret_cast<us4v*>(&h1s[((size_t)s*HH + u)*NB + sbase]) = pk;
    }
    if (hasNext){
      #pragma unroll
      for (int i=0;i<4;++i){
        float iv = sg(ac0[0][i]), fv = sg(ac0[1][i]), gv = th(ac0[2][i]), ov = sg(ac0[3][i]);
        c0[i] = fv*c0[i] + iv*gv;
        if (u < HH) Hh0[s&1][wrow + i*HSTR2] = f2b(ov*th(c0[i]));
      }
    }
    __syncthreads();
  }
}

// ---------------- BN2 stats: contiguous-array reductions ----------------
__global__ __launch_bounds__(256) void k_bn2h(
    const __hip_bfloat16* __restrict__ h1n, double* __restrict__ s2)
{
  __shared__ double sd[256];
  __shared__ double qd[256];
  const int s = blockIdx.x, u = blockIdx.y;
  const unsigned short* p = (const unsigned short*)(h1n + ((size_t)s*HH + u)*NB);
  double sv = 0.0, sq = 0.0;
  #pragma unroll
  for (int c = 0; c < 8; ++c){
    s8v v = *(const s8v*)(p + ((size_t)c*256 + threadIdx.x)*8);
    #pragma unroll
    for (int j=0;j<8;++j){
      float f = b2f((unsigned short)v[j]);
      sv += f; sq += (double)f*(double)f;
    }
  }
  sd[threadIdx.x] = sv; qd[threadIdx.x] = sq;
  __syncthreads();
  for (int st2=128; st2>0; st2>>=1){
    if ((int)threadIdx.x < st2){
      sd[threadIdx.x] += sd[threadIdx.x+st2];
      qd[threadIdx.x] += qd[threadIdx.x+st2];
    }
    __syncthreads();
  }
  if (threadIdx.x == 0){
    s2[((size_t)s*F2 + u)*2]   = sd[0];
    s2[((size_t)s*F2 + u)*2+1] = qd[0];
  }
}

__global__ __launch_bounds__(256) void k_bn2y(
    const float* __restrict__ ypack, const float* __restrict__ yT, double* __restrict__ s2)
{
  __shared__ double sd[256];
  __shared__ double qd[256];
  const int s = blockIdx.x;
  const float* src = (s == 0) ? ypack : (yT + (size_t)(s-1)*NB);
  double sv = 0.0, sq = 0.0;
  #pragma unroll
  for (int c = 0; c < 16; ++c){
    float4 v = *(const float4*)(src + ((size_t)c*256 + threadIdx.x)*4);
    sv += (double)v.x + (double)v.y + (double)v.z + (double)v.w;
    sq += (double)v.x*v.x + (double)v.y*v.y + (double)v.z*v.z + (double)v.w*v.w;
  }
  sd[threadIdx.x] = sv; qd[threadIdx.x] = sq;
  __syncthreads();
  for (int st2=128; st2>0; st2>>=1){
    if ((int)threadIdx.x < st2){
      sd[threadIdx.x] += sd[threadIdx.x+st2];
      qd[threadIdx.x] += qd[threadIdx.x+st2];
    }
    __syncthreads();
  }
  if (threadIdx.x == 0){
    s2[((size_t)s*F2 + 51)*2]   = sd[0];
    s2[((size_t)s*F2 + 51)*2+1] = qd[0];
  }
}

// t feature: fast chain + store per-step t values for k_rdm
__global__ __launch_bounds__(256) void k_bn2t(
    const float* __restrict__ tpack, double* __restrict__ s2, float* __restrict__ tfull)
{
  const int r = blockIdx.x*256 + threadIdx.x;
  float t = fmodf(tpack[r] + 15.f, 1440.f);   // s=0: true fmod
  const int lane = threadIdx.x & 63;
  for (int s = 0; s < NOUT; ++s){
    tfull[(size_t)s*NB + r] = t;
    double sv = (double)t, sq = (double)t*(double)t;
    #pragma unroll
    for (int m=32;m>0;m>>=1){ sv += shfl_xor_d(sv,m); sq += shfl_xor_d(sq,m); }
    if (lane == 0){
      atomicAdd(&s2[((size_t)s*F2 + 50)*2],   sv);
      atomicAdd(&s2[((size_t)s*F2 + 50)*2+1], sq);
    }
    t = tstep(t);
  }
}

__global__ __launch_bounds__(256) void k_fin2b(
    const double* __restrict__ s1, const double* __restrict__ s2,
    float* __restrict__ m2, float* __restrict__ r2)
{
  int i = blockIdx.x*256 + threadIdx.x;
  if (i >= NOUT*F2) return;
  int f = i % F2;
  double sv, sq;
  if (f >= HH && f < HH+CVD){
    sv = s1[(2*HH + (f-HH))*2];
    sq = s1[(2*HH + (f-HH))*2+1];
  } else {
    sv = s2[i*2]; sq = s2[i*2+1];
  }
  double m = sv/(double)NB;
  double var = sq/(double)NB - m*m;
  if (var < 0.0) var = 0.0;
  m2[i] = (float)m;
  r2[i] = (float)(1.0/sqrt(var + 1e-5));
}

// ---------------- readout: MFMA GEMM with split-A bf16 ----------------
__global__ __launch_bounds__(256, 4) void k_rdm(
    const __hip_bfloat16* __restrict__ h1n, const float* __restrict__ xcg,
    const float* __restrict__ tfull, const float* __restrict__ ypack, const float* __restrict__ yT,
    const float* __restrict__ m2, const float* __restrict__ r2,
    const float* __restrict__ g2, const float* __restrict__ b2v,
    const unsigned short* __restrict__ wd5, const float* __restrict__ Bd,
    const float* __restrict__ Ud, const float* __restrict__ Cd,
    float* __restrict__ outT)
{
  __shared__ __align__(16) unsigned short FH[64*64];
  __shared__ __align__(16) unsigned short FL[64*64];
  __shared__ float scl[F2], sft[F2];
  const int tid = threadIdx.x, l = tid & 63, w = tid >> 6;
  const int lr = l & 15, lq = l >> 4;
  const int s = blockIdx.y, rr0 = blockIdx.x*64;
  if (tid < F2){
    float m = m2[s*F2+tid], rv = r2[s*F2+tid];
    float sc = rv * g2[tid];
    scl[tid] = sc;
    sft[tid] = b2v[tid] - m*sc;
  }
  __syncthreads();
  for (int i = tid; i < 64*64; i += 256){
    int f = i >> 6, r = i & 63;
    float v;
    if (f < HH) v = __bfloat162float(h1n[((size_t)s*HH + f)*NB + rr0 + r]);
    else if (f < HH+CVD) v = xcg[(size_t)(rr0+r)*CVD + (f-HH)];
    else if (f == 50) v = tfull[(size_t)s*NB + rr0 + r];
    else if (f == 51) v = (s==0) ? ypack[rr0+r] : yT[(size_t)(s-1)*NB + rr0 + r];
    else v = 0.f;
    if (f < F2) v = v*scl[f] + sft[f];
    unsigned short hi = f2b(v);
    float lo = v - b2f(hi);
    int off = r*64 + ((((f>>3) ^ (r&7))&7)<<3) + (f&7);
    FH[off] = hi;
    FL[off] = f2b(lo);
  }
  __syncthreads();
  const int row = w*16 + lr;
  s8v ah[2], al[2];
  #pragma unroll
  for (int ks=0;ks<2;++ks){
    int ch = ((ks*4+lq) ^ (row&7)) & 7;
    ah[ks] = *(const s8v*)&FH[row*64 + ch*8];
    al[ks] = *(const s8v*)&FL[row*64 + ch*8];
  }
  f4v ps = {0.f,0.f,0.f,0.f};
  #pragma unroll 7
  for (int ct=0; ct<7; ++ct){
    int col = ct*16 + lr;
    float bd = (col < HID) ? Bd[(size_t)s*HID + col] : 0.f;
    f4v acc = {bd,bd,bd,bd};
    #pragma unroll
    for (int ks=0;ks<2;++ks){
      s8v B = *(const s8v*)(wd5 + ((size_t)(s*14 + ks*7 + ct)*512) + l*8);
      acc = __builtin_amdgcn_mfma_f32_16x16x32_bf16(ah[ks], B, acc, 0, 0, 0);
      acc = __builtin_amdgcn_mfma_f32_16x16x32_bf16(al[ks], B, acc, 0, 0, 0);
    }
    float ud = (col < HID) ? Ud[(size_t)s*HID + col] : 0.f;
    #pragma unroll
    for (int i=0;i<4;++i) ps[i] += fmaxf(acc[i], 0.f) * ud;
  }
  #pragma unroll
  for (int m=1; m<16; m<<=1){
    #pragma unroll
    for (int i=0;i<4;++i) ps[i] += __shfl_xor(ps[i], m, 64);
  }
  if (lr == 0){
    float cd = Cd[s];
    float4 o = { ps[0]+cd, ps[1]+cd, ps[2]+cd, ps[3]+cd };
    *(float4*)&outT[(size_t)s*NB + rr0 + w*16 + lq*4] = o;
  }
}

// ---------------- host ----------------
extern "C" void kernel_launch(void* const* d_in, const int* in_sizes, int n_in,
                              void* d_out, int out_size, void* d_ws, size_t ws_size,
                              hipStream_t stream)
{
  const float* x    = (const float*)d_in[0];
  const float* y    = (const float*)d_in[1];
  const float* h0i  = (const float*)d_in[2];
  const float* c0i  = (const float*)d_in[3];
  const float* wih0 = (const float*)d_in[4];
  const float* whh0 = (const float*)d_in[5];
  const float* bih0 = (const float*)d_in[6];
  const float* bhh0 = (const float*)d_in[7];
  const float* wih1 = (const float*)d_in[8];
  const float* whh1 = (const float*)d_in[9];
  const float* bih1 = (const float*)d_in[10];
  const float* bhh1 = (const float*)d_in[11];
  const float* w2ih0= (const float*)d_in[12];
  const float* w2hh0= (const float*)d_in[13];
  const float* b2ih0= (const float*)d_in[14];
  const float* b2hh0= (const float*)d_in[15];
  const float* w2ih1= (const float*)d_in[16];
  const float* w2hh1= (const float*)d_in[17];
  const float* b2ih1= (const float*)d_in[18];
  const float* b2hh1= (const float*)d_in[19];
  const float* c1w  = (const float*)d_in[20];
  const float* c1b  = (const float*)d_in[21];
  const float* c2w  = (const float*)d_in[22];
  const float* c2b  = (const float*)d_in[23];
  const float* c3w  = (const float*)d_in[24];
  const float* c3b  = (const float*)d_in[25];
  const float* fcw  = (const float*)d_in[26];
  const float* fcb  = (const float*)d_in[27];
  const float* bn1g = (const float*)d_in[28];
  const float* bn1b = (const float*)d_in[29];
  const float* bn2g = (const float*)d_in[30];
  const float* bn2b = (const float*)d_in[31];
  const float* Wd   = (const float*)d_in[32];
  const float* Bd   = (const float*)d_in[33];
  const float* Ud   = (const float*)d_in[34];
  const float* Cd   = (const float*)d_in[35];
  float* out = (float*)d_out;

  char* base = (char*)d_ws;
  size_t off = 0;
  auto take = [&](size_t bytes)->char*{
    char* p = base + off;
    off = (off + bytes + 255) & ~(size_t)255;
    return p;
  };
  float*  h0f = (float*) take((size_t)NB*HH*sizeof(float));
  float*  h1f = (float*) take((size_t)NB*HH*sizeof(float));
  float*  c0f = (float*) take((size_t)NB*HH*sizeof(float));
  float*  c1f = (float*) take((size_t)NB*HH*sizeof(float));
  float*  xcg = (float*) take((size_t)NB*CVD*sizeof(float));
  float*  ctx = (float*) take((size_t)NB*CTXD*sizeof(float));
  double* s1  = (double*)take((size_t)CTXD*2*sizeof(double));
  float*  st1 = (float*) take((size_t)CTXD*2*sizeof(float));
  double* s2  = (double*)take((size_t)NOUT*F2*2*sizeof(double));
  float*  m2  = (float*) take((size_t)NOUT*F2*sizeof(float));
  float*  r2  = (float*) take((size_t)NOUT*F2*sizeof(float));
  unsigned short* wb2 = (unsigned short*) take((size_t)48*512*sizeof(unsigned short));
  float*  tb  = (float*) take((size_t)4*128*sizeof(float));
  unsigned short* wb3 = (unsigned short*) take((size_t)32*512*sizeof(unsigned short));
  float*  tbe = (float*) take((size_t)2*128*sizeof(float));
  unsigned short* wc  = (unsigned short*) take((size_t)96*512*sizeof(unsigned short));
  unsigned short* wd5 = (unsigned short*) take((size_t)NOUT*14*512*sizeof(unsigned short));
  float*  tpk = (float*) take((size_t)NB*sizeof(float));
  float*  ypk = (float*) take((size_t)NB*sizeof(float));
  float*  yT  = (float*) take((size_t)NOUT*NB*sizeof(float));
  float*  oT  = (float*) take((size_t)NOUT*NB*sizeof(float));
  float*  tfl = (float*) take((size_t)NOUT*NB*sizeof(float));
  __hip_bfloat16* h1n = (__hip_bfloat16*) take((size_t)NOUT*HH*NB*sizeof(__hip_bfloat16));
  (void)ws_size;

  k_tw2<<<dim3((48*512+512+255)/256), dim3(256), 0, stream>>>(w2ih0, w2hh0, w2ih1, w2hh1,
      b2ih0, b2hh0, b2ih1, b2hh1, wb2, tb);
  k_tw3<<<dim3((32*512+256+255)/256), dim3(256), 0, stream>>>(wih0, whh0, wih1, whh1,
      bih0, bhh0, bih1, bhh1, wb3, tbe);
  k_tw4<<<dim3((96*512+255)/256), dim3(256), 0, stream>>>(c1w, c2w, c3w, fcw, wc);
  k_tw5<<<dim3((NOUT*14*512+255)/256), dim3(256), 0, stream>>>(Wd, wd5);
  k_pack<<<dim3(NB/256), dim3(256), 0, stream>>>(x, tpk, ypk);
  k_ty<<<dim3(NB/64), dim3(256), 0, stream>>>(y, yT);
  k_zero<<<dim3((NOUT*F2*2+255)/256), dim3(256), 0, stream>>>(s1, s2);
  k_encm<<<dim3(NB/SMP), dim3(512), 0, stream>>>(x, h0i, c0i, wb3, tbe, h0f, h1f, c0f, c1f);
  k_convm<<<dim3(NB/16), dim3(256), 0, stream>>>(x, wc, c1b, c2b, c3b, fcb, xcg);
  k_bn1s<<<dim3(NB/128), dim3(128), 0, stream>>>(h0f, h1f, xcg, s1);
  k_fin1<<<dim3(1), dim3(128), 0, stream>>>(s1, st1);
  k_context<<<dim3((NB*CTXD + 255)/256), dim3(256), 0, stream>>>(h0f, h1f, xcg, st1, bn1g, bn1b, ctx);
  k_dec1m<<<dim3(NB/SMP), dim3(512), 0, stream>>>(tpk, ypk, yT, ctx, wb2, tb,
      h0f, h1f, c0f, c1f, h1n);
  k_bn2h<<<dim3(NOUT, HH), dim3(256), 0, stream>>>(h1n, s2);
  k_bn2y<<<dim3(NOUT), dim3(256), 0, stream>>>(ypk, yT, s2);
  k_bn2t<<<dim3(NB/256), dim3(256), 0, stream>>>(tpk, s2, tfl);
  k_fin2b<<<dim3((NOUT*F2+255)/256), dim3(256), 0, stream>>>(s1, s2, m2, r2);
  k_rdm<<<dim3(NB/64, NOUT), dim3(256), 0, stream>>>(h1n, xcg, tfl, ypk, yT,
      m2, r2, bn2g, bn2b, wd5, Bd, Ud, Cd, oT);
  k_tro<<<dim3(NB/64), dim3(256), 0, stream>>>(oT, out);
}